// Round 1
// baseline (3493.517 us; speedup 1.0000x reference)
//
#include <hip/hip_runtime.h>
#include <hip/hip_bf16.h>

// Performer (FAVOR+) forward, f32 baseline pipeline.
// B=4, S=4096, D=1024, H=16, K=64, M=128 supports.
//
// Stage order (all on `stream`):
//   1. k_proj = key @ Wk + bk            (gemm)      -> ws[A]
//   2. global stab = max(wx_k)           (wxmax + reduce)
//   3. v_proj = value @ Wv + bv          (gemm)      -> ws[B]
//   4. kv/k1 = sum_s phi_k (x) v         (kvpart + kvreduce)
//   5. q_proj = query @ Wq + bq          (gemm)      -> ws[A] (k_proj dead)
//   6. out_h = (phi_q @ kv) / (phi_q.k1) (qkv)       -> ws[B] (v_proj dead)
//   7. out = out_h @ Wo + bo             (gemm)      -> d_out

#define B_  4
#define S_  4096
#define Dm  1024
#define H_  16
#define Kh  64
#define M_  128

#define SCALE_X 0.3535533905932738f     // 64^-0.25
#define CM      0.08838834764831845f    // 128^-0.5

// ---- ws layout (in floats) ----
#define OFF_A    ((size_t)0)            // 16384*1024 : k_proj then q_proj
#define OFF_B    ((size_t)16777216)     // 16384*1024 : v_proj then out_h
#define OFF_BM   ((size_t)33554432)     // 1024 block maxes
#define OFF_ST   ((size_t)33555456)     // 1 stab scalar
#define OFF_KVP  ((size_t)33555712)     // 512 * 8320 kv partials (+k1)
#define OFF_KV   ((size_t)37815552)     // 64 * 8192
#define OFF_K1   ((size_t)38339840)     // 64 * 128
// total 38348032 floats = 153.4 MB

// ---------------------------------------------------------------------------
// Generic f32 GEMM: C[M,N] = A[M,Kd] @ B[Kd,N] + bias[N]
// 64x64 tile, BK=16, 256 threads, 4x4 microtile per thread.
// ---------------------------------------------------------------------------
__global__ __launch_bounds__(256) void gemm_f32_kernel(
    const float* __restrict__ A, const float* __restrict__ Bm,
    const float* __restrict__ bias, float* __restrict__ C,
    int M, int N, int Kd) {
  __shared__ float As[16][68];
  __shared__ float Bs[16][68];
  const int tid = threadIdx.x;
  const int m0 = blockIdx.x * 64;
  const int n0 = blockIdx.y * 64;

  const int tm = (tid >> 4) << 2;   // row group 0..60
  const int tn = (tid & 15) << 2;   // col group 0..60

  const int arow = tid >> 2;        // 0..63
  const int acol = (tid & 3) << 2;  // 0,4,8,12
  const int brow = tid >> 4;        // 0..15
  const int bcol = (tid & 15) << 2; // 0..60

  float acc[4][4] = {};

  const float* Ap = A + (size_t)(m0 + arow) * Kd + acol;

  for (int k0 = 0; k0 < Kd; k0 += 16) {
    float4 a4 = *reinterpret_cast<const float4*>(Ap + k0);
    float4 b4 = *reinterpret_cast<const float4*>(
        Bm + (size_t)(k0 + brow) * N + n0 + bcol);
    __syncthreads();
    As[acol + 0][arow] = a4.x;
    As[acol + 1][arow] = a4.y;
    As[acol + 2][arow] = a4.z;
    As[acol + 3][arow] = a4.w;
    *reinterpret_cast<float4*>(&Bs[brow][bcol]) = b4;
    __syncthreads();
#pragma unroll
    for (int kk = 0; kk < 16; ++kk) {
      float4 av = *reinterpret_cast<const float4*>(&As[kk][tm]);
      float4 bv = *reinterpret_cast<const float4*>(&Bs[kk][tn]);
      acc[0][0] = fmaf(av.x, bv.x, acc[0][0]);
      acc[0][1] = fmaf(av.x, bv.y, acc[0][1]);
      acc[0][2] = fmaf(av.x, bv.z, acc[0][2]);
      acc[0][3] = fmaf(av.x, bv.w, acc[0][3]);
      acc[1][0] = fmaf(av.y, bv.x, acc[1][0]);
      acc[1][1] = fmaf(av.y, bv.y, acc[1][1]);
      acc[1][2] = fmaf(av.y, bv.z, acc[1][2]);
      acc[1][3] = fmaf(av.y, bv.w, acc[1][3]);
      acc[2][0] = fmaf(av.z, bv.x, acc[2][0]);
      acc[2][1] = fmaf(av.z, bv.y, acc[2][1]);
      acc[2][2] = fmaf(av.z, bv.z, acc[2][2]);
      acc[2][3] = fmaf(av.z, bv.w, acc[2][3]);
      acc[3][0] = fmaf(av.w, bv.x, acc[3][0]);
      acc[3][1] = fmaf(av.w, bv.y, acc[3][1]);
      acc[3][2] = fmaf(av.w, bv.z, acc[3][2]);
      acc[3][3] = fmaf(av.w, bv.w, acc[3][3]);
    }
  }

  float4 bb = *reinterpret_cast<const float4*>(&bias[n0 + tn]);
#pragma unroll
  for (int i = 0; i < 4; ++i) {
    float4 o;
    o.x = acc[i][0] + bb.x;
    o.y = acc[i][1] + bb.y;
    o.z = acc[i][2] + bb.z;
    o.w = acc[i][3] + bb.w;
    *reinterpret_cast<float4*>(&C[(size_t)(m0 + tm + i) * N + n0 + tn]) = o;
  }
}

// ---------------------------------------------------------------------------
// Global max of wx_k over all (b,s,h,m). One wave per row batch.
// ---------------------------------------------------------------------------
__global__ __launch_bounds__(256) void wxmax_kernel(
    const float* __restrict__ kproj, const float* __restrict__ proj,
    float* __restrict__ blockmax) {
  __shared__ float projT[64][128];  // projT[k][m] = proj[m*64+k]
  __shared__ float wmax_s[4];
  const int tid = threadIdx.x;
  for (int i = tid; i < 128 * 64; i += 256) {
    int m = i >> 6, k = i & 63;
    projT[k][m] = proj[i];
  }
  __syncthreads();
  const int lane = tid & 63, w = tid >> 6;
  const int gw = blockIdx.x * 4 + w;  // 4096 waves total
  const int ROWS = B_ * S_ * H_;      // 262144
  float wmax = -3.4e38f;
  for (int r = gw; r < ROWS; r += 4096) {
    float xv = kproj[(size_t)r * 64 + lane] * SCALE_X;
    float w0 = 0.f, w1 = 0.f;
#pragma unroll
    for (int k = 0; k < 64; ++k) {
      float xk = __shfl(xv, k);
      w0 = fmaf(xk, projT[k][lane], w0);
      w1 = fmaf(xk, projT[k][lane + 64], w1);
    }
    wmax = fmaxf(wmax, fmaxf(w0, w1));
  }
#pragma unroll
  for (int off = 32; off; off >>= 1) wmax = fmaxf(wmax, __shfl_xor(wmax, off));
  if (lane == 0) wmax_s[w] = wmax;
  __syncthreads();
  if (tid == 0)
    blockmax[blockIdx.x] =
        fmaxf(fmaxf(wmax_s[0], wmax_s[1]), fmaxf(wmax_s[2], wmax_s[3]));
}

__global__ __launch_bounds__(256) void maxreduce_kernel(
    const float* __restrict__ blockmax, float* __restrict__ stab, int n) {
  __shared__ float sm[256];
  float v = -3.4e38f;
  for (int i = threadIdx.x; i < n; i += 256) v = fmaxf(v, blockmax[i]);
  sm[threadIdx.x] = v;
  __syncthreads();
  for (int s = 128; s; s >>= 1) {
    if (threadIdx.x < s) sm[threadIdx.x] = fmaxf(sm[threadIdx.x], sm[threadIdx.x + s]);
    __syncthreads();
  }
  if (threadIdx.x == 0) *stab = sm[0];
}

// ---------------------------------------------------------------------------
// kv partials: block = (bh, chunk of 512 s). Recompute phi_k on the fly,
// accumulate kv[128][64] and k1[128] partials.
// ---------------------------------------------------------------------------
__global__ __launch_bounds__(256) void kvpart_kernel(
    const float* __restrict__ kproj, const float* __restrict__ vproj,
    const float* __restrict__ proj, const float* __restrict__ stabp,
    float* __restrict__ kvpart) {
  __shared__ float projT[64][128];
  __shared__ float xs[16][64];
  __shared__ float phis[16][128];
  __shared__ float diags[16];
  const int tid = threadIdx.x;
  const int blk = blockIdx.x;        // 512
  const int c = blk & 7, bh = blk >> 3;
  const int b = bh >> 4, h = bh & 15;
  const float stab = *stabp;

  for (int i = tid; i < 128 * 64; i += 256) {
    int m = i >> 6, k = i & 63;
    projT[k][m] = proj[i];
  }
  __syncthreads();

  float acc[32] = {};
  float k1acc = 0.f;
  const int kk = tid & 63, mb = tid >> 6;     // accumulate mapping
  const int mphi = tid & 127, rbase = tid >> 7;  // wx mapping
  const int xrow = tid >> 4, xq = (tid & 15) << 2;
  const int s0c = c * 512;

  for (int batch = 0; batch < 32; ++batch) {
    const int s0 = s0c + batch * 16;
    {
      const float* src =
          kproj + (((size_t)(b * S_ + s0 + xrow) * H_ + h) << 6) + xq;
      float4 v4 = *reinterpret_cast<const float4*>(src);
      xs[xrow][xq + 0] = v4.x * SCALE_X;
      xs[xrow][xq + 1] = v4.y * SCALE_X;
      xs[xrow][xq + 2] = v4.z * SCALE_X;
      xs[xrow][xq + 3] = v4.w * SCALE_X;
    }
    __syncthreads();
    if (tid < 16) {
      float d = 0.f;
#pragma unroll
      for (int k = 0; k < 64; ++k) d = fmaf(xs[tid][k], xs[tid][k], d);
      diags[tid] = 0.5f * d;
    }
    __syncthreads();
#pragma unroll
    for (int i = 0; i < 8; ++i) {
      const int r = rbase + 2 * i;
      float wv = 0.f;
#pragma unroll
      for (int k = 0; k < 64; ++k) wv = fmaf(xs[r][k], projT[k][mphi], wv);
      phis[r][mphi] = __expf(wv - diags[r] - stab) * CM;
    }
    __syncthreads();
    for (int si = 0; si < 16; ++si) {
      float vv = vproj[(((size_t)(b * S_ + s0 + si) * H_ + h) << 6) + kk];
#pragma unroll
      for (int j = 0; j < 32; ++j)
        acc[j] = fmaf(phis[si][mb + 4 * j], vv, acc[j]);
      if (tid < 128) k1acc += phis[si][tid];
    }
    __syncthreads();
  }

  float* outp = kvpart + (size_t)blk * 8320;
#pragma unroll
  for (int j = 0; j < 32; ++j) outp[(mb + 4 * j) * 64 + kk] = acc[j];
  if (tid < 128) outp[8192 + tid] = k1acc;
}

__global__ __launch_bounds__(256) void kvreduce_kernel(
    const float* __restrict__ kvpart, float* __restrict__ kv,
    float* __restrict__ k1) {
  const int bh = blockIdx.x;  // 64
  for (int idx = threadIdx.x; idx < 8192; idx += 256) {
    float s = 0.f;
#pragma unroll
    for (int c = 0; c < 8; ++c) s += kvpart[(size_t)(bh * 8 + c) * 8320 + idx];
    kv[(size_t)bh * 8192 + idx] = s;
  }
  if (threadIdx.x < 128) {
    float s = 0.f;
#pragma unroll
    for (int c = 0; c < 8; ++c)
      s += kvpart[(size_t)(bh * 8 + c) * 8320 + 8192 + threadIdx.x];
    k1[bh * 128 + threadIdx.x] = s;
  }
}

// ---------------------------------------------------------------------------
// qkv: block = (bh, chunk of 256 t). phi_q on the fly (per-row max),
// contract with LDS-staged kv + k1, normalize, write out_h.
// ---------------------------------------------------------------------------
__global__ __launch_bounds__(256) void qkv_kernel(
    const float* __restrict__ qproj, const float* __restrict__ kv,
    const float* __restrict__ k1, const float* __restrict__ proj,
    float* __restrict__ outh) {
  __shared__ float projT[64][128];
  __shared__ float kvs[128][64];
  __shared__ float k1s[128];
  __shared__ float xs[16][64];
  __shared__ float phis[16][128];
  __shared__ float diags[16], rmax[16], dens[16];
  const int tid = threadIdx.x;
  const int blk = blockIdx.x;        // 1024 = 64 bh * 16 chunks
  const int ch = blk & 15, bh = blk >> 4;
  const int b = bh >> 4, h = bh & 15;

  for (int i = tid; i < 128 * 64; i += 256) {
    int m = i >> 6, k = i & 63;
    projT[k][m] = proj[i];
  }
  for (int i = tid; i < 8192; i += 256)
    (&kvs[0][0])[i] = kv[(size_t)bh * 8192 + i];
  if (tid < 128) k1s[tid] = k1[bh * 128 + tid];
  __syncthreads();

  const int t0 = ch * 256;
  const int mphi = tid & 127, rbase = tid >> 7;
  const int kk = tid & 63, rb2 = tid >> 6;
  const int xrow = tid >> 4, xq = (tid & 15) << 2;

  for (int batch = 0; batch < 16; ++batch) {
    const int s0 = t0 + batch * 16;
    {
      const float* src =
          qproj + (((size_t)(b * S_ + s0 + xrow) * H_ + h) << 6) + xq;
      float4 v4 = *reinterpret_cast<const float4*>(src);
      xs[xrow][xq + 0] = v4.x * SCALE_X;
      xs[xrow][xq + 1] = v4.y * SCALE_X;
      xs[xrow][xq + 2] = v4.z * SCALE_X;
      xs[xrow][xq + 3] = v4.w * SCALE_X;
    }
    __syncthreads();
    if (tid < 16) {
      float d = 0.f;
#pragma unroll
      for (int k = 0; k < 64; ++k) d = fmaf(xs[tid][k], xs[tid][k], d);
      diags[tid] = 0.5f * d;
    }
    __syncthreads();
#pragma unroll
    for (int i = 0; i < 8; ++i) {
      const int r = rbase + 2 * i;
      float wv = 0.f;
#pragma unroll
      for (int k = 0; k < 64; ++k) wv = fmaf(xs[r][k], projT[k][mphi], wv);
      phis[r][mphi] = wv;
    }
    __syncthreads();
    if (tid < 16) {
      float mx = -3.4e38f;
#pragma unroll
      for (int m = 0; m < 128; ++m) mx = fmaxf(mx, phis[tid][m]);
      rmax[tid] = mx;
    }
    __syncthreads();
#pragma unroll
    for (int i = 0; i < 8; ++i) {
      const int r = rbase + 2 * i;
      phis[r][mphi] = __expf(phis[r][mphi] - diags[r] - rmax[r]) * CM;
    }
    __syncthreads();
    if (tid < 16) {
      float dsum = 0.f;
#pragma unroll
      for (int m = 0; m < 128; ++m) dsum = fmaf(phis[tid][m], k1s[m], dsum);
      dens[tid] = 1.f / (dsum + 1e-6f);
    }
    __syncthreads();
#pragma unroll
    for (int i = 0; i < 4; ++i) {
      const int r = rb2 + 4 * i;
      float o = 0.f;
#pragma unroll
      for (int m = 0; m < 128; ++m) o = fmaf(phis[r][m], kvs[m][kk], o);
      outh[(((size_t)(b * S_ + s0 + r) * H_ + h) << 6) + kk] = o * dens[r];
    }
    __syncthreads();
  }
}

// ---------------------------------------------------------------------------
extern "C" void kernel_launch(void* const* d_in, const int* in_sizes, int n_in,
                              void* d_out, int out_size, void* d_ws,
                              size_t ws_size, hipStream_t stream) {
  const float* query = (const float*)d_in[0];
  const float* value = (const float*)d_in[1];   // NOTE: value is index 1
  const float* key   = (const float*)d_in[2];   // key is index 2
  const float* Wq = (const float*)d_in[3];
  const float* bq = (const float*)d_in[4];
  const float* Wk = (const float*)d_in[5];
  const float* bk = (const float*)d_in[6];
  const float* Wv = (const float*)d_in[7];
  const float* bv = (const float*)d_in[8];
  const float* Wo = (const float*)d_in[9];
  const float* bo = (const float*)d_in[10];
  const float* proj = (const float*)d_in[11];
  float* out = (float*)d_out;
  float* ws = (float*)d_ws;

  const int Mrows = B_ * S_;  // 16384
  dim3 gg(Mrows / 64, Dm / 64);

  // 1. k_proj
  gemm_f32_kernel<<<gg, 256, 0, stream>>>(key, Wk, bk, ws + OFF_A, Mrows, Dm, Dm);
  // 2. global stab
  wxmax_kernel<<<1024, 256, 0, stream>>>(ws + OFF_A, proj, ws + OFF_BM);
  maxreduce_kernel<<<1, 256, 0, stream>>>(ws + OFF_BM, ws + OFF_ST, 1024);
  // 3. v_proj
  gemm_f32_kernel<<<gg, 256, 0, stream>>>(value, Wv, bv, ws + OFF_B, Mrows, Dm, Dm);
  // 4. kv / k1
  kvpart_kernel<<<512, 256, 0, stream>>>(ws + OFF_A, ws + OFF_B, proj,
                                         ws + OFF_ST, ws + OFF_KVP);
  kvreduce_kernel<<<64, 256, 0, stream>>>(ws + OFF_KVP, ws + OFF_KV, ws + OFF_K1);
  // 5. q_proj (reuse A)
  gemm_f32_kernel<<<gg, 256, 0, stream>>>(query, Wq, bq, ws + OFF_A, Mrows, Dm, Dm);
  // 6. out_h (reuse B)
  qkv_kernel<<<1024, 256, 0, stream>>>(ws + OFF_A, ws + OFF_KV, ws + OFF_K1,
                                       proj, ws + OFF_B);
  // 7. output projection
  gemm_f32_kernel<<<gg, 256, 0, stream>>>(ws + OFF_B, Wo, bo, out, Mrows, Dm, Dm);
}

// Round 2
// 942.650 us; speedup vs baseline: 3.7061x; 3.7061x over previous
//
#include <hip/hip_runtime.h>
#include <hip/hip_bf16.h>

// Performer (FAVOR+) forward. Round 2: split-bf16 MFMA GEMMs + spill-free middle.
// B=4, S=4096, D=1024, H=16, K=64, M=128.

#define B_  4
#define S_  4096
#define H_  16

#define SCALE_X 0.3535533905932738f     // 64^-0.25
#define CM      0.08838834764831845f    // 128^-0.5

typedef __attribute__((ext_vector_type(8))) short bf16x8;
typedef __attribute__((ext_vector_type(8))) unsigned short u16x8;
typedef __attribute__((ext_vector_type(4))) float f32x4;

// ---- ws layout (float units) ----
#define OFF_A   ((size_t)0)          // 16777216 : k_proj then q_proj
#define OFF_B   ((size_t)16777216)   // 16777216 : v_proj then out_h
#define OFF_X   ((size_t)33554432)   // union: WT split (1M floats) / KVP (4259840)
#define OFF_KV  ((size_t)37814272)   // kv bf16: 64*8192 ushort = 262144 floats
#define OFF_K1  ((size_t)38076416)   // 64*128 f32
#define OFF_BM  ((size_t)38084608)   // 512 block maxes
#define OFF_ST  ((size_t)38085120)   // stab scalar
// end 38085121 floats = 152.3 MB

__device__ __forceinline__ unsigned short f2bf(float x) {
  union { __hip_bfloat16 b; unsigned short u; } c;
  c.b = __float2bfloat16(x);
  return c.u;
}
__device__ __forceinline__ float bf2f(unsigned short u) {
  union { float f; unsigned int i; } c;
  c.i = ((unsigned int)u) << 16;
  return c.f;
}

// ---------------------------------------------------------------------------
// Weight transform: W[1024 k][1024 n] f32 -> WT_hi/WT_lo [n][k] bf16.
// ---------------------------------------------------------------------------
__global__ __launch_bounds__(256) void wt_split_kernel(
    const float* __restrict__ W, unsigned short* __restrict__ Th,
    unsigned short* __restrict__ Tl) {
  __shared__ float t[32][33];
  const int tx = threadIdx.x & 31, ty = threadIdx.x >> 5;  // 32 x 8
  const int k0 = blockIdx.x * 32, n0 = blockIdx.y * 32;
#pragma unroll
  for (int i = 0; i < 4; ++i)
    t[ty + 8 * i][tx] = W[(size_t)(k0 + ty + 8 * i) * 1024 + n0 + tx];
  __syncthreads();
#pragma unroll
  for (int i = 0; i < 4; ++i) {
    float v = t[tx][ty + 8 * i];  // = W[k0+tx][n0+ty+8i]
    unsigned short hu = f2bf(v);
    unsigned short lu = f2bf(v - bf2f(hu));
    size_t o = (size_t)(n0 + ty + 8 * i) * 1024 + k0 + tx;
    Th[o] = hu;
    Tl[o] = lu;
  }
}

// ---------------------------------------------------------------------------
// Split-bf16 MFMA GEMM: C[16384,1024] = A[16384,1024] @ W + bias.
// A f32 (converted hi/lo on the fly), W pre-split as BT_hi/BT_lo [n][k] bf16.
// 128x128 tile, BK=32, 256 threads (4 waves 2x2, 64x64 each).
// LDS rows: 128B = [hi 4 chunks][lo 4 chunks], chunk swizzle c ^ (row&7).
// ---------------------------------------------------------------------------
#define CVT1(F, H, L)                         \
  {                                           \
    unsigned short hu_ = f2bf(F);             \
    (H) = hu_;                                \
    (L) = f2bf((F) - bf2f(hu_));              \
  }

__global__ __launch_bounds__(256) void gemm_split_kernel(
    const float* __restrict__ A, const unsigned short* __restrict__ BTh,
    const unsigned short* __restrict__ BTl, const float* __restrict__ bias,
    float* __restrict__ C) {
  __shared__ unsigned short As[2][128][64];
  __shared__ unsigned short Bs[2][128][64];
  const int tid = threadIdx.x;
  const int m0 = blockIdx.x * 128, n0 = blockIdx.y * 128;
  const int srow = tid >> 1, skh = tid & 1;
  const int wave = tid >> 6, lane = tid & 63;
  const int wm = (wave >> 1) << 6, wn = (wave & 1) << 6;
  const int l15 = lane & 15, lk = lane >> 4;

  const float* pa = A + (size_t)(m0 + srow) * 1024 + skh * 16;
  const unsigned short* pbh = BTh + (size_t)(n0 + srow) * 1024 + skh * 16;
  const unsigned short* pbl = BTl + (size_t)(n0 + srow) * 1024 + skh * 16;

  f32x4 acc[4][4];
#pragma unroll
  for (int i = 0; i < 4; ++i)
#pragma unroll
    for (int j = 0; j < 4; ++j) acc[i][j] = f32x4{0.f, 0.f, 0.f, 0.f};

  float4 af0, af1, af2, af3;
  u16x8 gb0, gb1, gb2, gb3;

#define LOADG(kt)                                                         \
  {                                                                       \
    const float* p_ = pa + (kt) * 32;                                     \
    af0 = *reinterpret_cast<const float4*>(p_);                           \
    af1 = *reinterpret_cast<const float4*>(p_ + 4);                       \
    af2 = *reinterpret_cast<const float4*>(p_ + 8);                       \
    af3 = *reinterpret_cast<const float4*>(p_ + 12);                      \
    gb0 = *reinterpret_cast<const u16x8*>(pbh + (kt) * 32);               \
    gb1 = *reinterpret_cast<const u16x8*>(pbh + (kt) * 32 + 8);           \
    gb2 = *reinterpret_cast<const u16x8*>(pbl + (kt) * 32);               \
    gb3 = *reinterpret_cast<const u16x8*>(pbl + (kt) * 32 + 8);           \
  }

#define STAGE(nb)                                                              \
  {                                                                            \
    u16x8 h0, h1, l0, l1;                                                      \
    CVT1(af0.x, h0[0], l0[0]); CVT1(af0.y, h0[1], l0[1]);                      \
    CVT1(af0.z, h0[2], l0[2]); CVT1(af0.w, h0[3], l0[3]);                      \
    CVT1(af1.x, h0[4], l0[4]); CVT1(af1.y, h0[5], l0[5]);                      \
    CVT1(af1.z, h0[6], l0[6]); CVT1(af1.w, h0[7], l0[7]);                      \
    CVT1(af2.x, h1[0], l1[0]); CVT1(af2.y, h1[1], l1[1]);                      \
    CVT1(af2.z, h1[2], l1[2]); CVT1(af2.w, h1[3], l1[3]);                      \
    CVT1(af3.x, h1[4], l1[4]); CVT1(af3.y, h1[5], l1[5]);                      \
    CVT1(af3.z, h1[6], l1[6]); CVT1(af3.w, h1[7], l1[7]);                      \
    unsigned short* rowA = &As[nb][srow][0];                                   \
    const int sw_ = srow & 7;                                                  \
    *reinterpret_cast<u16x8*>(rowA + (((skh * 2 + 0) ^ sw_) << 3)) = h0;       \
    *reinterpret_cast<u16x8*>(rowA + (((skh * 2 + 1) ^ sw_) << 3)) = h1;       \
    *reinterpret_cast<u16x8*>(rowA + (((skh * 2 + 4) ^ sw_) << 3)) = l0;       \
    *reinterpret_cast<u16x8*>(rowA + (((skh * 2 + 5) ^ sw_) << 3)) = l1;       \
    unsigned short* rowB = &Bs[nb][srow][0];                                   \
    *reinterpret_cast<u16x8*>(rowB + (((skh * 2 + 0) ^ sw_) << 3)) = gb0;      \
    *reinterpret_cast<u16x8*>(rowB + (((skh * 2 + 1) ^ sw_) << 3)) = gb1;      \
    *reinterpret_cast<u16x8*>(rowB + (((skh * 2 + 4) ^ sw_) << 3)) = gb2;      \
    *reinterpret_cast<u16x8*>(rowB + (((skh * 2 + 5) ^ sw_) << 3)) = gb3;      \
  }

  LOADG(0);
  STAGE(0);
  __syncthreads();

  for (int kt = 0; kt < 32; ++kt) {
    const int cur = kt & 1;
    if (kt < 31) LOADG(kt + 1);

    bf16x8 bfh[4], bfl[4];
#pragma unroll
    for (int fn = 0; fn < 4; ++fn) {
      const int r = wn + fn * 16 + l15;
      const unsigned short* rp = &Bs[cur][r][0];
      bfh[fn] = *reinterpret_cast<const bf16x8*>(rp + (((lk) ^ (r & 7)) << 3));
      bfl[fn] =
          *reinterpret_cast<const bf16x8*>(rp + (((lk + 4) ^ (r & 7)) << 3));
    }
#pragma unroll
    for (int fm = 0; fm < 4; ++fm) {
      const int r = wm + fm * 16 + l15;
      const unsigned short* rp = &As[cur][r][0];
      bf16x8 ah = *reinterpret_cast<const bf16x8*>(rp + (((lk) ^ (r & 7)) << 3));
      bf16x8 al =
          *reinterpret_cast<const bf16x8*>(rp + (((lk + 4) ^ (r & 7)) << 3));
#pragma unroll
      for (int fn = 0; fn < 4; ++fn) {
        acc[fm][fn] = __builtin_amdgcn_mfma_f32_16x16x32_bf16(ah, bfh[fn],
                                                              acc[fm][fn], 0, 0, 0);
        acc[fm][fn] = __builtin_amdgcn_mfma_f32_16x16x32_bf16(ah, bfl[fn],
                                                              acc[fm][fn], 0, 0, 0);
        acc[fm][fn] = __builtin_amdgcn_mfma_f32_16x16x32_bf16(al, bfh[fn],
                                                              acc[fm][fn], 0, 0, 0);
      }
    }
    if (kt < 31) STAGE(cur ^ 1);
    __syncthreads();
  }

#pragma unroll
  for (int fm = 0; fm < 4; ++fm) {
    const int row = m0 + wm + fm * 16 + (lk << 2);
#pragma unroll
    for (int fn = 0; fn < 4; ++fn) {
      const int col = n0 + wn + fn * 16 + l15;
      const float bc = bias[col];
      f32x4 v = acc[fm][fn];
#pragma unroll
      for (int j = 0; j < 4; ++j) C[(size_t)(row + j) * 1024 + col] = v[j] + bc;
    }
  }
}

// ---------------------------------------------------------------------------
// wx max: blocks = 64 bh * 8 s-chunks. Per batch 16 rows: wx microtile
// (2 rows x 4 m per thread), running max.
// ---------------------------------------------------------------------------
__global__ __launch_bounds__(256) void wxmax2_kernel(
    const float* __restrict__ kproj, const float* __restrict__ proj,
    float* __restrict__ blockmax) {
  __shared__ float projT[64][128];
  __shared__ float xs[16][68];
  __shared__ float red2[256];
  const int tid = threadIdx.x;
  const int blk = blockIdx.x;
  const int c = blk & 7, bh = blk >> 3, b = bh >> 4, h = bh & 15;

  for (int i = tid; i < 8192; i += 256) {
    int m = i & 127, k = i >> 7;
    projT[k][m] = proj[m * 64 + k];
  }
  __syncthreads();

  const int sr = tid >> 4, sq = (tid & 15) << 2;
  const int r2 = tid >> 5, mg = (tid & 31) << 2;
  float gmax = -3.4e38f;

  for (int batch = 0; batch < 32; ++batch) {
    const int s0 = c * 512 + batch * 16;
    {
      const float* src = kproj + (((size_t)((b * S_ + s0 + sr) * H_ + h)) << 6) + sq;
      float4 v = *reinterpret_cast<const float4*>(src);
      xs[sr][sq + 0] = v.x * SCALE_X;
      xs[sr][sq + 1] = v.y * SCALE_X;
      xs[sr][sq + 2] = v.z * SCALE_X;
      xs[sr][sq + 3] = v.w * SCALE_X;
    }
    __syncthreads();
    f32x4 wv0 = {0, 0, 0, 0}, wv1 = {0, 0, 0, 0};
#pragma unroll 16
    for (int k = 0; k < 64; ++k) {
      f32x4 p = *reinterpret_cast<const f32x4*>(&projT[k][mg]);
      float x0 = xs[2 * r2][k], x1 = xs[2 * r2 + 1][k];
      wv0 += p * x0;
      wv1 += p * x1;
    }
    f32x4 w = wv0 > wv1 ? wv0 : wv1;  // elementwise? use fmax explicitly
    float m0 = fmaxf(fmaxf(wv0[0], wv0[1]), fmaxf(wv0[2], wv0[3]));
    float m1 = fmaxf(fmaxf(wv1[0], wv1[1]), fmaxf(wv1[2], wv1[3]));
    (void)w;
    gmax = fmaxf(gmax, fmaxf(m0, m1));
    __syncthreads();
  }
  red2[tid] = gmax;
  __syncthreads();
  for (int s = 128; s; s >>= 1) {
    if (tid < s) red2[tid] = fmaxf(red2[tid], red2[tid + s]);
    __syncthreads();
  }
  if (tid == 0) blockmax[blk] = red2[0];
}

__global__ __launch_bounds__(256) void maxreduce_kernel(
    const float* __restrict__ blockmax, float* __restrict__ stab, int n) {
  __shared__ float sm[256];
  float v = -3.4e38f;
  for (int i = threadIdx.x; i < n; i += 256) v = fmaxf(v, blockmax[i]);
  sm[threadIdx.x] = v;
  __syncthreads();
  for (int s = 128; s; s >>= 1) {
    if (threadIdx.x < s)
      sm[threadIdx.x] = fmaxf(sm[threadIdx.x], sm[threadIdx.x + s]);
    __syncthreads();
  }
  if (threadIdx.x == 0) *stab = sm[0];
}

// ---------------------------------------------------------------------------
// kv partials: blocks = 64 bh * 8 chunks (512 s each). Fused phi_k + outer
// product accumulate into kv[128][64] + k1[128] partials. No spills.
// ---------------------------------------------------------------------------
__global__ __launch_bounds__(256) void kv_f32_kernel(
    const float* __restrict__ kproj, const float* __restrict__ vproj,
    const float* __restrict__ proj, const float* __restrict__ stabp,
    float* __restrict__ kvpart) {
  __shared__ float projT[64][128];
  __shared__ float xs[16][68];
  __shared__ float vs[16][68];
  __shared__ float phis[16][128];
  __shared__ float red[16][17];
  __shared__ float diags[16];
  const int tid = threadIdx.x;
  const int blk = blockIdx.x;
  const int c = blk & 7, bh = blk >> 3, b = bh >> 4, h = bh & 15;
  const float stab = *stabp;

  for (int i = tid; i < 8192; i += 256) {
    int m = i & 127, k = i >> 7;
    projT[k][m] = proj[m * 64 + k];
  }
  __syncthreads();

  const int sr = tid >> 4, sq = (tid & 15) << 2;
  const int r2 = tid >> 5, mg = (tid & 31) << 2;
  const int mg2 = tid >> 4, dg = tid & 15;  // accum: m=8*mg2, d=4*dg

  f32x4 acc4[8];
#pragma unroll
  for (int j = 0; j < 8; ++j) acc4[j] = f32x4{0, 0, 0, 0};
  float k1a = 0.f;

  for (int batch = 0; batch < 32; ++batch) {
    const int s0 = c * 512 + batch * 16;
    {
      const size_t rb = ((size_t)((b * S_ + s0 + sr) * H_ + h)) << 6;
      float4 xv = *reinterpret_cast<const float4*>(kproj + rb + sq);
      float4 vv = *reinterpret_cast<const float4*>(vproj + rb + sq);
      xs[sr][sq + 0] = xv.x * SCALE_X;
      xs[sr][sq + 1] = xv.y * SCALE_X;
      xs[sr][sq + 2] = xv.z * SCALE_X;
      xs[sr][sq + 3] = xv.w * SCALE_X;
      *reinterpret_cast<float4*>(&vs[sr][sq]) = vv;
    }
    __syncthreads();
    {
      float4 q = *reinterpret_cast<const float4*>(&xs[sr][sq]);
      red[sr][tid & 15] = q.x * q.x + q.y * q.y + q.z * q.z + q.w * q.w;
    }
    __syncthreads();
    if (tid < 16) {
      float d = 0.f;
#pragma unroll
      for (int i = 0; i < 16; ++i) d += red[tid][i];
      diags[tid] = 0.5f * d;
    }
    __syncthreads();
    // phi
    {
      f32x4 wv0 = {0, 0, 0, 0}, wv1 = {0, 0, 0, 0};
#pragma unroll 16
      for (int k = 0; k < 64; ++k) {
        f32x4 p = *reinterpret_cast<const f32x4*>(&projT[k][mg]);
        float x0 = xs[2 * r2][k], x1 = xs[2 * r2 + 1][k];
        wv0 += p * x0;
        wv1 += p * x1;
      }
      const float e0 = diags[2 * r2] + stab, e1 = diags[2 * r2 + 1] + stab;
      f32x4 ph0, ph1;
#pragma unroll
      for (int j = 0; j < 4; ++j) {
        ph0[j] = __expf(wv0[j] - e0) * CM;
        ph1[j] = __expf(wv1[j] - e1) * CM;
      }
      *reinterpret_cast<f32x4*>(&phis[2 * r2][mg]) = ph0;
      *reinterpret_cast<f32x4*>(&phis[2 * r2 + 1][mg]) = ph1;
    }
    __syncthreads();
    // accumulate
    for (int si = 0; si < 16; ++si) {
      f32x4 va = *reinterpret_cast<const f32x4*>(&vs[si][dg << 2]);
      f32x4 p0 = *reinterpret_cast<const f32x4*>(&phis[si][mg2 << 3]);
      f32x4 p1 = *reinterpret_cast<const f32x4*>(&phis[si][(mg2 << 3) + 4]);
      acc4[0] += va * p0[0];
      acc4[1] += va * p0[1];
      acc4[2] += va * p0[2];
      acc4[3] += va * p0[3];
      acc4[4] += va * p1[0];
      acc4[5] += va * p1[1];
      acc4[6] += va * p1[2];
      acc4[7] += va * p1[3];
    }
    if (tid < 128) {
      float s = 0.f;
#pragma unroll
      for (int si = 0; si < 16; ++si) s += phis[si][tid];
      k1a += s;
    }
    __syncthreads();
  }

  float* op = kvpart + (size_t)blk * 8320;
#pragma unroll
  for (int j = 0; j < 8; ++j)
    *reinterpret_cast<f32x4*>(&op[((mg2 << 3) + j) * 64 + (dg << 2)]) = acc4[j];
  if (tid < 128) op[8192 + tid] = k1a;
}

__global__ __launch_bounds__(256) void kvreduce_kernel(
    const float* __restrict__ kvpart, unsigned short* __restrict__ kv,
    float* __restrict__ k1) {
  const int bh = blockIdx.x;
  for (int idx = threadIdx.x; idx < 8320; idx += 256) {
    float s = 0.f;
#pragma unroll
    for (int c = 0; c < 8; ++c) s += kvpart[(size_t)(bh * 8 + c) * 8320 + idx];
    if (idx < 8192)
      kv[(size_t)bh * 8192 + idx] = f2bf(s);
    else
      k1[bh * 128 + (idx - 8192)] = s;
  }
}

// ---------------------------------------------------------------------------
// qkv: blocks = 64 bh * 16 chunks (256 t). Fused phi_q (per-row max) +
// contraction with kv (bf16 LDS) + normalize -> out_h.
// ---------------------------------------------------------------------------
__global__ __launch_bounds__(256) void qkv_f32_kernel(
    const float* __restrict__ qproj, const unsigned short* __restrict__ kv,
    const float* __restrict__ k1, const float* __restrict__ proj,
    float* __restrict__ outh) {
  __shared__ float projT[64][128];
  __shared__ unsigned short kvsu[128][64];
  __shared__ float k1s[128];
  __shared__ float xs[16][68];
  __shared__ float phis[16][128];
  __shared__ float red[16][17];
  __shared__ float diags[16], rmax[16], dens[16];
  const int tid = threadIdx.x;
  const int blk = blockIdx.x;
  const int ch = blk & 15, bh = blk >> 4, b = bh >> 4, h = bh & 15;

  for (int i = tid; i < 8192; i += 256) {
    int m = i & 127, k = i >> 7;
    projT[k][m] = proj[m * 64 + k];
    kvsu[0][0 * 8192 + i] = kv[(size_t)bh * 8192 + i];  // flat copy
  }
  if (tid < 128) k1s[tid] = k1[bh * 128 + tid];
  __syncthreads();

  const int sr = tid >> 4, sq = (tid & 15) << 2;
  const int r2 = tid >> 5, mg = (tid & 31) << 2;
  // out phase: hs = m-half, rg rows pair, dg 4 d
  const int hs = (tid >> 4) & 1, rg = tid >> 5, dg = tid & 15;

  for (int batch = 0; batch < 16; ++batch) {
    const int s0 = ch * 256 + batch * 16;
    {
      const size_t rb = ((size_t)((b * S_ + s0 + sr) * H_ + h)) << 6;
      float4 xv = *reinterpret_cast<const float4*>(qproj + rb + sq);
      xs[sr][sq + 0] = xv.x * SCALE_X;
      xs[sr][sq + 1] = xv.y * SCALE_X;
      xs[sr][sq + 2] = xv.z * SCALE_X;
      xs[sr][sq + 3] = xv.w * SCALE_X;
    }
    __syncthreads();
    {
      float4 q = *reinterpret_cast<const float4*>(&xs[sr][sq]);
      red[sr][tid & 15] = q.x * q.x + q.y * q.y + q.z * q.z + q.w * q.w;
    }
    __syncthreads();
    if (tid < 16) {
      float d = 0.f;
#pragma unroll
      for (int i = 0; i < 16; ++i) d += red[tid][i];
      diags[tid] = 0.5f * d;
    }
    __syncthreads();
    // raw wx
    f32x4 wv0 = {0, 0, 0, 0}, wv1 = {0, 0, 0, 0};
#pragma unroll 16
    for (int k = 0; k < 64; ++k) {
      f32x4 p = *reinterpret_cast<const f32x4*>(&projT[k][mg]);
      float x0 = xs[2 * r2][k], x1 = xs[2 * r2 + 1][k];
      wv0 += p * x0;
      wv1 += p * x1;
    }
    *reinterpret_cast<f32x4*>(&phis[2 * r2][mg]) = wv0;
    *reinterpret_cast<f32x4*>(&phis[2 * r2 + 1][mg]) = wv1;
    __syncthreads();
    // row max
    {
      const int mc = (tid & 15) << 3;
      float mx = phis[sr][mc];
#pragma unroll
      for (int j = 1; j < 8; ++j) mx = fmaxf(mx, phis[sr][mc + j]);
      red[sr][tid & 15] = mx;
    }
    __syncthreads();
    if (tid < 16) {
      float mx = red[tid][0];
#pragma unroll
      for (int i = 1; i < 16; ++i) mx = fmaxf(mx, red[tid][i]);
      rmax[tid] = mx;
    }
    __syncthreads();
    // phi
    {
      const float e0 = diags[2 * r2] + rmax[2 * r2];
      const float e1 = diags[2 * r2 + 1] + rmax[2 * r2 + 1];
      f32x4 ph0, ph1;
#pragma unroll
      for (int j = 0; j < 4; ++j) {
        ph0[j] = __expf(wv0[j] - e0) * CM;
        ph1[j] = __expf(wv1[j] - e1) * CM;
      }
      *reinterpret_cast<f32x4*>(&phis[2 * r2][mg]) = ph0;
      *reinterpret_cast<f32x4*>(&phis[2 * r2 + 1][mg]) = ph1;
    }
    __syncthreads();
    // denom
    {
      const int mc = (tid & 15) << 3;
      float s = 0.f;
#pragma unroll
      for (int j = 0; j < 8; ++j) s += phis[sr][mc + j] * k1s[mc + j];
      red[sr][tid & 15] = s;
    }
    __syncthreads();
    if (tid < 16) {
      float s = 0.f;
#pragma unroll
      for (int i = 0; i < 16; ++i) s += red[tid][i];
      dens[tid] = 1.f / (s + 1e-6f);
    }
    __syncthreads();
    // out: acc over m-half, rows {2rg,2rg+1}, d 4dg
    {
      f32x4 a0 = {0, 0, 0, 0}, a1 = {0, 0, 0, 0};
      const int r0 = 2 * (rg & 7), r1 = r0 + 1;
      for (int mm = 0; mm < 64; ++mm) {
        const int m = hs * 64 + mm;
        uint2 kp = *reinterpret_cast<const uint2*>(&kvsu[m][dg << 2]);
        f32x4 kvv;
        kvv[0] = __uint_as_float(kp.x << 16);
        kvv[1] = __uint_as_float(kp.x & 0xFFFF0000u);
        kvv[2] = __uint_as_float(kp.y << 16);
        kvv[3] = __uint_as_float(kp.y & 0xFFFF0000u);
        a0 += kvv * phis[r0][m];
        a1 += kvv * phis[r1][m];
      }
#pragma unroll
      for (int j = 0; j < 4; ++j) {
        a0[j] += __shfl_xor(a0[j], 16);
        a1[j] += __shfl_xor(a1[j], 16);
      }
      if (hs == 0) {
        const float d0 = dens[r0], d1 = dens[r1];
        float4 o0, o1;
        o0.x = a0[0] * d0; o0.y = a0[1] * d0; o0.z = a0[2] * d0; o0.w = a0[3] * d0;
        o1.x = a1[0] * d1; o1.y = a1[1] * d1; o1.z = a1[2] * d1; o1.w = a1[3] * d1;
        const size_t ob0 = (size_t)(b * S_ + s0 + r0) * 1024 + h * 64 + (dg << 2);
        const size_t ob1 = (size_t)(b * S_ + s0 + r1) * 1024 + h * 64 + (dg << 2);
        *reinterpret_cast<float4*>(&outh[ob0]) = o0;
        *reinterpret_cast<float4*>(&outh[ob1]) = o1;
      }
    }
    __syncthreads();
  }
}

// ---------------------------------------------------------------------------
extern "C" void kernel_launch(void* const* d_in, const int* in_sizes, int n_in,
                              void* d_out, int out_size, void* d_ws,
                              size_t ws_size, hipStream_t stream) {
  const float* query = (const float*)d_in[0];
  const float* value = (const float*)d_in[1];
  const float* key   = (const float*)d_in[2];
  const float* Wq = (const float*)d_in[3];
  const float* bq = (const float*)d_in[4];
  const float* Wk = (const float*)d_in[5];
  const float* bk = (const float*)d_in[6];
  const float* Wv = (const float*)d_in[7];
  const float* bv = (const float*)d_in[8];
  const float* Wo = (const float*)d_in[9];
  const float* bo = (const float*)d_in[10];
  const float* proj = (const float*)d_in[11];
  float* out = (float*)d_out;
  float* ws = (float*)d_ws;

  float* Abuf = ws + OFF_A;
  float* Bbuf = ws + OFF_B;
  unsigned short* WTh = (unsigned short*)(ws + OFF_X);
  unsigned short* WTl = WTh + 1048576;
  float* KVP = ws + OFF_X;
  unsigned short* KV = (unsigned short*)(ws + OFF_KV);
  float* K1 = ws + OFF_K1;
  float* BMX = ws + OFF_BM;
  float* ST = ws + OFF_ST;

  dim3 gw(32, 32);
  dim3 gg(128, 8);

  // 1. k_proj
  wt_split_kernel<<<gw, 256, 0, stream>>>(Wk, WTh, WTl);
  gemm_split_kernel<<<gg, 256, 0, stream>>>(key, WTh, WTl, bk, Abuf);
  // 2. stab
  wxmax2_kernel<<<512, 256, 0, stream>>>(Abuf, proj, BMX);
  maxreduce_kernel<<<1, 256, 0, stream>>>(BMX, ST, 512);
  // 3. v_proj
  wt_split_kernel<<<gw, 256, 0, stream>>>(Wv, WTh, WTl);
  gemm_split_kernel<<<gg, 256, 0, stream>>>(value, WTh, WTl, bv, Bbuf);
  // 4. kv / k1 (KVP aliases WT region; WvT dead now)
  kv_f32_kernel<<<512, 256, 0, stream>>>(Abuf, Bbuf, proj, ST, KVP);
  kvreduce_kernel<<<64, 256, 0, stream>>>(KVP, KV, K1);
  // 5. q_proj (KVP dead after reduce)
  wt_split_kernel<<<gw, 256, 0, stream>>>(Wq, WTh, WTl);
  gemm_split_kernel<<<gg, 256, 0, stream>>>(query, WTh, WTl, bq, Abuf);
  // 6. out_h
  qkv_f32_kernel<<<1024, 256, 0, stream>>>(Abuf, KV, K1, proj, Bbuf);
  // 7. output projection
  wt_split_kernel<<<gw, 256, 0, stream>>>(Wo, WTh, WTl);
  gemm_split_kernel<<<gg, 256, 0, stream>>>(Bbuf, WTh, WTl, bo, out);
}

// Round 5
// 670.414 us; speedup vs baseline: 5.2110x; 1.4061x over previous
//
#include <hip/hip_runtime.h>
#include <hip/hip_bf16.h>

// Performer (FAVOR+) forward. Round 5: R4 structure + Vs LDS overflow fix
// (Vs[32][33] -> Vs[32][66]). B=4, S=4096, D=1024, H=16, K=64, M=128.

#define B_  4
#define S_  4096
#define H_  16

#define SCALE_X 0.3535533905932738f     // 64^-0.25
#define CM      0.08838834764831845f    // 128^-0.5

typedef __attribute__((ext_vector_type(8))) short bf16x8;
typedef __attribute__((ext_vector_type(4))) short s16x4;
typedef __attribute__((ext_vector_type(8))) unsigned short u16x8;
typedef __attribute__((ext_vector_type(4))) float f32x4;

// ---- ws layout (float units) ----
#define OFF_A    ((size_t)0)          // 16777216 : k_proj then q_proj
#define OFF_B    ((size_t)16777216)   // 16777216 : v_proj then out_h
#define OFF_X    ((size_t)33554432)   // union: WT split (1M f32) / kvpartT+k1part
#define OFF_KV   ((size_t)37814272)   // kvT hi+lo: 2*524288 ush = 524288 f32
#define OFF_K1   ((size_t)38338560)   // 64*128 f32
#define OFF_BM   ((size_t)38346752)   // 512 block maxes
#define OFF_ST   ((size_t)38347264)   // stab scalar
// total 38347265 f32 = 153.4 MB

__device__ __forceinline__ unsigned short f2bf(float x) {
  union { __hip_bfloat16 b; unsigned short u; } c;
  c.b = __float2bfloat16(x);
  return c.u;
}
__device__ __forceinline__ float bf2f(unsigned short u) {
  union { float f; unsigned int i; } c;
  c.i = ((unsigned int)u) << 16;
  return c.f;
}

#define MFMA_ ( __builtin_amdgcn_mfma_f32_16x16x32_bf16 )
#define MFMA3(ACC, AH, AL, BH, BL)                                    \
  {                                                                   \
    ACC = __builtin_amdgcn_mfma_f32_16x16x32_bf16(AH, BH, ACC, 0,0,0);\
    ACC = __builtin_amdgcn_mfma_f32_16x16x32_bf16(AH, BL, ACC, 0,0,0);\
    ACC = __builtin_amdgcn_mfma_f32_16x16x32_bf16(AL, BH, ACC, 0,0,0);\
  }

// load P-operand fragment (B for wx): lane supplies P[m][kb..kb+7] split hi/lo
__device__ __forceinline__ void load_pfrag(const float* __restrict__ proj, int m,
                                           int kb, bf16x8* ph, bf16x8* pl) {
  const float* p = proj + m * 64 + kb;
  float4 a = *reinterpret_cast<const float4*>(p);
  float4 b = *reinterpret_cast<const float4*>(p + 4);
  float v[8] = {a.x, a.y, a.z, a.w, b.x, b.y, b.z, b.w};
  bf16x8 h, l;
#pragma unroll
  for (int j = 0; j < 8; ++j) {
    unsigned short hu = f2bf(v[j]);
    h[j] = (short)hu;
    l[j] = (short)f2bf(v[j] - bf2f(hu));
  }
  *ph = h;
  *pl = l;
}

// Stage one X row-chunk: scale, hi/lo split, chunk-XOR LDS write (+opt diag).
// Requires in scope: srow, q8, xc, tid, Xh, Xl (and diags if WANT_DIAG).
#define STAGE_X(PTR, WANT_DIAG)                                           \
  {                                                                       \
    float4 a_ = *reinterpret_cast<const float4*>(PTR);                    \
    float4 b_ = *reinterpret_cast<const float4*>((PTR) + 4);              \
    float v_[8] = {a_.x * SCALE_X, a_.y * SCALE_X, a_.z * SCALE_X,        \
                   a_.w * SCALE_X, b_.x * SCALE_X, b_.y * SCALE_X,        \
                   b_.z * SCALE_X, b_.w * SCALE_X};                       \
    u16x8 hh_, ll_;                                                       \
    float sq_ = 0.f;                                                      \
    _Pragma("unroll") for (int j = 0; j < 8; ++j) {                       \
      sq_ += v_[j] * v_[j];                                               \
      unsigned short hu_ = f2bf(v_[j]);                                   \
      hh_[j] = hu_;                                                       \
      ll_[j] = f2bf(v_[j] - bf2f(hu_));                                   \
    }                                                                     \
    *reinterpret_cast<u16x8*>(&Xh[srow][xc]) = hh_;                       \
    *reinterpret_cast<u16x8*>(&Xl[srow][xc]) = ll_;                       \
    if (WANT_DIAG) {                                                      \
      sq_ += __shfl_xor(sq_, 1);                                          \
      sq_ += __shfl_xor(sq_, 2);                                          \
      sq_ += __shfl_xor(sq_, 4);                                          \
      if ((tid & 7) == 0) diags[srow] = 0.5f * sq_;                       \
    }                                                                     \
  }

// wx MFMA block: 2 st x 2 ks x 2 mtl x MFMA3. Needs l15, lg, ph, pl, Xh, Xl.
#define WX_COMPUTE(WX)                                                       \
  _Pragma("unroll") for (int st_ = 0; st_ < 2; ++st_)                        \
  _Pragma("unroll") for (int ks_ = 0; ks_ < 2; ++ks_) {                      \
    const int rr_ = st_ * 16 + l15;                                          \
    const int cc_ = ((ks_ * 4 + lg) ^ (l15 & 7)) << 3;                       \
    bf16x8 xh_ = *reinterpret_cast<const bf16x8*>(&Xh[rr_][cc_]);            \
    bf16x8 xl_ = *reinterpret_cast<const bf16x8*>(&Xl[rr_][cc_]);            \
    _Pragma("unroll") for (int mtl_ = 0; mtl_ < 2; ++mtl_)                   \
        MFMA3(WX[st_][mtl_], xh_, xl_, ph[mtl_][ks_], pl[mtl_][ks_]);        \
  }

// ---------------------------------------------------------------------------
// Weight transform: W[1024 k][1024 n] f32 -> WT_hi/WT_lo [n][k] bf16.
// ---------------------------------------------------------------------------
__global__ __launch_bounds__(256) void wt_split_kernel(
    const float* __restrict__ W, unsigned short* __restrict__ Th,
    unsigned short* __restrict__ Tl) {
  __shared__ float t[32][33];
  const int tx = threadIdx.x & 31, ty = threadIdx.x >> 5;
  const int k0 = blockIdx.x * 32, n0 = blockIdx.y * 32;
#pragma unroll
  for (int i = 0; i < 4; ++i)
    t[ty + 8 * i][tx] = W[(size_t)(k0 + ty + 8 * i) * 1024 + n0 + tx];
  __syncthreads();
#pragma unroll
  for (int i = 0; i < 4; ++i) {
    float v = t[tx][ty + 8 * i];
    unsigned short hu = f2bf(v);
    unsigned short lu = f2bf(v - bf2f(hu));
    size_t o = (size_t)(n0 + ty + 8 * i) * 1024 + k0 + tx;
    Th[o] = hu;
    Tl[o] = lu;
  }
}

// ---------------------------------------------------------------------------
// Split-bf16 MFMA GEMM (unchanged, passed R2).
// ---------------------------------------------------------------------------
#define CVT1(F, H, L)                         \
  {                                           \
    unsigned short hu_ = f2bf(F);             \
    (H) = hu_;                                \
    (L) = f2bf((F) - bf2f(hu_));              \
  }

__global__ __launch_bounds__(256) void gemm_split_kernel(
    const float* __restrict__ A, const unsigned short* __restrict__ BTh,
    const unsigned short* __restrict__ BTl, const float* __restrict__ bias,
    float* __restrict__ C) {
  __shared__ unsigned short As[2][128][64];
  __shared__ unsigned short Bs[2][128][64];
  const int tid = threadIdx.x;
  const int m0 = blockIdx.x * 128, n0 = blockIdx.y * 128;
  const int srow = tid >> 1, skh = tid & 1;
  const int wave = tid >> 6, lane = tid & 63;
  const int wm = (wave >> 1) << 6, wn = (wave & 1) << 6;
  const int l15 = lane & 15, lk = lane >> 4;

  const float* pa = A + (size_t)(m0 + srow) * 1024 + skh * 16;
  const unsigned short* pbh = BTh + (size_t)(n0 + srow) * 1024 + skh * 16;
  const unsigned short* pbl = BTl + (size_t)(n0 + srow) * 1024 + skh * 16;

  f32x4 acc[4][4];
#pragma unroll
  for (int i = 0; i < 4; ++i)
#pragma unroll
    for (int j = 0; j < 4; ++j) acc[i][j] = f32x4{0.f, 0.f, 0.f, 0.f};

  float4 af0, af1, af2, af3;
  u16x8 gb0, gb1, gb2, gb3;

#define LOADG(kt)                                                         \
  {                                                                       \
    const float* p_ = pa + (kt) * 32;                                     \
    af0 = *reinterpret_cast<const float4*>(p_);                           \
    af1 = *reinterpret_cast<const float4*>(p_ + 4);                       \
    af2 = *reinterpret_cast<const float4*>(p_ + 8);                       \
    af3 = *reinterpret_cast<const float4*>(p_ + 12);                      \
    gb0 = *reinterpret_cast<const u16x8*>(pbh + (kt) * 32);               \
    gb1 = *reinterpret_cast<const u16x8*>(pbh + (kt) * 32 + 8);           \
    gb2 = *reinterpret_cast<const u16x8*>(pbl + (kt) * 32);               \
    gb3 = *reinterpret_cast<const u16x8*>(pbl + (kt) * 32 + 8);           \
  }

#define STAGE(nb)                                                              \
  {                                                                            \
    u16x8 h0, h1, l0, l1;                                                      \
    CVT1(af0.x, h0[0], l0[0]); CVT1(af0.y, h0[1], l0[1]);                      \
    CVT1(af0.z, h0[2], l0[2]); CVT1(af0.w, h0[3], l0[3]);                      \
    CVT1(af1.x, h0[4], l0[4]); CVT1(af1.y, h0[5], l0[5]);                      \
    CVT1(af1.z, h0[6], l0[6]); CVT1(af1.w, h0[7], l0[7]);                      \
    CVT1(af2.x, h1[0], l1[0]); CVT1(af2.y, h1[1], l1[1]);                      \
    CVT1(af2.z, h1[2], l1[2]); CVT1(af2.w, h1[3], l1[3]);                      \
    CVT1(af3.x, h1[4], l1[4]); CVT1(af3.y, h1[5], l1[5]);                      \
    CVT1(af3.z, h1[6], l1[6]); CVT1(af3.w, h1[7], l1[7]);                      \
    unsigned short* rowA = &As[nb][srow][0];                                   \
    const int sw_ = srow & 7;                                                  \
    *reinterpret_cast<u16x8*>(rowA + (((skh * 2 + 0) ^ sw_) << 3)) = h0;       \
    *reinterpret_cast<u16x8*>(rowA + (((skh * 2 + 1) ^ sw_) << 3)) = h1;       \
    *reinterpret_cast<u16x8*>(rowA + (((skh * 2 + 4) ^ sw_) << 3)) = l0;       \
    *reinterpret_cast<u16x8*>(rowA + (((skh * 2 + 5) ^ sw_) << 3)) = l1;       \
    unsigned short* rowB = &Bs[nb][srow][0];                                   \
    *reinterpret_cast<u16x8*>(rowB + (((skh * 2 + 0) ^ sw_) << 3)) = gb0;      \
    *reinterpret_cast<u16x8*>(rowB + (((skh * 2 + 1) ^ sw_) << 3)) = gb1;      \
    *reinterpret_cast<u16x8*>(rowB + (((skh * 2 + 4) ^ sw_) << 3)) = gb2;      \
    *reinterpret_cast<u16x8*>(rowB + (((skh * 2 + 5) ^ sw_) << 3)) = gb3;      \
  }

  LOADG(0);
  STAGE(0);
  __syncthreads();

  for (int kt = 0; kt < 32; ++kt) {
    const int cur = kt & 1;
    if (kt < 31) LOADG(kt + 1);

    bf16x8 bfh[4], bfl[4];
#pragma unroll
    for (int fn = 0; fn < 4; ++fn) {
      const int r = wn + fn * 16 + l15;
      const unsigned short* rp = &Bs[cur][r][0];
      bfh[fn] = *reinterpret_cast<const bf16x8*>(rp + (((lk) ^ (r & 7)) << 3));
      bfl[fn] =
          *reinterpret_cast<const bf16x8*>(rp + (((lk + 4) ^ (r & 7)) << 3));
    }
#pragma unroll
    for (int fm = 0; fm < 4; ++fm) {
      const int r = wm + fm * 16 + l15;
      const unsigned short* rp = &As[cur][r][0];
      bf16x8 ah = *reinterpret_cast<const bf16x8*>(rp + (((lk) ^ (r & 7)) << 3));
      bf16x8 al =
          *reinterpret_cast<const bf16x8*>(rp + (((lk + 4) ^ (r & 7)) << 3));
#pragma unroll
      for (int fn = 0; fn < 4; ++fn) {
        acc[fm][fn] = MFMA_(ah, bfh[fn], acc[fm][fn], 0, 0, 0);
        acc[fm][fn] = MFMA_(ah, bfl[fn], acc[fm][fn], 0, 0, 0);
        acc[fm][fn] = MFMA_(al, bfh[fn], acc[fm][fn], 0, 0, 0);
      }
    }
    if (kt < 31) STAGE(cur ^ 1);
    __syncthreads();
  }

#pragma unroll
  for (int fm = 0; fm < 4; ++fm) {
    const int row = m0 + wm + fm * 16 + (lk << 2);
#pragma unroll
    for (int fn = 0; fn < 4; ++fn) {
      const int col = n0 + wn + fn * 16 + l15;
      const float bc = bias[col];
      f32x4 v = acc[fm][fn];
#pragma unroll
      for (int j = 0; j < 4; ++j) C[(size_t)(row + j) * 1024 + col] = v[j] + bc;
    }
  }
}

// ---------------------------------------------------------------------------
// wxmax: global max of wx_k via MFMA. 512 blocks x 512 flat rows.
// ---------------------------------------------------------------------------
__global__ __launch_bounds__(256) void wxmax_mfma_kernel(
    const float* __restrict__ kproj, const float* __restrict__ proj,
    float* __restrict__ blockmax) {
  __shared__ unsigned short Xh[32][64], Xl[32][64];
  __shared__ float diags[32];  // unused (STAGE_X with WANT_DIAG=false)
  __shared__ float redw[4];
  const int tid = threadIdx.x, blk = blockIdx.x;
  const int lane = tid & 63, w = tid >> 6;
  const int l15 = lane & 15, lg = lane >> 4;
  (void)diags;

  bf16x8 ph[2][2], pl[2][2];
#pragma unroll
  for (int mtl = 0; mtl < 2; ++mtl)
#pragma unroll
    for (int ks = 0; ks < 2; ++ks)
      load_pfrag(proj, (2 * w + mtl) * 16 + l15, ks * 32 + lg * 8,
                 &ph[mtl][ks], &pl[mtl][ks]);

  float gmax = -3.4e38f;
  const int srow = tid >> 3, q8 = (tid & 7) << 3;
  const int xc = ((q8 >> 3) ^ (srow & 7)) << 3;

  for (int batch = 0; batch < 16; ++batch) {
    const int row0 = blk * 512 + batch * 32;
    STAGE_X(kproj + (size_t)(row0 + srow) * 64 + q8, false);
    __syncthreads();
    f32x4 wx[2][2];
#pragma unroll
    for (int st = 0; st < 2; ++st)
#pragma unroll
      for (int mtl = 0; mtl < 2; ++mtl) wx[st][mtl] = f32x4{0, 0, 0, 0};
    WX_COMPUTE(wx);
#pragma unroll
    for (int st = 0; st < 2; ++st)
#pragma unroll
      for (int mtl = 0; mtl < 2; ++mtl)
#pragma unroll
        for (int r = 0; r < 4; ++r) gmax = fmaxf(gmax, wx[st][mtl][r]);
    __syncthreads();
  }
#pragma unroll
  for (int off = 32; off; off >>= 1) gmax = fmaxf(gmax, __shfl_xor(gmax, off));
  if (lane == 0) redw[w] = gmax;
  __syncthreads();
  if (tid == 0)
    blockmax[blk] = fmaxf(fmaxf(redw[0], redw[1]), fmaxf(redw[2], redw[3]));
}

__global__ __launch_bounds__(256) void maxreduce_kernel(
    const float* __restrict__ blockmax, float* __restrict__ stab, int n) {
  __shared__ float sm[256];
  float v = -3.4e38f;
  for (int i = threadIdx.x; i < n; i += 256) v = fmaxf(v, blockmax[i]);
  sm[threadIdx.x] = v;
  __syncthreads();
  for (int s = 128; s; s >>= 1) {
    if (threadIdx.x < s)
      sm[threadIdx.x] = fmaxf(sm[threadIdx.x], sm[threadIdx.x + s]);
    __syncthreads();
  }
  if (threadIdx.x == 0) *stab = sm[0];
}

// ---------------------------------------------------------------------------
// kv: kv[m][d] = sum_s phi_k[s][m] V[s][d], plus k1[m] = sum_s phi_k[s][m].
// blocks = 64 bh * 8 chunks of 512 s. phi via wx MFMA; phi transposed through
// LDS (phiT[m][s]); V kept f32 in LDS (stride 66: 2-way banks = free),
// B-frags via scalar reads + in-register hi/lo split.
// ---------------------------------------------------------------------------
__global__ __launch_bounds__(256) void kv_mfma_kernel(
    const float* __restrict__ kproj, const float* __restrict__ vproj,
    const float* __restrict__ proj, const float* __restrict__ stabp,
    float* __restrict__ kvpartT, float* __restrict__ k1part) {
  __shared__ unsigned short Xh[32][64], Xl[32][64];
  __shared__ float Vs[32][66];   // FIX: was [32][33] -> OOB into phiTh (NaN)
  __shared__ unsigned short phiTh[128][40], phiTl[128][40];
  __shared__ float diags[32];
  const int tid = threadIdx.x, blk = blockIdx.x;
  const int c = blk & 7, bh = blk >> 3, b = bh >> 4, h = bh & 15;
  const int lane = tid & 63, w = tid >> 6;
  const int l15 = lane & 15, lg = lane >> 4;
  const float stab = *stabp;

  bf16x8 ph[2][2], pl[2][2];
#pragma unroll
  for (int mtl = 0; mtl < 2; ++mtl)
#pragma unroll
    for (int ks = 0; ks < 2; ++ks)
      load_pfrag(proj, (2 * w + mtl) * 16 + l15, ks * 32 + lg * 8,
                 &ph[mtl][ks], &pl[mtl][ks]);

  f32x4 akv[2][4];
#pragma unroll
  for (int i = 0; i < 2; ++i)
#pragma unroll
    for (int j = 0; j < 4; ++j) akv[i][j] = f32x4{0, 0, 0, 0};
  float k1acc[2] = {0.f, 0.f};

  const int srow = tid >> 3, q8 = (tid & 7) << 3;
  const int xc = ((q8 >> 3) ^ (srow & 7)) << 3;

  for (int batch = 0; batch < 16; ++batch) {
    const int s0 = c * 512 + batch * 32;
    const size_t rb = (((size_t)(b * S_ + s0 + srow) * H_ + h)) << 6;
    STAGE_X(kproj + rb + q8, true);
    {
      float4 va = *reinterpret_cast<const float4*>(vproj + rb + q8);
      float4 vb = *reinterpret_cast<const float4*>(vproj + rb + q8 + 4);
      Vs[srow][q8 + 0] = va.x; Vs[srow][q8 + 1] = va.y;
      Vs[srow][q8 + 2] = va.z; Vs[srow][q8 + 3] = va.w;
      Vs[srow][q8 + 4] = vb.x; Vs[srow][q8 + 5] = vb.y;
      Vs[srow][q8 + 6] = vb.z; Vs[srow][q8 + 7] = vb.w;
    }
    __syncthreads();  // bar1

    // wx MFMA
    f32x4 wx[2][2];
#pragma unroll
    for (int st = 0; st < 2; ++st)
#pragma unroll
      for (int mtl = 0; mtl < 2; ++mtl) wx[st][mtl] = f32x4{0, 0, 0, 0};
    WX_COMPUTE(wx);

    // phi + phiT write + k1
#pragma unroll
    for (int st = 0; st < 2; ++st)
#pragma unroll
      for (int mtl = 0; mtl < 2; ++mtl) {
        const int m = (2 * w + mtl) * 16 + l15;
        s16x4 hv, lv;
        float psum = 0.f;
#pragma unroll
        for (int r = 0; r < 4; ++r) {
          const int s = st * 16 + lg * 4 + r;
          float p = __expf(wx[st][mtl][r] - diags[s] - stab) * CM;
          psum += p;
          unsigned short hu = f2bf(p);
          hv[r] = (short)hu;
          lv[r] = (short)f2bf(p - bf2f(hu));
        }
        k1acc[mtl] += psum;
        *reinterpret_cast<s16x4*>(&phiTh[m][st * 16 + lg * 4]) = hv;
        *reinterpret_cast<s16x4*>(&phiTl[m][st * 16 + lg * 4]) = lv;
      }
    __syncthreads();  // bar2

    // kv contraction: A = phiT[m][s] (contiguous), B = V[s][d] (scalar gather)
    bf16x8 pah[2], pal[2];
#pragma unroll
    for (int mtl = 0; mtl < 2; ++mtl) {
      pah[mtl] = *reinterpret_cast<const bf16x8*>(
          &phiTh[(2 * w + mtl) * 16 + l15][lg * 8]);
      pal[mtl] = *reinterpret_cast<const bf16x8*>(
          &phiTl[(2 * w + mtl) * 16 + l15][lg * 8]);
    }
#pragma unroll
    for (int dt = 0; dt < 4; ++dt) {
      bf16x8 bvh, bvl;
#pragma unroll
      for (int j = 0; j < 8; ++j) {
        float v = Vs[lg * 8 + j][dt * 16 + l15];
        unsigned short hu = f2bf(v);
        bvh[j] = (short)hu;
        bvl[j] = (short)f2bf(v - bf2f(hu));
      }
#pragma unroll
      for (int mtl = 0; mtl < 2; ++mtl)
        MFMA3(akv[mtl][dt], pah[mtl], pal[mtl], bvh, bvl);
    }
    __syncthreads();  // bar3
  }

#pragma unroll
  for (int mtl = 0; mtl < 2; ++mtl) {
#pragma unroll
    for (int dt = 0; dt < 4; ++dt) {
      const int d = dt * 16 + l15, m0 = (2 * w + mtl) * 16 + lg * 4;
      *reinterpret_cast<f32x4*>(&kvpartT[(size_t)blk * 8192 + d * 128 + m0]) =
          akv[mtl][dt];
    }
    float kk = k1acc[mtl];
    kk += __shfl_xor(kk, 16);
    kk += __shfl_xor(kk, 32);
    if (lane < 16) k1part[blk * 128 + (2 * w + mtl) * 16 + lane] = kk;
  }
}

__global__ __launch_bounds__(256) void kvreduce_kernel(
    const float* __restrict__ kvpartT, const float* __restrict__ k1part,
    unsigned short* __restrict__ kvTh, unsigned short* __restrict__ kvTl,
    float* __restrict__ k1) {
  const int bh = blockIdx.x;
  for (int i = threadIdx.x; i < 8192; i += 256) {
    float s = 0.f;
#pragma unroll
    for (int c = 0; c < 8; ++c) s += kvpartT[(size_t)(bh * 8 + c) * 8192 + i];
    unsigned short hu = f2bf(s);
    kvTh[(size_t)bh * 8192 + i] = hu;
    kvTl[(size_t)bh * 8192 + i] = f2bf(s - bf2f(hu));
  }
  if (threadIdx.x < 128) {
    float s = 0.f;
#pragma unroll
    for (int c = 0; c < 8; ++c) s += k1part[(bh * 8 + c) * 128 + threadIdx.x];
    k1[bh * 128 + threadIdx.x] = s;
  }
}

// ---------------------------------------------------------------------------
// qkv: phi_q (per-row max) -> out^T[d][s] = sum_m kvT[d][m] phi[s][m] / denom.
// blocks = 64 bh * 16 chunks of 256 t. phi stored [s][m] chunk-XOR, read as
// contiguous b128 B-frags. kvT A-frags live in registers (global, L2-hot).
// ---------------------------------------------------------------------------
__global__ __launch_bounds__(256) void qkv_mfma_kernel(
    const float* __restrict__ qproj, const unsigned short* __restrict__ kvTh,
    const unsigned short* __restrict__ kvTl, const float* __restrict__ k1g,
    const float* __restrict__ proj, float* __restrict__ outh) {
  __shared__ unsigned short Xh[32][64], Xl[32][64];
  __shared__ unsigned short Ph[32][128], Pl[32][128];
  __shared__ float k1s[128];
  __shared__ float diags[32];
  __shared__ float rmaxp[4][32];
  __shared__ float denp[4][32];
  const int tid = threadIdx.x, blk = blockIdx.x;
  const int ch = blk & 15, bh = blk >> 4, b = bh >> 4, h = bh & 15;
  const int lane = tid & 63, w = tid >> 6;
  const int l15 = lane & 15, lg = lane >> 4;

  bf16x8 ph[2][2], pl[2][2];
#pragma unroll
  for (int mtl = 0; mtl < 2; ++mtl)
#pragma unroll
    for (int ks = 0; ks < 2; ++ks)
      load_pfrag(proj, (2 * w + mtl) * 16 + l15, ks * 32 + lg * 8,
                 &ph[mtl][ks], &pl[mtl][ks]);

  // kvT A-fragments (constant per block): A[d = w*16+l15][m contiguous]
  bf16x8 kah[4], kal[4];
#pragma unroll
  for (int ks = 0; ks < 4; ++ks) {
    const size_t o = (size_t)bh * 8192 + (w * 16 + l15) * 128 + ks * 32 + lg * 8;
    kah[ks] = *reinterpret_cast<const bf16x8*>(kvTh + o);
    kal[ks] = *reinterpret_cast<const bf16x8*>(kvTl + o);
  }
  if (tid < 128) k1s[tid] = k1g[bh * 128 + tid];

  const int srow = tid >> 3, q8 = (tid & 7) << 3;
  const int xc = ((q8 >> 3) ^ (srow & 7)) << 3;

  for (int batch = 0; batch < 8; ++batch) {
    const int s0 = ch * 256 + batch * 32;
    const size_t rb = (((size_t)(b * S_ + s0 + srow) * H_ + h)) << 6;
    STAGE_X(qproj + rb + q8, true);
    __syncthreads();  // bar1

    // wx MFMA
    f32x4 wx[2][2];
#pragma unroll
    for (int st = 0; st < 2; ++st)
#pragma unroll
      for (int mtl = 0; mtl < 2; ++mtl) wx[st][mtl] = f32x4{0, 0, 0, 0};
    WX_COMPUTE(wx);

    // wave-local row max over this wave's 32 m
#pragma unroll
    for (int st = 0; st < 2; ++st)
#pragma unroll
      for (int r = 0; r < 4; ++r) {
        float v = fmaxf(wx[st][0][r], wx[st][1][r]);
        v = fmaxf(v, __shfl_xor(v, 1));
        v = fmaxf(v, __shfl_xor(v, 2));
        v = fmaxf(v, __shfl_xor(v, 4));
        v = fmaxf(v, __shfl_xor(v, 8));
        if (l15 == 0) rmaxp[w][st * 16 + lg * 4 + r] = v;
      }
    __syncthreads();  // bar2

    // phi + swizzled [s][m] write + denom partials
#pragma unroll
    for (int st = 0; st < 2; ++st) {
      float off[4];
#pragma unroll
      for (int r = 0; r < 4; ++r) {
        const int s = st * 16 + lg * 4 + r;
        float rmx = fmaxf(fmaxf(rmaxp[0][s], rmaxp[1][s]),
                          fmaxf(rmaxp[2][s], rmaxp[3][s]));
        off[r] = rmx + diags[s];
      }
      float den[4] = {0.f, 0.f, 0.f, 0.f};
#pragma unroll
      for (int mtl = 0; mtl < 2; ++mtl) {
        const int m = (2 * w + mtl) * 16 + l15;
        const float k1v = k1s[m];
#pragma unroll
        for (int r = 0; r < 4; ++r) {
          const int s = st * 16 + lg * 4 + r;
          float p = __expf(wx[st][mtl][r] - off[r]) * CM;
          den[r] += p * k1v;
          unsigned short hu = f2bf(p);
          const int cw = ((((m >> 3) ^ (s & 7)) << 3) | (m & 7));
          Ph[s][cw] = hu;
          Pl[s][cw] = f2bf(p - bf2f(hu));
        }
      }
#pragma unroll
      for (int r = 0; r < 4; ++r) {
        float v = den[r];
        v += __shfl_xor(v, 1);
        v += __shfl_xor(v, 2);
        v += __shfl_xor(v, 4);
        v += __shfl_xor(v, 8);
        if (l15 == 0) denp[w][st * 16 + lg * 4 + r] = v;
      }
    }
    __syncthreads();  // bar3

    // PV: out^T[d][s] = sum_m kvT[d][m] * phi[s][m]
#pragma unroll
    for (int st = 0; st < 2; ++st) {
      f32x4 od = {0.f, 0.f, 0.f, 0.f};
#pragma unroll
      for (int ks = 0; ks < 4; ++ks) {
        const int cc = ((ks * 4 + lg) ^ (l15 & 7)) << 3;
        bf16x8 bph = *reinterpret_cast<const bf16x8*>(&Ph[st * 16 + l15][cc]);
        bf16x8 bpl = *reinterpret_cast<const bf16x8*>(&Pl[st * 16 + l15][cc]);
        MFMA3(od, kah[ks], kal[ks], bph, bpl);
      }
      const int s = st * 16 + l15;
      const float dens =
          1.f / (denp[0][s] + denp[1][s] + denp[2][s] + denp[3][s] + 1e-6f);
      f32x4 o = od * dens;
      *reinterpret_cast<f32x4*>(
          &outh[(size_t)(b * S_ + s0 + s) * 1024 + h * 64 + w * 16 + lg * 4]) = o;
    }
    __syncthreads();  // bar4: protect X/Ph overwrite next batch
  }
}

// ---------------------------------------------------------------------------
extern "C" void kernel_launch(void* const* d_in, const int* in_sizes, int n_in,
                              void* d_out, int out_size, void* d_ws,
                              size_t ws_size, hipStream_t stream) {
  const float* query = (const float*)d_in[0];
  const float* value = (const float*)d_in[1];
  const float* key   = (const float*)d_in[2];
  const float* Wq = (const float*)d_in[3];
  const float* bq = (const float*)d_in[4];
  const float* Wk = (const float*)d_in[5];
  const float* bk = (const float*)d_in[6];
  const float* Wv = (const float*)d_in[7];
  const float* bv = (const float*)d_in[8];
  const float* Wo = (const float*)d_in[9];
  const float* bo = (const float*)d_in[10];
  const float* proj = (const float*)d_in[11];
  float* out = (float*)d_out;
  float* ws = (float*)d_ws;

  float* Abuf = ws + OFF_A;
  float* Bbuf = ws + OFF_B;
  unsigned short* WTh = (unsigned short*)(ws + OFF_X);
  unsigned short* WTl = WTh + 1048576;
  float* KVPT = ws + OFF_X;
  float* K1P = ws + OFF_X + 4194304;
  unsigned short* KVTh = (unsigned short*)(ws + OFF_KV);
  unsigned short* KVTl = KVTh + 524288;
  float* K1 = ws + OFF_K1;
  float* BMX = ws + OFF_BM;
  float* ST = ws + OFF_ST;

  dim3 gw(32, 32);
  dim3 gg(128, 8);

  // 1. k_proj
  wt_split_kernel<<<gw, 256, 0, stream>>>(Wk, WTh, WTl);
  gemm_split_kernel<<<gg, 256, 0, stream>>>(key, WTh, WTl, bk, Abuf);
  // 2. stab
  wxmax_mfma_kernel<<<512, 256, 0, stream>>>(Abuf, proj, BMX);
  maxreduce_kernel<<<1, 256, 0, stream>>>(BMX, ST, 512);
  // 3. v_proj
  wt_split_kernel<<<gw, 256, 0, stream>>>(Wv, WTh, WTl);
  gemm_split_kernel<<<gg, 256, 0, stream>>>(value, WTh, WTl, bv, Bbuf);
  // 4. kv / k1
  kv_mfma_kernel<<<512, 256, 0, stream>>>(Abuf, Bbuf, proj, ST, KVPT, K1P);
  kvreduce_kernel<<<64, 256, 0, stream>>>(KVPT, K1P, KVTh, KVTl, K1);
  // 5. q_proj (KVP dead after reduce)
  wt_split_kernel<<<gw, 256, 0, stream>>>(Wq, WTh, WTl);
  gemm_split_kernel<<<gg, 256, 0, stream>>>(query, WTh, WTl, bq, Abuf);
  // 6. out_h
  qkv_mfma_kernel<<<1024, 256, 0, stream>>>(Abuf, KVTh, KVTl, K1, proj, Bbuf);
  // 7. output projection
  wt_split_kernel<<<gw, 256, 0, stream>>>(Wo, WTh, WTl);
  gemm_split_kernel<<<gg, 256, 0, stream>>>(Bbuf, WTh, WTl, bo, out);
}

// Round 6
// 566.841 us; speedup vs baseline: 6.1631x; 1.1827x over previous
//
#include <hip/hip_runtime.h>
#include <hip/hip_bf16.h>

// Performer (FAVOR+) forward. Round 6: single-pass fp16 MFMA GEMMs
// (3x less MFMA work than split-bf16) + conflict-free BK=64 LDS layout.
// Middle section (split-bf16 MFMA) unchanged from R5 (passed).
// B=4, S=4096, D=1024, H=16, K=64, M=128.

#define B_  4
#define S_  4096
#define H_  16

#define SCALE_X 0.3535533905932738f     // 64^-0.25
#define CM      0.08838834764831845f    // 128^-0.5

typedef __attribute__((ext_vector_type(8))) short bf16x8;
typedef __attribute__((ext_vector_type(4))) short s16x4;
typedef __attribute__((ext_vector_type(8))) unsigned short u16x8;
typedef __attribute__((ext_vector_type(8))) _Float16 f16x8;
typedef __attribute__((ext_vector_type(4))) float f32x4;

// ---- ws layout (float units) ----
#define OFF_A    ((size_t)0)          // 16777216 : k_proj then q_proj
#define OFF_B    ((size_t)16777216)   // 16777216 : v_proj then out_h
#define OFF_X    ((size_t)33554432)   // union: WT fp16 (512K f32) / kvpartT+k1part
#define OFF_KV   ((size_t)37814272)   // kvT hi+lo: 2*524288 ush = 524288 f32
#define OFF_K1   ((size_t)38338560)   // 64*128 f32
#define OFF_BM   ((size_t)38346752)   // 512 block maxes
#define OFF_ST   ((size_t)38347264)   // stab scalar
// total 38347265 f32 = 153.4 MB

__device__ __forceinline__ unsigned short f2bf(float x) {
  union { __hip_bfloat16 b; unsigned short u; } c;
  c.b = __float2bfloat16(x);
  return c.u;
}
__device__ __forceinline__ float bf2f(unsigned short u) {
  union { float f; unsigned int i; } c;
  c.i = ((unsigned int)u) << 16;
  return c.f;
}

#define MFMA_ ( __builtin_amdgcn_mfma_f32_16x16x32_bf16 )
#define MFMA3(ACC, AH, AL, BH, BL)                                    \
  {                                                                   \
    ACC = __builtin_amdgcn_mfma_f32_16x16x32_bf16(AH, BH, ACC, 0,0,0);\
    ACC = __builtin_amdgcn_mfma_f32_16x16x32_bf16(AH, BL, ACC, 0,0,0);\
    ACC = __builtin_amdgcn_mfma_f32_16x16x32_bf16(AL, BH, ACC, 0,0,0);\
  }

// load P-operand fragment (B for wx): lane supplies P[m][kb..kb+7] split hi/lo
__device__ __forceinline__ void load_pfrag(const float* __restrict__ proj, int m,
                                           int kb, bf16x8* ph, bf16x8* pl) {
  const float* p = proj + m * 64 + kb;
  float4 a = *reinterpret_cast<const float4*>(p);
  float4 b = *reinterpret_cast<const float4*>(p + 4);
  float v[8] = {a.x, a.y, a.z, a.w, b.x, b.y, b.z, b.w};
  bf16x8 h, l;
#pragma unroll
  for (int j = 0; j < 8; ++j) {
    unsigned short hu = f2bf(v[j]);
    h[j] = (short)hu;
    l[j] = (short)f2bf(v[j] - bf2f(hu));
  }
  *ph = h;
  *pl = l;
}

// Stage one X row-chunk: scale, hi/lo split, chunk-XOR LDS write (+opt diag).
#define STAGE_X(PTR, WANT_DIAG)                                           \
  {                                                                       \
    float4 a_ = *reinterpret_cast<const float4*>(PTR);                    \
    float4 b_ = *reinterpret_cast<const float4*>((PTR) + 4);              \
    float v_[8] = {a_.x * SCALE_X, a_.y * SCALE_X, a_.z * SCALE_X,        \
                   a_.w * SCALE_X, b_.x * SCALE_X, b_.y * SCALE_X,        \
                   b_.z * SCALE_X, b_.w * SCALE_X};                       \
    u16x8 hh_, ll_;                                                       \
    float sq_ = 0.f;                                                      \
    _Pragma("unroll") for (int j = 0; j < 8; ++j) {                       \
      sq_ += v_[j] * v_[j];                                               \
      unsigned short hu_ = f2bf(v_[j]);                                   \
      hh_[j] = hu_;                                                       \
      ll_[j] = f2bf(v_[j] - bf2f(hu_));                                   \
    }                                                                     \
    *reinterpret_cast<u16x8*>(&Xh[srow][xc]) = hh_;                       \
    *reinterpret_cast<u16x8*>(&Xl[srow][xc]) = ll_;                       \
    if (WANT_DIAG) {                                                      \
      sq_ += __shfl_xor(sq_, 1);                                          \
      sq_ += __shfl_xor(sq_, 2);                                          \
      sq_ += __shfl_xor(sq_, 4);                                          \
      if ((tid & 7) == 0) diags[srow] = 0.5f * sq_;                       \
    }                                                                     \
  }

// wx MFMA block: 2 st x 2 ks x 2 mtl x MFMA3.
#define WX_COMPUTE(WX)                                                       \
  _Pragma("unroll") for (int st_ = 0; st_ < 2; ++st_)                        \
  _Pragma("unroll") for (int ks_ = 0; ks_ < 2; ++ks_) {                      \
    const int rr_ = st_ * 16 + l15;                                          \
    const int cc_ = ((ks_ * 4 + lg) ^ (l15 & 7)) << 3;                       \
    bf16x8 xh_ = *reinterpret_cast<const bf16x8*>(&Xh[rr_][cc_]);            \
    bf16x8 xl_ = *reinterpret_cast<const bf16x8*>(&Xl[rr_][cc_]);            \
    _Pragma("unroll") for (int mtl_ = 0; mtl_ < 2; ++mtl_)                   \
        MFMA3(WX[st_][mtl_], xh_, xl_, ph[mtl_][ks_], pl[mtl_][ks_]);        \
  }

// ---------------------------------------------------------------------------
// Weight transform: W[1024 k][1024 n] f32 -> WT [n][k] fp16.
// ---------------------------------------------------------------------------
__global__ __launch_bounds__(256) void wt_f16_kernel(
    const float* __restrict__ W, _Float16* __restrict__ T) {
  __shared__ float t[32][33];
  const int tx = threadIdx.x & 31, ty = threadIdx.x >> 5;
  const int k0 = blockIdx.x * 32, n0 = blockIdx.y * 32;
#pragma unroll
  for (int i = 0; i < 4; ++i)
    t[ty + 8 * i][tx] = W[(size_t)(k0 + ty + 8 * i) * 1024 + n0 + tx];
  __syncthreads();
#pragma unroll
  for (int i = 0; i < 4; ++i)
    T[(size_t)(n0 + ty + 8 * i) * 1024 + k0 + tx] = (_Float16)t[tx][ty + 8 * i];
}

// ---------------------------------------------------------------------------
// fp16 MFMA GEMM: C[16384,1024] = A[16384,1024] @ W + bias.
// A f32 (converted fp16 on the fly), W pre-transposed fp16 [n][k].
// 128x128 tile, BK=64, 256 threads (4 waves 2x2, 64x64 each).
// LDS rows 128B (64 halfs), 8 chunks of 16B, swizzle chunk ^ (row&7).
// ---------------------------------------------------------------------------
__global__ __launch_bounds__(256) void gemm_f16_kernel(
    const float* __restrict__ A, const _Float16* __restrict__ BT,
    const float* __restrict__ bias, float* __restrict__ C) {
  __shared__ _Float16 As[2][128][64];
  __shared__ _Float16 Bs[2][128][64];
  const int tid = threadIdx.x;
  const int m0 = blockIdx.x * 128, n0 = blockIdx.y * 128;
  const int srow = tid >> 1, skh = tid & 1;   // half-row of 32 elems
  const int wave = tid >> 6, lane = tid & 63;
  const int wm = (wave >> 1) << 6, wn = (wave & 1) << 6;
  const int l15 = lane & 15, lg = lane >> 4;

  const float* pa = A + (size_t)(m0 + srow) * 1024 + skh * 32;
  const _Float16* pb = BT + (size_t)(n0 + srow) * 1024 + skh * 32;

  f32x4 acc[4][4];
#pragma unroll
  for (int i = 0; i < 4; ++i)
#pragma unroll
    for (int j = 0; j < 4; ++j) acc[i][j] = f32x4{0.f, 0.f, 0.f, 0.f};

  float4 af[8];
  f16x8 gb[4];

#define LOADGH(kt)                                                        \
  {                                                                       \
    const float* p_ = pa + (kt) * 64;                                     \
    _Pragma("unroll") for (int j = 0; j < 8; ++j)                         \
      af[j] = *reinterpret_cast<const float4*>(p_ + 4 * j);               \
    const _Float16* q_ = pb + (kt) * 64;                                  \
    _Pragma("unroll") for (int j = 0; j < 4; ++j)                         \
      gb[j] = *reinterpret_cast<const f16x8*>(q_ + 8 * j);                \
  }

#define STAGEH(nb)                                                        \
  {                                                                       \
    _Pragma("unroll") for (int j = 0; j < 4; ++j) {                       \
      f16x8 hz;                                                           \
      hz[0] = (_Float16)af[2 * j].x;     hz[1] = (_Float16)af[2 * j].y;   \
      hz[2] = (_Float16)af[2 * j].z;     hz[3] = (_Float16)af[2 * j].w;   \
      hz[4] = (_Float16)af[2 * j + 1].x; hz[5] = (_Float16)af[2 * j + 1].y;\
      hz[6] = (_Float16)af[2 * j + 1].z; hz[7] = (_Float16)af[2 * j + 1].w;\
      const int cA = (((skh * 4 + j) ^ (srow & 7)) << 3);                 \
      *reinterpret_cast<f16x8*>(&As[nb][srow][cA]) = hz;                  \
      *reinterpret_cast<f16x8*>(&Bs[nb][srow][cA]) = gb[j];               \
    }                                                                     \
  }

  LOADGH(0);
  STAGEH(0);
  __syncthreads();

  for (int kt = 0; kt < 16; ++kt) {
    const int cur = kt & 1;
    if (kt < 15) LOADGH(kt + 1);

    f16x8 bf[2][4];
#pragma unroll
    for (int ks = 0; ks < 2; ++ks)
#pragma unroll
      for (int fn = 0; fn < 4; ++fn) {
        const int r = wn + fn * 16 + l15;
        bf[ks][fn] = *reinterpret_cast<const f16x8*>(
            &Bs[cur][r][(((ks * 4 + lg) ^ (r & 7)) << 3)]);
      }
#pragma unroll
    for (int fm = 0; fm < 4; ++fm) {
      const int r = wm + fm * 16 + l15;
#pragma unroll
      for (int ks = 0; ks < 2; ++ks) {
        f16x8 av = *reinterpret_cast<const f16x8*>(
            &As[cur][r][(((ks * 4 + lg) ^ (r & 7)) << 3)]);
#pragma unroll
        for (int fn = 0; fn < 4; ++fn)
          acc[fm][fn] = __builtin_amdgcn_mfma_f32_16x16x32_f16(
              av, bf[ks][fn], acc[fm][fn], 0, 0, 0);
      }
    }
    if (kt < 15) STAGEH(cur ^ 1);
    __syncthreads();
  }

#pragma unroll
  for (int fm = 0; fm < 4; ++fm) {
    const int row = m0 + wm + fm * 16 + (lg << 2);
#pragma unroll
    for (int fn = 0; fn < 4; ++fn) {
      const int col = n0 + wn + fn * 16 + l15;
      const float bc = bias[col];
      f32x4 v = acc[fm][fn];
#pragma unroll
      for (int j = 0; j < 4; ++j) C[(size_t)(row + j) * 1024 + col] = v[j] + bc;
    }
  }
}

// ---------------------------------------------------------------------------
// wxmax: global max of wx_k via MFMA. 512 blocks x 512 flat rows.
// ---------------------------------------------------------------------------
__global__ __launch_bounds__(256) void wxmax_mfma_kernel(
    const float* __restrict__ kproj, const float* __restrict__ proj,
    float* __restrict__ blockmax) {
  __shared__ unsigned short Xh[32][64], Xl[32][64];
  __shared__ float diags[32];  // unused (WANT_DIAG=false)
  __shared__ float redw[4];
  const int tid = threadIdx.x, blk = blockIdx.x;
  const int lane = tid & 63, w = tid >> 6;
  const int l15 = lane & 15, lg = lane >> 4;
  (void)diags;

  bf16x8 ph[2][2], pl[2][2];
#pragma unroll
  for (int mtl = 0; mtl < 2; ++mtl)
#pragma unroll
    for (int ks = 0; ks < 2; ++ks)
      load_pfrag(proj, (2 * w + mtl) * 16 + l15, ks * 32 + lg * 8,
                 &ph[mtl][ks], &pl[mtl][ks]);

  float gmax = -3.4e38f;
  const int srow = tid >> 3, q8 = (tid & 7) << 3;
  const int xc = ((q8 >> 3) ^ (srow & 7)) << 3;

  for (int batch = 0; batch < 16; ++batch) {
    const int row0 = blk * 512 + batch * 32;
    STAGE_X(kproj + (size_t)(row0 + srow) * 64 + q8, false);
    __syncthreads();
    f32x4 wx[2][2];
#pragma unroll
    for (int st = 0; st < 2; ++st)
#pragma unroll
      for (int mtl = 0; mtl < 2; ++mtl) wx[st][mtl] = f32x4{0, 0, 0, 0};
    WX_COMPUTE(wx);
#pragma unroll
    for (int st = 0; st < 2; ++st)
#pragma unroll
      for (int mtl = 0; mtl < 2; ++mtl)
#pragma unroll
        for (int r = 0; r < 4; ++r) gmax = fmaxf(gmax, wx[st][mtl][r]);
    __syncthreads();
  }
#pragma unroll
  for (int off = 32; off; off >>= 1) gmax = fmaxf(gmax, __shfl_xor(gmax, off));
  if (lane == 0) redw[w] = gmax;
  __syncthreads();
  if (tid == 0)
    blockmax[blk] = fmaxf(fmaxf(redw[0], redw[1]), fmaxf(redw[2], redw[3]));
}

__global__ __launch_bounds__(256) void maxreduce_kernel(
    const float* __restrict__ blockmax, float* __restrict__ stab, int n) {
  __shared__ float sm[256];
  float v = -3.4e38f;
  for (int i = threadIdx.x; i < n; i += 256) v = fmaxf(v, blockmax[i]);
  sm[threadIdx.x] = v;
  __syncthreads();
  for (int s = 128; s; s >>= 1) {
    if (threadIdx.x < s)
      sm[threadIdx.x] = fmaxf(sm[threadIdx.x], sm[threadIdx.x + s]);
    __syncthreads();
  }
  if (threadIdx.x == 0) *stab = sm[0];
}

// ---------------------------------------------------------------------------
// kv: kv[m][d] = sum_s phi_k[s][m] V[s][d], plus k1[m].
// ---------------------------------------------------------------------------
__global__ __launch_bounds__(256) void kv_mfma_kernel(
    const float* __restrict__ kproj, const float* __restrict__ vproj,
    const float* __restrict__ proj, const float* __restrict__ stabp,
    float* __restrict__ kvpartT, float* __restrict__ k1part) {
  __shared__ unsigned short Xh[32][64], Xl[32][64];
  __shared__ float Vs[32][66];
  __shared__ unsigned short phiTh[128][40], phiTl[128][40];
  __shared__ float diags[32];
  const int tid = threadIdx.x, blk = blockIdx.x;
  const int c = blk & 7, bh = blk >> 3, b = bh >> 4, h = bh & 15;
  const int lane = tid & 63, w = tid >> 6;
  const int l15 = lane & 15, lg = lane >> 4;
  const float stab = *stabp;

  bf16x8 ph[2][2], pl[2][2];
#pragma unroll
  for (int mtl = 0; mtl < 2; ++mtl)
#pragma unroll
    for (int ks = 0; ks < 2; ++ks)
      load_pfrag(proj, (2 * w + mtl) * 16 + l15, ks * 32 + lg * 8,
                 &ph[mtl][ks], &pl[mtl][ks]);

  f32x4 akv[2][4];
#pragma unroll
  for (int i = 0; i < 2; ++i)
#pragma unroll
    for (int j = 0; j < 4; ++j) akv[i][j] = f32x4{0, 0, 0, 0};
  float k1acc[2] = {0.f, 0.f};

  const int srow = tid >> 3, q8 = (tid & 7) << 3;
  const int xc = ((q8 >> 3) ^ (srow & 7)) << 3;

  for (int batch = 0; batch < 16; ++batch) {
    const int s0 = c * 512 + batch * 32;
    const size_t rb = (((size_t)(b * S_ + s0 + srow) * H_ + h)) << 6;
    STAGE_X(kproj + rb + q8, true);
    {
      float4 va = *reinterpret_cast<const float4*>(vproj + rb + q8);
      float4 vb = *reinterpret_cast<const float4*>(vproj + rb + q8 + 4);
      Vs[srow][q8 + 0] = va.x; Vs[srow][q8 + 1] = va.y;
      Vs[srow][q8 + 2] = va.z; Vs[srow][q8 + 3] = va.w;
      Vs[srow][q8 + 4] = vb.x; Vs[srow][q8 + 5] = vb.y;
      Vs[srow][q8 + 6] = vb.z; Vs[srow][q8 + 7] = vb.w;
    }
    __syncthreads();  // bar1

    f32x4 wx[2][2];
#pragma unroll
    for (int st = 0; st < 2; ++st)
#pragma unroll
      for (int mtl = 0; mtl < 2; ++mtl) wx[st][mtl] = f32x4{0, 0, 0, 0};
    WX_COMPUTE(wx);

#pragma unroll
    for (int st = 0; st < 2; ++st)
#pragma unroll
      for (int mtl = 0; mtl < 2; ++mtl) {
        const int m = (2 * w + mtl) * 16 + l15;
        s16x4 hv, lv;
        float psum = 0.f;
#pragma unroll
        for (int r = 0; r < 4; ++r) {
          const int s = st * 16 + lg * 4 + r;
          float p = __expf(wx[st][mtl][r] - diags[s] - stab) * CM;
          psum += p;
          unsigned short hu = f2bf(p);
          hv[r] = (short)hu;
          lv[r] = (short)f2bf(p - bf2f(hu));
        }
        k1acc[mtl] += psum;
        *reinterpret_cast<s16x4*>(&phiTh[m][st * 16 + lg * 4]) = hv;
        *reinterpret_cast<s16x4*>(&phiTl[m][st * 16 + lg * 4]) = lv;
      }
    __syncthreads();  // bar2

    bf16x8 pah[2], pal[2];
#pragma unroll
    for (int mtl = 0; mtl < 2; ++mtl) {
      pah[mtl] = *reinterpret_cast<const bf16x8*>(
          &phiTh[(2 * w + mtl) * 16 + l15][lg * 8]);
      pal[mtl] = *reinterpret_cast<const bf16x8*>(
          &phiTl[(2 * w + mtl) * 16 + l15][lg * 8]);
    }
#pragma unroll
    for (int dt = 0; dt < 4; ++dt) {
      bf16x8 bvh, bvl;
#pragma unroll
      for (int j = 0; j < 8; ++j) {
        float v = Vs[lg * 8 + j][dt * 16 + l15];
        unsigned short hu = f2bf(v);
        bvh[j] = (short)hu;
        bvl[j] = (short)f2bf(v - bf2f(hu));
      }
#pragma unroll
      for (int mtl = 0; mtl < 2; ++mtl)
        MFMA3(akv[mtl][dt], pah[mtl], pal[mtl], bvh, bvl);
    }
    __syncthreads();  // bar3
  }

#pragma unroll
  for (int mtl = 0; mtl < 2; ++mtl) {
#pragma unroll
    for (int dt = 0; dt < 4; ++dt) {
      const int d = dt * 16 + l15, m0 = (2 * w + mtl) * 16 + lg * 4;
      *reinterpret_cast<f32x4*>(&kvpartT[(size_t)blk * 8192 + d * 128 + m0]) =
          akv[mtl][dt];
    }
    float kk = k1acc[mtl];
    kk += __shfl_xor(kk, 16);
    kk += __shfl_xor(kk, 32);
    if (lane < 16) k1part[blk * 128 + (2 * w + mtl) * 16 + lane] = kk;
  }
}

__global__ __launch_bounds__(256) void kvreduce_kernel(
    const float* __restrict__ kvpartT, const float* __restrict__ k1part,
    unsigned short* __restrict__ kvTh, unsigned short* __restrict__ kvTl,
    float* __restrict__ k1) {
  const int bh = blockIdx.x;
  for (int i = threadIdx.x; i < 8192; i += 256) {
    float s = 0.f;
#pragma unroll
    for (int c = 0; c < 8; ++c) s += kvpartT[(size_t)(bh * 8 + c) * 8192 + i];
    unsigned short hu = f2bf(s);
    kvTh[(size_t)bh * 8192 + i] = hu;
    kvTl[(size_t)bh * 8192 + i] = f2bf(s - bf2f(hu));
  }
  if (threadIdx.x < 128) {
    float s = 0.f;
#pragma unroll
    for (int c = 0; c < 8; ++c) s += k1part[(bh * 8 + c) * 128 + threadIdx.x];
    k1[bh * 128 + threadIdx.x] = s;
  }
}

// ---------------------------------------------------------------------------
// qkv: phi_q (per-row max) -> out^T[d][s] = sum_m kvT[d][m] phi[s][m] / denom.
// ---------------------------------------------------------------------------
__global__ __launch_bounds__(256) void qkv_mfma_kernel(
    const float* __restrict__ qproj, const unsigned short* __restrict__ kvTh,
    const unsigned short* __restrict__ kvTl, const float* __restrict__ k1g,
    const float* __restrict__ proj, float* __restrict__ outh) {
  __shared__ unsigned short Xh[32][64], Xl[32][64];
  __shared__ unsigned short Ph[32][128], Pl[32][128];
  __shared__ float k1s[128];
  __shared__ float diags[32];
  __shared__ float rmaxp[4][32];
  __shared__ float denp[4][32];
  const int tid = threadIdx.x, blk = blockIdx.x;
  const int ch = blk & 15, bh = blk >> 4, b = bh >> 4, h = bh & 15;
  const int lane = tid & 63, w = tid >> 6;
  const int l15 = lane & 15, lg = lane >> 4;

  bf16x8 ph[2][2], pl[2][2];
#pragma unroll
  for (int mtl = 0; mtl < 2; ++mtl)
#pragma unroll
    for (int ks = 0; ks < 2; ++ks)
      load_pfrag(proj, (2 * w + mtl) * 16 + l15, ks * 32 + lg * 8,
                 &ph[mtl][ks], &pl[mtl][ks]);

  bf16x8 kah[4], kal[4];
#pragma unroll
  for (int ks = 0; ks < 4; ++ks) {
    const size_t o = (size_t)bh * 8192 + (w * 16 + l15) * 128 + ks * 32 + lg * 8;
    kah[ks] = *reinterpret_cast<const bf16x8*>(kvTh + o);
    kal[ks] = *reinterpret_cast<const bf16x8*>(kvTl + o);
  }
  if (tid < 128) k1s[tid] = k1g[bh * 128 + tid];

  const int srow = tid >> 3, q8 = (tid & 7) << 3;
  const int xc = ((q8 >> 3) ^ (srow & 7)) << 3;

  for (int batch = 0; batch < 8; ++batch) {
    const int s0 = ch * 256 + batch * 32;
    const size_t rb = (((size_t)(b * S_ + s0 + srow) * H_ + h)) << 6;
    STAGE_X(qproj + rb + q8, true);
    __syncthreads();  // bar1

    f32x4 wx[2][2];
#pragma unroll
    for (int st = 0; st < 2; ++st)
#pragma unroll
      for (int mtl = 0; mtl < 2; ++mtl) wx[st][mtl] = f32x4{0, 0, 0, 0};
    WX_COMPUTE(wx);

#pragma unroll
    for (int st = 0; st < 2; ++st)
#pragma unroll
      for (int r = 0; r < 4; ++r) {
        float v = fmaxf(wx[st][0][r], wx[st][1][r]);
        v = fmaxf(v, __shfl_xor(v, 1));
        v = fmaxf(v, __shfl_xor(v, 2));
        v = fmaxf(v, __shfl_xor(v, 4));
        v = fmaxf(v, __shfl_xor(v, 8));
        if (l15 == 0) rmaxp[w][st * 16 + lg * 4 + r] = v;
      }
    __syncthreads();  // bar2

#pragma unroll
    for (int st = 0; st < 2; ++st) {
      float off[4];
#pragma unroll
      for (int r = 0; r < 4; ++r) {
        const int s = st * 16 + lg * 4 + r;
        float rmx = fmaxf(fmaxf(rmaxp[0][s], rmaxp[1][s]),
                          fmaxf(rmaxp[2][s], rmaxp[3][s]));
        off[r] = rmx + diags[s];
      }
      float den[4] = {0.f, 0.f, 0.f, 0.f};
#pragma unroll
      for (int mtl = 0; mtl < 2; ++mtl) {
        const int m = (2 * w + mtl) * 16 + l15;
        const float k1v = k1s[m];
#pragma unroll
        for (int r = 0; r < 4; ++r) {
          const int s = st * 16 + lg * 4 + r;
          float p = __expf(wx[st][mtl][r] - off[r]) * CM;
          den[r] += p * k1v;
          unsigned short hu = f2bf(p);
          const int cw = ((((m >> 3) ^ (s & 7)) << 3) | (m & 7));
          Ph[s][cw] = hu;
          Pl[s][cw] = f2bf(p - bf2f(hu));
        }
      }
#pragma unroll
      for (int r = 0; r < 4; ++r) {
        float v = den[r];
        v += __shfl_xor(v, 1);
        v += __shfl_xor(v, 2);
        v += __shfl_xor(v, 4);
        v += __shfl_xor(v, 8);
        if (l15 == 0) denp[w][st * 16 + lg * 4 + r] = v;
      }
    }
    __syncthreads();  // bar3

#pragma unroll
    for (int st = 0; st < 2; ++st) {
      f32x4 od = {0.f, 0.f, 0.f, 0.f};
#pragma unroll
      for (int ks = 0; ks < 4; ++ks) {
        const int cc = ((ks * 4 + lg) ^ (l15 & 7)) << 3;
        bf16x8 bph = *reinterpret_cast<const bf16x8*>(&Ph[st * 16 + l15][cc]);
        bf16x8 bpl = *reinterpret_cast<const bf16x8*>(&Pl[st * 16 + l15][cc]);
        MFMA3(od, kah[ks], kal[ks], bph, bpl);
      }
      const int s = st * 16 + l15;
      const float dens =
          1.f / (denp[0][s] + denp[1][s] + denp[2][s] + denp[3][s] + 1e-6f);
      f32x4 o = od * dens;
      *reinterpret_cast<f32x4*>(
          &outh[(size_t)(b * S_ + s0 + s) * 1024 + h * 64 + w * 16 + lg * 4]) = o;
    }
    __syncthreads();  // bar4
  }
}

// ---------------------------------------------------------------------------
extern "C" void kernel_launch(void* const* d_in, const int* in_sizes, int n_in,
                              void* d_out, int out_size, void* d_ws,
                              size_t ws_size, hipStream_t stream) {
  const float* query = (const float*)d_in[0];
  const float* value = (const float*)d_in[1];
  const float* key   = (const float*)d_in[2];
  const float* Wq = (const float*)d_in[3];
  const float* bq = (const float*)d_in[4];
  const float* Wk = (const float*)d_in[5];
  const float* bk = (const float*)d_in[6];
  const float* Wv = (const float*)d_in[7];
  const float* bv = (const float*)d_in[8];
  const float* Wo = (const float*)d_in[9];
  const float* bo = (const float*)d_in[10];
  const float* proj = (const float*)d_in[11];
  float* out = (float*)d_out;
  float* ws = (float*)d_ws;

  float* Abuf = ws + OFF_A;
  float* Bbuf = ws + OFF_B;
  _Float16* WT = (_Float16*)(ws + OFF_X);
  float* KVPT = ws + OFF_X;
  float* K1P = ws + OFF_X + 4194304;
  unsigned short* KVTh = (unsigned short*)(ws + OFF_KV);
  unsigned short* KVTl = KVTh + 524288;
  float* K1 = ws + OFF_K1;
  float* BMX = ws + OFF_BM;
  float* ST = ws + OFF_ST;

  dim3 gw(32, 32);
  dim3 gg(128, 8);

  // 1. k_proj
  wt_f16_kernel<<<gw, 256, 0, stream>>>(Wk, WT);
  gemm_f16_kernel<<<gg, 256, 0, stream>>>(key, WT, bk, Abuf);
  // 2. stab
  wxmax_mfma_kernel<<<512, 256, 0, stream>>>(Abuf, proj, BMX);
  maxreduce_kernel<<<1, 256, 0, stream>>>(BMX, ST, 512);
  // 3. v_proj
  wt_f16_kernel<<<gw, 256, 0, stream>>>(Wv, WT);
  gemm_f16_kernel<<<gg, 256, 0, stream>>>(value, WT, bv, Bbuf);
  // 4. kv / k1 (KVPT aliases WT region; WT dead now)
  kv_mfma_kernel<<<512, 256, 0, stream>>>(Abuf, Bbuf, proj, ST, KVPT, K1P);
  kvreduce_kernel<<<64, 256, 0, stream>>>(KVPT, K1P, KVTh, KVTl, K1);
  // 5. q_proj (KVPT dead after reduce)
  wt_f16_kernel<<<gw, 256, 0, stream>>>(Wq, WT);
  gemm_f16_kernel<<<gg, 256, 0, stream>>>(query, WT, bq, Abuf);
  // 6. out_h
  qkv_mfma_kernel<<<1024, 256, 0, stream>>>(Abuf, KVTh, KVTl, K1, proj, Bbuf);
  // 7. output projection
  wt_f16_kernel<<<gw, 256, 0, stream>>>(Wo, WT);
  gemm_f16_kernel<<<gg, 256, 0, stream>>>(Bbuf, WT, bo, out);
}

// Round 7
// 464.544 us; speedup vs baseline: 7.5203x; 1.2202x over previous
//
#include <hip/hip_runtime.h>
#include <hip/hip_bf16.h>

// Performer (FAVOR+) forward. Round 7: m97-structure fp16 GEMMs
// (global_load_lds width=16, BK=32 dbuf, pre-swizzled source) + fp16 A
// pre-conversion. Middle section unchanged from R6 (passed).
// B=4, S=4096, D=1024, H=16, K=64, M=128.

#define B_  4
#define S_  4096
#define H_  16

#define SCALE_X 0.3535533905932738f     // 64^-0.25
#define CM      0.08838834764831845f    // 128^-0.5

typedef __attribute__((ext_vector_type(8))) short bf16x8;
typedef __attribute__((ext_vector_type(4))) short s16x4;
typedef __attribute__((ext_vector_type(8))) unsigned short u16x8;
typedef __attribute__((ext_vector_type(8))) _Float16 f16x8;
typedef __attribute__((ext_vector_type(4))) _Float16 f16x4;
typedef __attribute__((ext_vector_type(4))) float f32x4;

// ---- ws layout (float units) ----
#define OFF_A    ((size_t)0)          // 16777216 : k_proj then q_proj (f32)
#define OFF_B    ((size_t)16777216)   // 16777216 : v_proj (f32)
#define OFF_X    ((size_t)33554432)   // union: WT fp16 (512K f32) / kvpartT+k1part
#define OFF_KV   ((size_t)37814272)   // kvT hi+lo: 2*524288 ush = 524288 f32
#define OFF_K1   ((size_t)38338560)   // 64*128 f32
#define OFF_BM   ((size_t)38346752)   // 512 block maxes
#define OFF_ST   ((size_t)38347264)   // stab scalar
#define OFF_A16  ((size_t)38347776)   // 8388608 f32 = 16M fp16: A-operand staging
// total 46736384 f32 = 186.9 MB

__device__ __forceinline__ unsigned short f2bf(float x) {
  union { __hip_bfloat16 b; unsigned short u; } c;
  c.b = __float2bfloat16(x);
  return c.u;
}
__device__ __forceinline__ float bf2f(unsigned short u) {
  union { float f; unsigned int i; } c;
  c.i = ((unsigned int)u) << 16;
  return c.f;
}

#define MFMA3(ACC, AH, AL, BH, BL)                                    \
  {                                                                   \
    ACC = __builtin_amdgcn_mfma_f32_16x16x32_bf16(AH, BH, ACC, 0,0,0);\
    ACC = __builtin_amdgcn_mfma_f32_16x16x32_bf16(AH, BL, ACC, 0,0,0);\
    ACC = __builtin_amdgcn_mfma_f32_16x16x32_bf16(AL, BH, ACC, 0,0,0);\
  }

#define GLDS(GP, LP)                                                  \
  __builtin_amdgcn_global_load_lds(                                   \
      (const __attribute__((address_space(1))) unsigned int*)(GP),    \
      (__attribute__((address_space(3))) unsigned int*)(LP), 16, 0, 0)

// load P-operand fragment (B for wx): lane supplies P[m][kb..kb+7] split hi/lo
__device__ __forceinline__ void load_pfrag(const float* __restrict__ proj, int m,
                                           int kb, bf16x8* ph, bf16x8* pl) {
  const float* p = proj + m * 64 + kb;
  float4 a = *reinterpret_cast<const float4*>(p);
  float4 b = *reinterpret_cast<const float4*>(p + 4);
  float v[8] = {a.x, a.y, a.z, a.w, b.x, b.y, b.z, b.w};
  bf16x8 h, l;
#pragma unroll
  for (int j = 0; j < 8; ++j) {
    unsigned short hu = f2bf(v[j]);
    h[j] = (short)hu;
    l[j] = (short)f2bf(v[j] - bf2f(hu));
  }
  *ph = h;
  *pl = l;
}

// Stage one X row-chunk: scale, hi/lo split, chunk-XOR LDS write (+opt diag).
#define STAGE_X(PTR, WANT_DIAG)                                           \
  {                                                                       \
    float4 a_ = *reinterpret_cast<const float4*>(PTR);                    \
    float4 b_ = *reinterpret_cast<const float4*>((PTR) + 4);              \
    float v_[8] = {a_.x * SCALE_X, a_.y * SCALE_X, a_.z * SCALE_X,        \
                   a_.w * SCALE_X, b_.x * SCALE_X, b_.y * SCALE_X,        \
                   b_.z * SCALE_X, b_.w * SCALE_X};                       \
    u16x8 hh_, ll_;                                                       \
    float sq_ = 0.f;                                                      \
    _Pragma("unroll") for (int j = 0; j < 8; ++j) {                       \
      sq_ += v_[j] * v_[j];                                               \
      unsigned short hu_ = f2bf(v_[j]);                                   \
      hh_[j] = hu_;                                                       \
      ll_[j] = f2bf(v_[j] - bf2f(hu_));                                   \
    }                                                                     \
    *reinterpret_cast<u16x8*>(&Xh[srow][xc]) = hh_;                       \
    *reinterpret_cast<u16x8*>(&Xl[srow][xc]) = ll_;                       \
    if (WANT_DIAG) {                                                      \
      sq_ += __shfl_xor(sq_, 1);                                          \
      sq_ += __shfl_xor(sq_, 2);                                          \
      sq_ += __shfl_xor(sq_, 4);                                          \
      if ((tid & 7) == 0) diags[srow] = 0.5f * sq_;                       \
    }                                                                     \
  }

// wx MFMA block: 2 st x 2 ks x 2 mtl x MFMA3.
#define WX_COMPUTE(WX)                                                       \
  _Pragma("unroll") for (int st_ = 0; st_ < 2; ++st_)                        \
  _Pragma("unroll") for (int ks_ = 0; ks_ < 2; ++ks_) {                      \
    const int rr_ = st_ * 16 + l15;                                          \
    const int cc_ = ((ks_ * 4 + lg) ^ (l15 & 7)) << 3;                       \
    bf16x8 xh_ = *reinterpret_cast<const bf16x8*>(&Xh[rr_][cc_]);            \
    bf16x8 xl_ = *reinterpret_cast<const bf16x8*>(&Xl[rr_][cc_]);            \
    _Pragma("unroll") for (int mtl_ = 0; mtl_ < 2; ++mtl_)                   \
        MFMA3(WX[st_][mtl_], xh_, xl_, ph[mtl_][ks_], pl[mtl_][ks_]);        \
  }

// ---------------------------------------------------------------------------
// f32 -> fp16 conversion pass (16777216 elements).
// ---------------------------------------------------------------------------
__global__ __launch_bounds__(256) void cvt_f16_kernel(
    const float* __restrict__ in, _Float16* __restrict__ out) {
  const size_t stride = (size_t)gridDim.x * 256 * 8;
  for (size_t i = ((size_t)blockIdx.x * 256 + threadIdx.x) * 8; i < 16777216UL;
       i += stride) {
    float4 a = *reinterpret_cast<const float4*>(in + i);
    float4 b = *reinterpret_cast<const float4*>(in + i + 4);
    f16x8 h;
    h[0] = (_Float16)a.x; h[1] = (_Float16)a.y;
    h[2] = (_Float16)a.z; h[3] = (_Float16)a.w;
    h[4] = (_Float16)b.x; h[5] = (_Float16)b.y;
    h[6] = (_Float16)b.z; h[7] = (_Float16)b.w;
    *reinterpret_cast<f16x8*>(out + i) = h;
  }
}

// ---------------------------------------------------------------------------
// Weight transform: W[1024 k][1024 n] f32 -> WT [n][k] fp16.
// ---------------------------------------------------------------------------
__global__ __launch_bounds__(256) void wt_f16_kernel(
    const float* __restrict__ W, _Float16* __restrict__ T) {
  __shared__ float t[32][33];
  const int tx = threadIdx.x & 31, ty = threadIdx.x >> 5;
  const int k0 = blockIdx.x * 32, n0 = blockIdx.y * 32;
#pragma unroll
  for (int i = 0; i < 4; ++i)
    t[ty + 8 * i][tx] = W[(size_t)(k0 + ty + 8 * i) * 1024 + n0 + tx];
  __syncthreads();
#pragma unroll
  for (int i = 0; i < 4; ++i)
    T[(size_t)(n0 + ty + 8 * i) * 1024 + k0 + tx] = (_Float16)t[tx][ty + 8 * i];
}

// ---------------------------------------------------------------------------
// m97-structure fp16 GEMM: C[16384,1024] = A16 @ WT^T + bias.
// A16 fp16 [16384][1024], WT fp16 [n][k]. 128x128 tile, BK=32, 256 threads
// (4 waves 2x2). Staging via global_load_lds width=16, LDS linear dest,
// PRE-SWIZZLED global source (chunk c fetches global chunk c^(r&3)).
// Fragment reads use the same XOR -> 4-way conflicts max.
// ---------------------------------------------------------------------------
__global__ __launch_bounds__(256) void gemm_lds_f16(
    const _Float16* __restrict__ A16, const _Float16* __restrict__ BT,
    const float* __restrict__ bias, float* __restrict__ C) {
  __shared__ _Float16 As[2][128][32];
  __shared__ _Float16 Bs[2][128][32];
  const int tid = threadIdx.x;
  const int bid = blockIdx.x;
  const int m0 = (bid & 127) << 7;
  const int n0 = (bid >> 7) << 7;
  const int wave = tid >> 6, lane = tid & 63;
  const int wm = (wave >> 1) << 6, wn = (wave & 1) << 6;
  const int l15 = lane & 15, lg = lane >> 4;

  // staging geometry: chunk q = issue*256 + tid; row = q>>2, chunk-pos = q&3.
  const int rlo = tid >> 2;                      // issue0 row (0..63)
  const int cg = ((tid & 3) ^ (rlo & 3)) << 3;   // pre-swizzled k-offset (halfs)
  const int wqbase = wave << 10;                 // wave-uniform LDS byte base

  const _Float16* pa = A16 + (size_t)(m0 + rlo) * 1024 + cg;
  const _Float16* pb = BT + (size_t)(n0 + rlo) * 1024 + cg;

  f32x4 acc[4][4];
#pragma unroll
  for (int i = 0; i < 4; ++i)
#pragma unroll
    for (int j = 0; j < 4; ++j) acc[i][j] = f32x4{0.f, 0.f, 0.f, 0.f};

#define STAGE_T(nb, kt)                                                   \
  {                                                                       \
    char* la = (char*)&As[nb][0][0] + wqbase;                             \
    char* lb = (char*)&Bs[nb][0][0] + wqbase;                             \
    GLDS(pa + (kt) * 32, la);                                             \
    GLDS(pa + (kt) * 32 + 65536, la + 4096);                              \
    GLDS(pb + (kt) * 32, lb);                                             \
    GLDS(pb + (kt) * 32 + 65536, lb + 4096);                              \
  }

  STAGE_T(0, 0);
  __syncthreads();

  for (int kt = 0; kt < 32; ++kt) {
    const int cur = kt & 1;
    if (kt < 31) STAGE_T(cur ^ 1, kt + 1);

    f16x8 bf[4];
#pragma unroll
    for (int fn = 0; fn < 4; ++fn) {
      const int r = wn + fn * 16 + l15;
      bf[fn] = *reinterpret_cast<const f16x8*>(&Bs[cur][r][(lg ^ (r & 3)) << 3]);
    }
#pragma unroll
    for (int fm = 0; fm < 4; ++fm) {
      const int r = wm + fm * 16 + l15;
      f16x8 av = *reinterpret_cast<const f16x8*>(&As[cur][r][(lg ^ (r & 3)) << 3]);
#pragma unroll
      for (int fn = 0; fn < 4; ++fn)
        acc[fm][fn] = __builtin_amdgcn_mfma_f32_16x16x32_f16(av, bf[fn],
                                                             acc[fm][fn], 0, 0, 0);
    }
    __syncthreads();
  }

#pragma unroll
  for (int fm = 0; fm < 4; ++fm) {
    const int row = m0 + wm + fm * 16 + (lg << 2);
#pragma unroll
    for (int fn = 0; fn < 4; ++fn) {
      const int col = n0 + wn + fn * 16 + l15;
      const float bc = bias[col];
      f32x4 v = acc[fm][fn];
#pragma unroll
      for (int j = 0; j < 4; ++j) C[(size_t)(row + j) * 1024 + col] = v[j] + bc;
    }
  }
#undef STAGE_T
}

// ---------------------------------------------------------------------------
// wxmax: global max of wx_k via MFMA. 512 blocks x 512 flat rows.
// ---------------------------------------------------------------------------
__global__ __launch_bounds__(256) void wxmax_mfma_kernel(
    const float* __restrict__ kproj, const float* __restrict__ proj,
    float* __restrict__ blockmax) {
  __shared__ unsigned short Xh[32][64], Xl[32][64];
  __shared__ float diags[32];  // unused (WANT_DIAG=false)
  __shared__ float redw[4];
  const int tid = threadIdx.x, blk = blockIdx.x;
  const int lane = tid & 63, w = tid >> 6;
  const int l15 = lane & 15, lg = lane >> 4;
  (void)diags;

  bf16x8 ph[2][2], pl[2][2];
#pragma unroll
  for (int mtl = 0; mtl < 2; ++mtl)
#pragma unroll
    for (int ks = 0; ks < 2; ++ks)
      load_pfrag(proj, (2 * w + mtl) * 16 + l15, ks * 32 + lg * 8,
                 &ph[mtl][ks], &pl[mtl][ks]);

  float gmax = -3.4e38f;
  const int srow = tid >> 3, q8 = (tid & 7) << 3;
  const int xc = ((q8 >> 3) ^ (srow & 7)) << 3;

  for (int batch = 0; batch < 16; ++batch) {
    const int row0 = blk * 512 + batch * 32;
    STAGE_X(kproj + (size_t)(row0 + srow) * 64 + q8, false);
    __syncthreads();
    f32x4 wx[2][2];
#pragma unroll
    for (int st = 0; st < 2; ++st)
#pragma unroll
      for (int mtl = 0; mtl < 2; ++mtl) wx[st][mtl] = f32x4{0, 0, 0, 0};
    WX_COMPUTE(wx);
#pragma unroll
    for (int st = 0; st < 2; ++st)
#pragma unroll
      for (int mtl = 0; mtl < 2; ++mtl)
#pragma unroll
        for (int r = 0; r < 4; ++r) gmax = fmaxf(gmax, wx[st][mtl][r]);
    __syncthreads();
  }
#pragma unroll
  for (int off = 32; off; off >>= 1) gmax = fmaxf(gmax, __shfl_xor(gmax, off));
  if (lane == 0) redw[w] = gmax;
  __syncthreads();
  if (tid == 0)
    blockmax[blk] = fmaxf(fmaxf(redw[0], redw[1]), fmaxf(redw[2], redw[3]));
}

__global__ __launch_bounds__(256) void maxreduce_kernel(
    const float* __restrict__ blockmax, float* __restrict__ stab, int n) {
  __shared__ float sm[256];
  float v = -3.4e38f;
  for (int i = threadIdx.x; i < n; i += 256) v = fmaxf(v, blockmax[i]);
  sm[threadIdx.x] = v;
  __syncthreads();
  for (int s = 128; s; s >>= 1) {
    if (threadIdx.x < s)
      sm[threadIdx.x] = fmaxf(sm[threadIdx.x], sm[threadIdx.x + s]);
    __syncthreads();
  }
  if (threadIdx.x == 0) *stab = sm[0];
}

// ---------------------------------------------------------------------------
// kv: kv[m][d] = sum_s phi_k[s][m] V[s][d], plus k1[m].
// ---------------------------------------------------------------------------
__global__ __launch_bounds__(256) void kv_mfma_kernel(
    const float* __restrict__ kproj, const float* __restrict__ vproj,
    const float* __restrict__ proj, const float* __restrict__ stabp,
    float* __restrict__ kvpartT, float* __restrict__ k1part) {
  __shared__ unsigned short Xh[32][64], Xl[32][64];
  __shared__ float Vs[32][66];
  __shared__ unsigned short phiTh[128][40], phiTl[128][40];
  __shared__ float diags[32];
  const int tid = threadIdx.x, blk = blockIdx.x;
  const int c = blk & 7, bh = blk >> 3, b = bh >> 4, h = bh & 15;
  const int lane = tid & 63, w = tid >> 6;
  const int l15 = lane & 15, lg = lane >> 4;
  const float stab = *stabp;

  bf16x8 ph[2][2], pl[2][2];
#pragma unroll
  for (int mtl = 0; mtl < 2; ++mtl)
#pragma unroll
    for (int ks = 0; ks < 2; ++ks)
      load_pfrag(proj, (2 * w + mtl) * 16 + l15, ks * 32 + lg * 8,
                 &ph[mtl][ks], &pl[mtl][ks]);

  f32x4 akv[2][4];
#pragma unroll
  for (int i = 0; i < 2; ++i)
#pragma unroll
    for (int j = 0; j < 4; ++j) akv[i][j] = f32x4{0, 0, 0, 0};
  float k1acc[2] = {0.f, 0.f};

  const int srow = tid >> 3, q8 = (tid & 7) << 3;
  const int xc = ((q8 >> 3) ^ (srow & 7)) << 3;

  for (int batch = 0; batch < 16; ++batch) {
    const int s0 = c * 512 + batch * 32;
    const size_t rb = (((size_t)(b * S_ + s0 + srow) * H_ + h)) << 6;
    STAGE_X(kproj + rb + q8, true);
    {
      float4 va = *reinterpret_cast<const float4*>(vproj + rb + q8);
      float4 vb = *reinterpret_cast<const float4*>(vproj + rb + q8 + 4);
      Vs[srow][q8 + 0] = va.x; Vs[srow][q8 + 1] = va.y;
      Vs[srow][q8 + 2] = va.z; Vs[srow][q8 + 3] = va.w;
      Vs[srow][q8 + 4] = vb.x; Vs[srow][q8 + 5] = vb.y;
      Vs[srow][q8 + 6] = vb.z; Vs[srow][q8 + 7] = vb.w;
    }
    __syncthreads();  // bar1

    f32x4 wx[2][2];
#pragma unroll
    for (int st = 0; st < 2; ++st)
#pragma unroll
      for (int mtl = 0; mtl < 2; ++mtl) wx[st][mtl] = f32x4{0, 0, 0, 0};
    WX_COMPUTE(wx);

#pragma unroll
    for (int st = 0; st < 2; ++st)
#pragma unroll
      for (int mtl = 0; mtl < 2; ++mtl) {
        const int m = (2 * w + mtl) * 16 + l15;
        s16x4 hv, lv;
        float psum = 0.f;
#pragma unroll
        for (int r = 0; r < 4; ++r) {
          const int s = st * 16 + lg * 4 + r;
          float p = __expf(wx[st][mtl][r] - diags[s] - stab) * CM;
          psum += p;
          unsigned short hu = f2bf(p);
          hv[r] = (short)hu;
          lv[r] = (short)f2bf(p - bf2f(hu));
        }
        k1acc[mtl] += psum;
        *reinterpret_cast<s16x4*>(&phiTh[m][st * 16 + lg * 4]) = hv;
        *reinterpret_cast<s16x4*>(&phiTl[m][st * 16 + lg * 4]) = lv;
      }
    __syncthreads();  // bar2

    bf16x8 pah[2], pal[2];
#pragma unroll
    for (int mtl = 0; mtl < 2; ++mtl) {
      pah[mtl] = *reinterpret_cast<const bf16x8*>(
          &phiTh[(2 * w + mtl) * 16 + l15][lg * 8]);
      pal[mtl] = *reinterpret_cast<const bf16x8*>(
          &phiTl[(2 * w + mtl) * 16 + l15][lg * 8]);
    }
#pragma unroll
    for (int dt = 0; dt < 4; ++dt) {
      bf16x8 bvh, bvl;
#pragma unroll
      for (int j = 0; j < 8; ++j) {
        float v = Vs[lg * 8 + j][dt * 16 + l15];
        unsigned short hu = f2bf(v);
        bvh[j] = (short)hu;
        bvl[j] = (short)f2bf(v - bf2f(hu));
      }
#pragma unroll
      for (int mtl = 0; mtl < 2; ++mtl)
        MFMA3(akv[mtl][dt], pah[mtl], pal[mtl], bvh, bvl);
    }
    __syncthreads();  // bar3
  }

#pragma unroll
  for (int mtl = 0; mtl < 2; ++mtl) {
#pragma unroll
    for (int dt = 0; dt < 4; ++dt) {
      const int d = dt * 16 + l15, m0 = (2 * w + mtl) * 16 + lg * 4;
      *reinterpret_cast<f32x4*>(&kvpartT[(size_t)blk * 8192 + d * 128 + m0]) =
          akv[mtl][dt];
    }
    float kk = k1acc[mtl];
    kk += __shfl_xor(kk, 16);
    kk += __shfl_xor(kk, 32);
    if (lane < 16) k1part[blk * 128 + (2 * w + mtl) * 16 + lane] = kk;
  }
}

__global__ __launch_bounds__(256) void kvreduce_kernel(
    const float* __restrict__ kvpartT, const float* __restrict__ k1part,
    unsigned short* __restrict__ kvTh, unsigned short* __restrict__ kvTl,
    float* __restrict__ k1) {
  const int bh = blockIdx.x;
  for (int i = threadIdx.x; i < 8192; i += 256) {
    float s = 0.f;
#pragma unroll
    for (int c = 0; c < 8; ++c) s += kvpartT[(size_t)(bh * 8 + c) * 8192 + i];
    unsigned short hu = f2bf(s);
    kvTh[(size_t)bh * 8192 + i] = hu;
    kvTl[(size_t)bh * 8192 + i] = f2bf(s - bf2f(hu));
  }
  if (threadIdx.x < 128) {
    float s = 0.f;
#pragma unroll
    for (int c = 0; c < 8; ++c) s += k1part[(bh * 8 + c) * 128 + threadIdx.x];
    k1[bh * 128 + threadIdx.x] = s;
  }
}

// ---------------------------------------------------------------------------
// qkv: phi_q (per-row max) -> out^T[d][s] = sum_m kvT[d][m] phi[s][m] / denom.
// Writes out_h directly as fp16 (consumed only by the final GEMM).
// ---------------------------------------------------------------------------
__global__ __launch_bounds__(256) void qkv_mfma_kernel(
    const float* __restrict__ qproj, const unsigned short* __restrict__ kvTh,
    const unsigned short* __restrict__ kvTl, const float* __restrict__ k1g,
    const float* __restrict__ proj, _Float16* __restrict__ outh) {
  __shared__ unsigned short Xh[32][64], Xl[32][64];
  __shared__ unsigned short Ph[32][128], Pl[32][128];
  __shared__ float k1s[128];
  __shared__ float diags[32];
  __shared__ float rmaxp[4][32];
  __shared__ float denp[4][32];
  const int tid = threadIdx.x, blk = blockIdx.x;
  const int ch = blk & 15, bh = blk >> 4, b = bh >> 4, h = bh & 15;
  const int lane = tid & 63, w = tid >> 6;
  const int l15 = lane & 15, lg = lane >> 4;

  bf16x8 ph[2][2], pl[2][2];
#pragma unroll
  for (int mtl = 0; mtl < 2; ++mtl)
#pragma unroll
    for (int ks = 0; ks < 2; ++ks)
      load_pfrag(proj, (2 * w + mtl) * 16 + l15, ks * 32 + lg * 8,
                 &ph[mtl][ks], &pl[mtl][ks]);

  bf16x8 kah[4], kal[4];
#pragma unroll
  for (int ks = 0; ks < 4; ++ks) {
    const size_t o = (size_t)bh * 8192 + (w * 16 + l15) * 128 + ks * 32 + lg * 8;
    kah[ks] = *reinterpret_cast<const bf16x8*>(kvTh + o);
    kal[ks] = *reinterpret_cast<const bf16x8*>(kvTl + o);
  }
  if (tid < 128) k1s[tid] = k1g[bh * 128 + tid];

  const int srow = tid >> 3, q8 = (tid & 7) << 3;
  const int xc = ((q8 >> 3) ^ (srow & 7)) << 3;

  for (int batch = 0; batch < 8; ++batch) {
    const int s0 = ch * 256 + batch * 32;
    const size_t rb = (((size_t)(b * S_ + s0 + srow) * H_ + h)) << 6;
    STAGE_X(qproj + rb + q8, true);
    __syncthreads();  // bar1

    f32x4 wx[2][2];
#pragma unroll
    for (int st = 0; st < 2; ++st)
#pragma unroll
      for (int mtl = 0; mtl < 2; ++mtl) wx[st][mtl] = f32x4{0, 0, 0, 0};
    WX_COMPUTE(wx);

#pragma unroll
    for (int st = 0; st < 2; ++st)
#pragma unroll
      for (int r = 0; r < 4; ++r) {
        float v = fmaxf(wx[st][0][r], wx[st][1][r]);
        v = fmaxf(v, __shfl_xor(v, 1));
        v = fmaxf(v, __shfl_xor(v, 2));
        v = fmaxf(v, __shfl_xor(v, 4));
        v = fmaxf(v, __shfl_xor(v, 8));
        if (l15 == 0) rmaxp[w][st * 16 + lg * 4 + r] = v;
      }
    __syncthreads();  // bar2

#pragma unroll
    for (int st = 0; st < 2; ++st) {
      float off[4];
#pragma unroll
      for (int r = 0; r < 4; ++r) {
        const int s = st * 16 + lg * 4 + r;
        float rmx = fmaxf(fmaxf(rmaxp[0][s], rmaxp[1][s]),
                          fmaxf(rmaxp[2][s], rmaxp[3][s]));
        off[r] = rmx + diags[s];
      }
      float den[4] = {0.f, 0.f, 0.f, 0.f};
#pragma unroll
      for (int mtl = 0; mtl < 2; ++mtl) {
        const int m = (2 * w + mtl) * 16 + l15;
        const float k1v = k1s[m];
#pragma unroll
        for (int r = 0; r < 4; ++r) {
          const int s = st * 16 + lg * 4 + r;
          float p = __expf(wx[st][mtl][r] - off[r]) * CM;
          den[r] += p * k1v;
          unsigned short hu = f2bf(p);
          const int cw = ((((m >> 3) ^ (s & 7)) << 3) | (m & 7));
          Ph[s][cw] = hu;
          Pl[s][cw] = f2bf(p - bf2f(hu));
        }
      }
#pragma unroll
      for (int r = 0; r < 4; ++r) {
        float v = den[r];
        v += __shfl_xor(v, 1);
        v += __shfl_xor(v, 2);
        v += __shfl_xor(v, 4);
        v += __shfl_xor(v, 8);
        if (l15 == 0) denp[w][st * 16 + lg * 4 + r] = v;
      }
    }
    __syncthreads();  // bar3

#pragma unroll
    for (int st = 0; st < 2; ++st) {
      f32x4 od = {0.f, 0.f, 0.f, 0.f};
#pragma unroll
      for (int ks = 0; ks < 4; ++ks) {
        const int cc = ((ks * 4 + lg) ^ (l15 & 7)) << 3;
        bf16x8 bph = *reinterpret_cast<const bf16x8*>(&Ph[st * 16 + l15][cc]);
        bf16x8 bpl = *reinterpret_cast<const bf16x8*>(&Pl[st * 16 + l15][cc]);
        MFMA3(od, kah[ks], kal[ks], bph, bpl);
      }
      const int s = st * 16 + l15;
      const float dens =
          1.f / (denp[0][s] + denp[1][s] + denp[2][s] + denp[3][s] + 1e-6f);
      f16x4 o;
#pragma unroll
      for (int j = 0; j < 4; ++j) o[j] = (_Float16)(od[j] * dens);
      *reinterpret_cast<f16x4*>(
          &outh[(size_t)(b * S_ + s0 + s) * 1024 + h * 64 + w * 16 + lg * 4]) = o;
    }
    __syncthreads();  // bar4
  }
}

// ---------------------------------------------------------------------------
extern "C" void kernel_launch(void* const* d_in, const int* in_sizes, int n_in,
                              void* d_out, int out_size, void* d_ws,
                              size_t ws_size, hipStream_t stream) {
  const float* query = (const float*)d_in[0];
  const float* value = (const float*)d_in[1];
  const float* key   = (const float*)d_in[2];
  const float* Wq = (const float*)d_in[3];
  const float* bq = (const float*)d_in[4];
  const float* Wk = (const float*)d_in[5];
  const float* bk = (const float*)d_in[6];
  const float* Wv = (const float*)d_in[7];
  const float* bv = (const float*)d_in[8];
  const float* Wo = (const float*)d_in[9];
  const float* bo = (const float*)d_in[10];
  const float* proj = (const float*)d_in[11];
  float* out = (float*)d_out;
  float* ws = (float*)d_ws;

  float* Abuf = ws + OFF_A;
  float* Bbuf = ws + OFF_B;
  _Float16* WT = (_Float16*)(ws + OFF_X);
  float* KVPT = ws + OFF_X;
  float* K1P = ws + OFF_X + 4194304;
  unsigned short* KVTh = (unsigned short*)(ws + OFF_KV);
  unsigned short* KVTl = KVTh + 524288;
  float* K1 = ws + OFF_K1;
  float* BMX = ws + OFF_BM;
  float* ST = ws + OFF_ST;
  _Float16* X16 = (_Float16*)(ws + OFF_A16);

  dim3 gw(32, 32);

  // 1. k_proj
  cvt_f16_kernel<<<2048, 256, 0, stream>>>(key, X16);
  wt_f16_kernel<<<gw, 256, 0, stream>>>(Wk, WT);
  gemm_lds_f16<<<1024, 256, 0, stream>>>(X16, WT, bk, Abuf);
  // 2. stab
  wxmax_mfma_kernel<<<512, 256, 0, stream>>>(Abuf, proj, BMX);
  maxreduce_kernel<<<1, 256, 0, stream>>>(BMX, ST, 512);
  // 3. v_proj
  cvt_f16_kernel<<<2048, 256, 0, stream>>>(value, X16);
  wt_f16_kernel<<<gw, 256, 0, stream>>>(Wv, WT);
  gemm_lds_f16<<<1024, 256, 0, stream>>>(X16, WT, bv, Bbuf);
  // 4. kv / k1 (KVPT aliases WT region; WT dead now)
  kv_mfma_kernel<<<512, 256, 0, stream>>>(Abuf, Bbuf, proj, ST, KVPT, K1P);
  kvreduce_kernel<<<64, 256, 0, stream>>>(KVPT, K1P, KVTh, KVTl, K1);
  // 5. q_proj (KVPT dead after reduce)
  cvt_f16_kernel<<<2048, 256, 0, stream>>>(query, X16);
  wt_f16_kernel<<<gw, 256, 0, stream>>>(Wq, WT);
  gemm_lds_f16<<<1024, 256, 0, stream>>>(X16, WT, bq, Abuf);
  // 6. out_h -> X16 as fp16 (query copy dead)
  qkv_mfma_kernel<<<1024, 256, 0, stream>>>(Abuf, KVTh, KVTl, K1, proj, X16);
  // 7. output projection
  wt_f16_kernel<<<gw, 256, 0, stream>>>(Wo, WT);
  gemm_lds_f16<<<1024, 256, 0, stream>>>(X16, WT, bo, out);
}

// Round 10
// 419.324 us; speedup vs baseline: 8.3313x; 1.1078x over previous
//
#include <hip/hip_runtime.h>
#include <hip/hip_bf16.h>

// Performer (FAVOR+) forward. Round 10: R7 verified structure + single-pass
// bf16 middle (drop hi/lo split corrections; 1/3 MFMA, half the cvt VALU).
// All layouts/indices/barriers identical to R7 (passed, 465us).
// B=4, S=4096, D=1024, H=16, K=64, M=128.

#define B_  4
#define S_  4096
#define H_  16

#define SCALE_X 0.3535533905932738f     // 64^-0.25
#define CM      0.08838834764831845f    // 128^-0.5

typedef __attribute__((ext_vector_type(8))) short bf16x8;
typedef __attribute__((ext_vector_type(4))) short s16x4;
typedef __attribute__((ext_vector_type(8))) unsigned short u16x8;
typedef __attribute__((ext_vector_type(8))) _Float16 f16x8;
typedef __attribute__((ext_vector_type(4))) _Float16 f16x4;
typedef __attribute__((ext_vector_type(4))) float f32x4;

// ---- ws layout (float units) ----
#define OFF_A    ((size_t)0)          // 16777216 : k_proj then q_proj (f32)
#define OFF_B    ((size_t)16777216)   // 16777216 : v_proj (f32)
#define OFF_X    ((size_t)33554432)   // union: WT fp16 (512K f32) / kvpartT+k1part
#define OFF_KV   ((size_t)37814272)   // kvT bf16: 524288 ush = 262144 f32
#define OFF_K1   ((size_t)38338560)   // 64*128 f32
#define OFF_BM   ((size_t)38346752)   // 512 block maxes
#define OFF_ST   ((size_t)38347264)   // stab scalar
#define OFF_A16  ((size_t)38347776)   // 8388608 f32 = 16M fp16: A-operand staging
// total 46736384 f32 = 186.9 MB

__device__ __forceinline__ unsigned short f2bf(float x) {
  union { __hip_bfloat16 b; unsigned short u; } c;
  c.b = __float2bfloat16(x);
  return c.u;
}

#define MFMAB(ACC, A, B)                                               \
  ACC = __builtin_amdgcn_mfma_f32_16x16x32_bf16(A, B, ACC, 0, 0, 0)

#define GLDS(GP, LP)                                                  \
  __builtin_amdgcn_global_load_lds(                                   \
      (const __attribute__((address_space(1))) unsigned int*)(GP),    \
      (__attribute__((address_space(3))) unsigned int*)(LP), 16, 0, 0)

// load P-operand fragment (B for wx): lane supplies P[m][kb..kb+7] as bf16
__device__ __forceinline__ void load_pfrag(const float* __restrict__ proj, int m,
                                           int kb, bf16x8* ph) {
  const float* p = proj + m * 64 + kb;
  float4 a = *reinterpret_cast<const float4*>(p);
  float4 b = *reinterpret_cast<const float4*>(p + 4);
  float v[8] = {a.x, a.y, a.z, a.w, b.x, b.y, b.z, b.w};
  bf16x8 h;
#pragma unroll
  for (int j = 0; j < 8; ++j) h[j] = (short)f2bf(v[j]);
  *ph = h;
}

// Stage one X row-chunk: scale, bf16, chunk-XOR LDS write (+opt diag).
// Requires in scope: srow, q8, xc, tid, Xh (and diags if WANT_DIAG).
#define STAGE_X(PTR, WANT_DIAG)                                           \
  {                                                                       \
    float4 a_ = *reinterpret_cast<const float4*>(PTR);                    \
    float4 b_ = *reinterpret_cast<const float4*>((PTR) + 4);              \
    float v_[8] = {a_.x * SCALE_X, a_.y * SCALE_X, a_.z * SCALE_X,        \
                   a_.w * SCALE_X, b_.x * SCALE_X, b_.y * SCALE_X,        \
                   b_.z * SCALE_X, b_.w * SCALE_X};                       \
    u16x8 hh_;                                                            \
    float sq_ = 0.f;                                                      \
    _Pragma("unroll") for (int j = 0; j < 8; ++j) {                       \
      sq_ += v_[j] * v_[j];                                               \
      hh_[j] = f2bf(v_[j]);                                               \
    }                                                                     \
    *reinterpret_cast<u16x8*>(&Xh[srow][xc]) = hh_;                       \
    if (WANT_DIAG) {                                                      \
      sq_ += __shfl_xor(sq_, 1);                                          \
      sq_ += __shfl_xor(sq_, 2);                                          \
      sq_ += __shfl_xor(sq_, 4);                                          \
      if ((tid & 7) == 0) diags[srow] = 0.5f * sq_;                       \
    }                                                                     \
  }

// wx MFMA block: 2 st x 2 ks x 2 mtl, single bf16 MFMA each.
#define WX_COMPUTE(WX)                                                       \
  _Pragma("unroll") for (int st_ = 0; st_ < 2; ++st_)                        \
  _Pragma("unroll") for (int ks_ = 0; ks_ < 2; ++ks_) {                      \
    const int rr_ = st_ * 16 + l15;                                          \
    const int cc_ = ((ks_ * 4 + lg) ^ (l15 & 7)) << 3;                       \
    bf16x8 xh_ = *reinterpret_cast<const bf16x8*>(&Xh[rr_][cc_]);            \
    _Pragma("unroll") for (int mtl_ = 0; mtl_ < 2; ++mtl_)                   \
        MFMAB(WX[st_][mtl_], xh_, ph[mtl_][ks_]);                            \
  }

// ---------------------------------------------------------------------------
// f32 -> fp16 conversion pass (16777216 elements).
// ---------------------------------------------------------------------------
__global__ __launch_bounds__(256) void cvt_f16_kernel(
    const float* __restrict__ in, _Float16* __restrict__ out) {
  const size_t stride = (size_t)gridDim.x * 256 * 8;
  for (size_t i = ((size_t)blockIdx.x * 256 + threadIdx.x) * 8; i < 16777216UL;
       i += stride) {
    float4 a = *reinterpret_cast<const float4*>(in + i);
    float4 b = *reinterpret_cast<const float4*>(in + i + 4);
    f16x8 h;
    h[0] = (_Float16)a.x; h[1] = (_Float16)a.y;
    h[2] = (_Float16)a.z; h[3] = (_Float16)a.w;
    h[4] = (_Float16)b.x; h[5] = (_Float16)b.y;
    h[6] = (_Float16)b.z; h[7] = (_Float16)b.w;
    *reinterpret_cast<f16x8*>(out + i) = h;
  }
}

// ---------------------------------------------------------------------------
// Weight transform: W[1024 k][1024 n] f32 -> WT [n][k] fp16.
// ---------------------------------------------------------------------------
__global__ __launch_bounds__(256) void wt_f16_kernel(
    const float* __restrict__ W, _Float16* __restrict__ T) {
  __shared__ float t[32][33];
  const int tx = threadIdx.x & 31, ty = threadIdx.x >> 5;
  const int k0 = blockIdx.x * 32, n0 = blockIdx.y * 32;
#pragma unroll
  for (int i = 0; i < 4; ++i)
    t[ty + 8 * i][tx] = W[(size_t)(k0 + ty + 8 * i) * 1024 + n0 + tx];
  __syncthreads();
#pragma unroll
  for (int i = 0; i < 4; ++i)
    T[(size_t)(n0 + ty + 8 * i) * 1024 + k0 + tx] = (_Float16)t[tx][ty + 8 * i];
}

// ---------------------------------------------------------------------------
// m97-structure fp16 GEMM (verified R7): C f32 = A16 @ WT^T + bias.
// ---------------------------------------------------------------------------
__global__ __launch_bounds__(256) void gemm_lds_f16(
    const _Float16* __restrict__ A16, const _Float16* __restrict__ BT,
    const float* __restrict__ bias, float* __restrict__ C) {
  __shared__ _Float16 As[2][128][32];
  __shared__ _Float16 Bs[2][128][32];
  const int tid = threadIdx.x;
  const int bid = blockIdx.x;
  const int m0 = (bid & 127) << 7;
  const int n0 = (bid >> 7) << 7;
  const int wave = tid >> 6, lane = tid & 63;
  const int wm = (wave >> 1) << 6, wn = (wave & 1) << 6;
  const int l15 = lane & 15, lg = lane >> 4;

  const int rlo = tid >> 2;
  const int cg = ((tid & 3) ^ (rlo & 3)) << 3;
  const int wqbase = wave << 10;

  const _Float16* pa = A16 + (size_t)(m0 + rlo) * 1024 + cg;
  const _Float16* pb = BT + (size_t)(n0 + rlo) * 1024 + cg;

  f32x4 acc[4][4];
#pragma unroll
  for (int i = 0; i < 4; ++i)
#pragma unroll
    for (int j = 0; j < 4; ++j) acc[i][j] = f32x4{0.f, 0.f, 0.f, 0.f};

#define STAGE_T(nb, kt)                                                   \
  {                                                                       \
    char* la = (char*)&As[nb][0][0] + wqbase;                             \
    char* lb = (char*)&Bs[nb][0][0] + wqbase;                             \
    GLDS(pa + (kt) * 32, la);                                             \
    GLDS(pa + (kt) * 32 + 65536, la + 4096);                              \
    GLDS(pb + (kt) * 32, lb);                                             \
    GLDS(pb + (kt) * 32 + 65536, lb + 4096);                              \
  }

  STAGE_T(0, 0);
  __syncthreads();

  for (int kt = 0; kt < 32; ++kt) {
    const int cur = kt & 1;
    if (kt < 31) STAGE_T(cur ^ 1, kt + 1);

    f16x8 bf[4];
#pragma unroll
    for (int fn = 0; fn < 4; ++fn) {
      const int r = wn + fn * 16 + l15;
      bf[fn] = *reinterpret_cast<const f16x8*>(&Bs[cur][r][(lg ^ (r & 3)) << 3]);
    }
#pragma unroll
    for (int fm = 0; fm < 4; ++fm) {
      const int r = wm + fm * 16 + l15;
      f16x8 av = *reinterpret_cast<const f16x8*>(&As[cur][r][(lg ^ (r & 3)) << 3]);
#pragma unroll
      for (int fn = 0; fn < 4; ++fn)
        acc[fm][fn] = __builtin_amdgcn_mfma_f32_16x16x32_f16(av, bf[fn],
                                                             acc[fm][fn], 0, 0, 0);
    }
    __syncthreads();
  }

#pragma unroll
  for (int fm = 0; fm < 4; ++fm) {
    const int row = m0 + wm + fm * 16 + (lg << 2);
#pragma unroll
    for (int fn = 0; fn < 4; ++fn) {
      const int col = n0 + wn + fn * 16 + l15;
      const float bc = bias[col];
      f32x4 v = acc[fm][fn];
#pragma unroll
      for (int j = 0; j < 4; ++j) C[(size_t)(row + j) * 1024 + col] = v[j] + bc;
    }
  }
#undef STAGE_T
}

// ---------------------------------------------------------------------------
// wxmax: global max of wx_k via MFMA. 512 blocks x 512 flat rows.
// ---------------------------------------------------------------------------
__global__ __launch_bounds__(256) void wxmax_mfma_kernel(
    const float* __restrict__ kproj, const float* __restrict__ proj,
    float* __restrict__ blockmax) {
  __shared__ unsigned short Xh[32][64];
  __shared__ float diags[32];  // unused (WANT_DIAG=false)
  __shared__ float redw[4];
  const int tid = threadIdx.x, blk = blockIdx.x;
  const int lane = tid & 63, w = tid >> 6;
  const int l15 = lane & 15, lg = lane >> 4;
  (void)diags;

  bf16x8 ph[2][2];
#pragma unroll
  for (int mtl = 0; mtl < 2; ++mtl)
#pragma unroll
    for (int ks = 0; ks < 2; ++ks)
      load_pfrag(proj, (2 * w + mtl) * 16 + l15, ks * 32 + lg * 8, &ph[mtl][ks]);

  float gmax = -3.4e38f;
  const int srow = tid >> 3, q8 = (tid & 7) << 3;
  const int xc = ((q8 >> 3) ^ (srow & 7)) << 3;

  for (int batch = 0; batch < 16; ++batch) {
    const int row0 = blk * 512 + batch * 32;
    STAGE_X(kproj + (size_t)(row0 + srow) * 64 + q8, false);
    __syncthreads();
    f32x4 wx[2][2];
#pragma unroll
    for (int st = 0; st < 2; ++st)
#pragma unroll
      for (int mtl = 0; mtl < 2; ++mtl) wx[st][mtl] = f32x4{0, 0, 0, 0};
    WX_COMPUTE(wx);
#pragma unroll
    for (int st = 0; st < 2; ++st)
#pragma unroll
      for (int mtl = 0; mtl < 2; ++mtl)
#pragma unroll
        for (int r = 0; r < 4; ++r) gmax = fmaxf(gmax, wx[st][mtl][r]);
    __syncthreads();
  }
#pragma unroll
  for (int off = 32; off; off >>= 1) gmax = fmaxf(gmax, __shfl_xor(gmax, off));
  if (lane == 0) redw[w] = gmax;
  __syncthreads();
  if (tid == 0)
    blockmax[blk] = fmaxf(fmaxf(redw[0], redw[1]), fmaxf(redw[2], redw[3]));
}

__global__ __launch_bounds__(256) void maxreduce_kernel(
    const float* __restrict__ blockmax, float* __restrict__ stab, int n) {
  __shared__ float sm[256];
  float v = -3.4e38f;
  for (int i = threadIdx.x; i < n; i += 256) v = fmaxf(v, blockmax[i]);
  sm[threadIdx.x] = v;
  __syncthreads();
  for (int s = 128; s; s >>= 1) {
    if (threadIdx.x < s)
      sm[threadIdx.x] = fmaxf(sm[threadIdx.x], sm[threadIdx.x + s]);
    __syncthreads();
  }
  if (threadIdx.x == 0) *stab = sm[0];
}

// ---------------------------------------------------------------------------
// kv: kv[m][d] = sum_s phi_k[s][m] V[s][d], plus k1[m].
// ---------------------------------------------------------------------------
__global__ __launch_bounds__(256) void kv_mfma_kernel(
    const float* __restrict__ kproj, const float* __restrict__ vproj,
    const float* __restrict__ proj, const float* __restrict__ stabp,
    float* __restrict__ kvpartT, float* __restrict__ k1part) {
  __shared__ unsigned short Xh[32][64];
  __shared__ float Vs[32][66];
  __shared__ unsigned short phiTh[128][40];
  __shared__ float diags[32];
  const int tid = threadIdx.x, blk = blockIdx.x;
  const int c = blk & 7, bh = blk >> 3, b = bh >> 4, h = bh & 15;
  const int lane = tid & 63, w = tid >> 6;
  const int l15 = lane & 15, lg = lane >> 4;
  const float stab = *stabp;

  bf16x8 ph[2][2];
#pragma unroll
  for (int mtl = 0; mtl < 2; ++mtl)
#pragma unroll
    for (int ks = 0; ks < 2; ++ks)
      load_pfrag(proj, (2 * w + mtl) * 16 + l15, ks * 32 + lg * 8, &ph[mtl][ks]);

  f32x4 akv[2][4];
#pragma unroll
  for (int i = 0; i < 2; ++i)
#pragma unroll
    for (int j = 0; j < 4; ++j) akv[i][j] = f32x4{0, 0, 0, 0};
  float k1acc[2] = {0.f, 0.f};

  const int srow = tid >> 3, q8 = (tid & 7) << 3;
  const int xc = ((q8 >> 3) ^ (srow & 7)) << 3;

  for (int batch = 0; batch < 16; ++batch) {
    const int s0 = c * 512 + batch * 32;
    const size_t rb = (((size_t)(b * S_ + s0 + srow) * H_ + h)) << 6;
    STAGE_X(kproj + rb + q8, true);
    {
      float4 va = *reinterpret_cast<const float4*>(vproj + rb + q8);
      float4 vb = *reinterpret_cast<const float4*>(vproj + rb + q8 + 4);
      Vs[srow][q8 + 0] = va.x; Vs[srow][q8 + 1] = va.y;
      Vs[srow][q8 + 2] = va.z; Vs[srow][q8 + 3] = va.w;
      Vs[srow][q8 + 4] = vb.x; Vs[srow][q8 + 5] = vb.y;
      Vs[srow][q8 + 6] = vb.z; Vs[srow][q8 + 7] = vb.w;
    }
    __syncthreads();  // bar1

    f32x4 wx[2][2];
#pragma unroll
    for (int st = 0; st < 2; ++st)
#pragma unroll
      for (int mtl = 0; mtl < 2; ++mtl) wx[st][mtl] = f32x4{0, 0, 0, 0};
    WX_COMPUTE(wx);

    // phi + phiT write + k1
#pragma unroll
    for (int st = 0; st < 2; ++st)
#pragma unroll
      for (int mtl = 0; mtl < 2; ++mtl) {
        const int m = (2 * w + mtl) * 16 + l15;
        s16x4 hv;
        float psum = 0.f;
#pragma unroll
        for (int r = 0; r < 4; ++r) {
          const int s = st * 16 + lg * 4 + r;
          float p = __expf(wx[st][mtl][r] - diags[s] - stab) * CM;
          psum += p;
          hv[r] = (short)f2bf(p);
        }
        k1acc[mtl] += psum;
        *reinterpret_cast<s16x4*>(&phiTh[m][st * 16 + lg * 4]) = hv;
      }
    __syncthreads();  // bar2

    // kv contraction: A = phiT[m][s] (contiguous), B = V[s][d] (scalar gather)
    bf16x8 pah[2];
#pragma unroll
    for (int mtl = 0; mtl < 2; ++mtl)
      pah[mtl] = *reinterpret_cast<const bf16x8*>(
          &phiTh[(2 * w + mtl) * 16 + l15][lg * 8]);
#pragma unroll
    for (int dt = 0; dt < 4; ++dt) {
      bf16x8 bvh;
#pragma unroll
      for (int j = 0; j < 8; ++j)
        bvh[j] = (short)f2bf(Vs[lg * 8 + j][dt * 16 + l15]);
#pragma unroll
      for (int mtl = 0; mtl < 2; ++mtl) MFMAB(akv[mtl][dt], pah[mtl], bvh);
    }
    __syncthreads();  // bar3
  }

#pragma unroll
  for (int mtl = 0; mtl < 2; ++mtl) {
#pragma unroll
    for (int dt = 0; dt < 4; ++dt) {
      const int d = dt * 16 + l15, m0 = (2 * w + mtl) * 16 + lg * 4;
      *reinterpret_cast<f32x4*>(&kvpartT[(size_t)blk * 8192 + d * 128 + m0]) =
          akv[mtl][dt];
    }
    float kk = k1acc[mtl];
    kk += __shfl_xor(kk, 16);
    kk += __shfl_xor(kk, 32);
    if (lane < 16) k1part[blk * 128 + (2 * w + mtl) * 16 + lane] = kk;
  }
}

__global__ __launch_bounds__(256) void kvreduce_kernel(
    const float* __restrict__ kvpartT, const float* __restrict__ k1part,
    unsigned short* __restrict__ kvT, float* __restrict__ k1) {
  const int bh = blockIdx.x;
  for (int i = threadIdx.x; i < 8192; i += 256) {
    float s = 0.f;
#pragma unroll
    for (int c = 0; c < 8; ++c) s += kvpartT[(size_t)(bh * 8 + c) * 8192 + i];
    kvT[(size_t)bh * 8192 + i] = f2bf(s);
  }
  if (threadIdx.x < 128) {
    float s = 0.f;
#pragma unroll
    for (int c = 0; c < 8; ++c) s += k1part[(bh * 8 + c) * 128 + threadIdx.x];
    k1[bh * 128 + threadIdx.x] = s;
  }
}

// ---------------------------------------------------------------------------
// qkv: phi_q (per-row max) -> out^T[d][s] = sum_m kvT[d][m] phi[s][m] / denom.
// Writes out_h as fp16 (consumed only by the final GEMM).
// ---------------------------------------------------------------------------
__global__ __launch_bounds__(256) void qkv_mfma_kernel(
    const float* __restrict__ qproj, const unsigned short* __restrict__ kvT,
    const float* __restrict__ k1g, const float* __restrict__ proj,
    _Float16* __restrict__ outh) {
  __shared__ unsigned short Xh[32][64];
  __shared__ unsigned short Ph[32][128];
  __shared__ float k1s[128];
  __shared__ float diags[32];
  __shared__ float rmaxp[4][32];
  __shared__ float denp[4][32];
  const int tid = threadIdx.x, blk = blockIdx.x;
  const int ch = blk & 15, bh = blk >> 4, b = bh >> 4, h = bh & 15;
  const int lane = tid & 63, w = tid >> 6;
  const int l15 = lane & 15, lg = lane >> 4;

  bf16x8 ph[2][2];
#pragma unroll
  for (int mtl = 0; mtl < 2; ++mtl)
#pragma unroll
    for (int ks = 0; ks < 2; ++ks)
      load_pfrag(proj, (2 * w + mtl) * 16 + l15, ks * 32 + lg * 8, &ph[mtl][ks]);

  // kvT A-fragments (constant per block): A[d = w*16+l15][m contiguous]
  bf16x8 kah[4];
#pragma unroll
  for (int ks = 0; ks < 4; ++ks) {
    const size_t o = (size_t)bh * 8192 + (w * 16 + l15) * 128 + ks * 32 + lg * 8;
    kah[ks] = *reinterpret_cast<const bf16x8*>(kvT + o);
  }
  if (tid < 128) k1s[tid] = k1g[bh * 128 + tid];

  const int srow = tid >> 3, q8 = (tid & 7) << 3;
  const int xc = ((q8 >> 3) ^ (srow & 7)) << 3;

  for (int batch = 0; batch < 8; ++batch) {
    const int s0 = ch * 256 + batch * 32;
    const size_t rb = (((size_t)(b * S_ + s0 + srow) * H_ + h)) << 6;
    STAGE_X(qproj + rb + q8, true);
    __syncthreads();  // bar1

    f32x4 wx[2][2];
#pragma unroll
    for (int st = 0; st < 2; ++st)
#pragma unroll
      for (int mtl = 0; mtl < 2; ++mtl) wx[st][mtl] = f32x4{0, 0, 0, 0};
    WX_COMPUTE(wx);

#pragma unroll
    for (int st = 0; st < 2; ++st)
#pragma unroll
      for (int r = 0; r < 4; ++r) {
        float v = fmaxf(wx[st][0][r], wx[st][1][r]);
        v = fmaxf(v, __shfl_xor(v, 1));
        v = fmaxf(v, __shfl_xor(v, 2));
        v = fmaxf(v, __shfl_xor(v, 4));
        v = fmaxf(v, __shfl_xor(v, 8));
        if (l15 == 0) rmaxp[w][st * 16 + lg * 4 + r] = v;
      }
    __syncthreads();  // bar2

#pragma unroll
    for (int st = 0; st < 2; ++st) {
      float off[4];
#pragma unroll
      for (int r = 0; r < 4; ++r) {
        const int s = st * 16 + lg * 4 + r;
        float rmx = fmaxf(fmaxf(rmaxp[0][s], rmaxp[1][s]),
                          fmaxf(rmaxp[2][s], rmaxp[3][s]));
        off[r] = rmx + diags[s];
      }
      float den[4] = {0.f, 0.f, 0.f, 0.f};
#pragma unroll
      for (int mtl = 0; mtl < 2; ++mtl) {
        const int m = (2 * w + mtl) * 16 + l15;
        const float k1v = k1s[m];
#pragma unroll
        for (int r = 0; r < 4; ++r) {
          const int s = st * 16 + lg * 4 + r;
          float p = __expf(wx[st][mtl][r] - off[r]) * CM;
          den[r] += p * k1v;
          Ph[s][((((m >> 3) ^ (s & 7)) << 3) | (m & 7))] = f2bf(p);
        }
      }
#pragma unroll
      for (int r = 0; r < 4; ++r) {
        float v = den[r];
        v += __shfl_xor(v, 1);
        v += __shfl_xor(v, 2);
        v += __shfl_xor(v, 4);
        v += __shfl_xor(v, 8);
        if (l15 == 0) denp[w][st * 16 + lg * 4 + r] = v;
      }
    }
    __syncthreads();  // bar3

#pragma unroll
    for (int st = 0; st < 2; ++st) {
      f32x4 od = {0.f, 0.f, 0.f, 0.f};
#pragma unroll
      for (int ks = 0; ks < 4; ++ks) {
        const int cc = ((ks * 4 + lg) ^ (l15 & 7)) << 3;
        bf16x8 bph = *reinterpret_cast<const bf16x8*>(&Ph[st * 16 + l15][cc]);
        MFMAB(od, kah[ks], bph);
      }
      const int s = st * 16 + l15;
      const float dens =
          1.f / (denp[0][s] + denp[1][s] + denp[2][s] + denp[3][s] + 1e-6f);
      f16x4 o;
#pragma unroll
      for (int j = 0; j < 4; ++j) o[j] = (_Float16)(od[j] * dens);
      *reinterpret_cast<f16x4*>(
          &outh[(size_t)(b * S_ + s0 + s) * 1024 + h * 64 + w * 16 + lg * 4]) = o;
    }
    __syncthreads();  // bar4
  }
}

// ---------------------------------------------------------------------------
extern "C" void kernel_launch(void* const* d_in, const int* in_sizes, int n_in,
                              void* d_out, int out_size, void* d_ws,
                              size_t ws_size, hipStream_t stream) {
  const float* query = (const float*)d_in[0];
  const float* value = (const float*)d_in[1];
  const float* key   = (const float*)d_in[2];
  const float* Wq = (const float*)d_in[3];
  const float* bq = (const float*)d_in[4];
  const float* Wk = (const float*)d_in[5];
  const float* bk = (const float*)d_in[6];
  const float* Wv = (const float*)d_in[7];
  const float* bv = (const float*)d_in[8];
  const float* Wo = (const float*)d_in[9];
  const float* bo = (const float*)d_in[10];
  const float* proj = (const float*)d_in[11];
  float* out = (float*)d_out;
  float* ws = (float*)d_ws;

  float* Abuf = ws + OFF_A;
  float* Bbuf = ws + OFF_B;
  _Float16* WT = (_Float16*)(ws + OFF_X);
  float* KVPT = ws + OFF_X;
  float* K1P = ws + OFF_X + 4194304;
  unsigned short* KVT = (unsigned short*)(ws + OFF_KV);
  float* K1 = ws + OFF_K1;
  float* BMX = ws + OFF_BM;
  float* ST = ws + OFF_ST;
  _Float16* X16 = (_Float16*)(ws + OFF_A16);

  dim3 gw(32, 32);

  // 1. k_proj
  cvt_f16_kernel<<<2048, 256, 0, stream>>>(key, X16);
  wt_f16_kernel<<<gw, 256, 0, stream>>>(Wk, WT);
  gemm_lds_f16<<<1024, 256, 0, stream>>>(X16, WT, bk, Abuf);
  // 2. stab
  wxmax_mfma_kernel<<<512, 256, 0, stream>>>(Abuf, proj, BMX);
  maxreduce_kernel<<<1, 256, 0, stream>>>(BMX, ST, 512);
  // 3. v_proj
  cvt_f16_kernel<<<2048, 256, 0, stream>>>(value, X16);
  wt_f16_kernel<<<gw, 256, 0, stream>>>(Wv, WT);
  gemm_lds_f16<<<1024, 256, 0, stream>>>(X16, WT, bv, Bbuf);
  // 4. kv / k1 (KVPT aliases WT region; WT dead now)
  kv_mfma_kernel<<<512, 256, 0, stream>>>(Abuf, Bbuf, proj, ST, KVPT, K1P);
  kvreduce_kernel<<<64, 256, 0, stream>>>(KVPT, K1P, KVT, K1);
  // 5. q_proj (KVPT dead after reduce)
  cvt_f16_kernel<<<2048, 256, 0, stream>>>(query, X16);
  wt_f16_kernel<<<gw, 256, 0, stream>>>(Wq, WT);
  gemm_lds_f16<<<1024, 256, 0, stream>>>(X16, WT, bq, Abuf);
  // 6. out_h -> X16 as fp16 (query copy dead)
  qkv_mfma_kernel<<<1024, 256, 0, stream>>>(Abuf, KVT, K1, proj, X16);
  // 7. output projection
  wt_f16_kernel<<<gw, 256, 0, stream>>>(Wo, WT);
  gemm_lds_f16<<<1024, 256, 0, stream>>>(X16, WT, bo, out);
}

// Round 11
// 410.618 us; speedup vs baseline: 8.5080x; 1.0212x over previous
//
#include <hip/hip_runtime.h>
#include <hip/hip_bf16.h>

// Performer (FAVOR+) forward. Round 11: R10 + (a) conflict-free GEMM LDS
// swizzle c^((r>>1)&3) on both write/read sides (4-way -> 2-way = free),
// (b) fp16 projection outputs + fp16 middle reads (layouts unchanged).
// B=4, S=4096, D=1024, H=16, K=64, M=128.

#define B_  4
#define S_  4096
#define H_  16

#define SCALE_X 0.3535533905932738f     // 64^-0.25
#define CM      0.08838834764831845f    // 128^-0.5

typedef __attribute__((ext_vector_type(8))) short bf16x8;
typedef __attribute__((ext_vector_type(4))) short s16x4;
typedef __attribute__((ext_vector_type(8))) unsigned short u16x8;
typedef __attribute__((ext_vector_type(8))) _Float16 f16x8;
typedef __attribute__((ext_vector_type(4))) _Float16 f16x4;
typedef __attribute__((ext_vector_type(4))) float f32x4;

// ---- ws layout (float units) ----
#define OFF_A    ((size_t)0)          // kproj16 then qproj16 (fp16, 32MB)
#define OFF_B    ((size_t)16777216)   // vproj16 (fp16)
#define OFF_X    ((size_t)33554432)   // union: WT fp16 / kvpartT+k1part
#define OFF_KV   ((size_t)37814272)   // kvT bf16: 524288 ush
#define OFF_K1   ((size_t)38338560)   // 64*128 f32
#define OFF_BM   ((size_t)38346752)   // 512 block maxes
#define OFF_ST   ((size_t)38347264)   // stab scalar
#define OFF_A16  ((size_t)38347776)   // 16M fp16: GEMM A staging / outh
// total 46736384 f32 = 186.9 MB

__device__ __forceinline__ unsigned short f2bf(float x) {
  union { __hip_bfloat16 b; unsigned short u; } c;
  c.b = __float2bfloat16(x);
  return c.u;
}

#define MFMAB(ACC, A, B)                                               \
  ACC = __builtin_amdgcn_mfma_f32_16x16x32_bf16(A, B, ACC, 0, 0, 0)

#define GLDS(GP, LP)                                                  \
  __builtin_amdgcn_global_load_lds(                                   \
      (const __attribute__((address_space(1))) unsigned int*)(GP),    \
      (__attribute__((address_space(3))) unsigned int*)(LP), 16, 0, 0)

// load P-operand fragment (B for wx): lane supplies P[m][kb..kb+7] as bf16
__device__ __forceinline__ void load_pfrag(const float* __restrict__ proj, int m,
                                           int kb, bf16x8* ph) {
  const float* p = proj + m * 64 + kb;
  float4 a = *reinterpret_cast<const float4*>(p);
  float4 b = *reinterpret_cast<const float4*>(p + 4);
  float v[8] = {a.x, a.y, a.z, a.w, b.x, b.y, b.z, b.w};
  bf16x8 h;
#pragma unroll
  for (int j = 0; j < 8; ++j) h[j] = (short)f2bf(v[j]);
  *ph = h;
}

// Stage one X row-chunk from fp16 source: scale, bf16, chunk-XOR LDS write.
// Requires in scope: srow, q8, xc, tid, Xh (and diags if WANT_DIAG).
#define STAGE_X(PTR, WANT_DIAG)                                           \
  {                                                                       \
    f16x8 xv_ = *reinterpret_cast<const f16x8*>(PTR);                     \
    u16x8 hh_;                                                            \
    float sq_ = 0.f;                                                      \
    _Pragma("unroll") for (int j = 0; j < 8; ++j) {                       \
      float vf_ = (float)xv_[j] * SCALE_X;                                \
      sq_ += vf_ * vf_;                                                   \
      hh_[j] = f2bf(vf_);                                                 \
    }                                                                     \
    *reinterpret_cast<u16x8*>(&Xh[srow][xc]) = hh_;                       \
    if (WANT_DIAG) {                                                      \
      sq_ += __shfl_xor(sq_, 1);                                          \
      sq_ += __shfl_xor(sq_, 2);                                          \
      sq_ += __shfl_xor(sq_, 4);                                          \
      if ((tid & 7) == 0) diags[srow] = 0.5f * sq_;                       \
    }                                                                     \
  }

// wx MFMA block: 2 st x 2 ks x 2 mtl, single bf16 MFMA each.
#define WX_COMPUTE(WX)                                                       \
  _Pragma("unroll") for (int st_ = 0; st_ < 2; ++st_)                        \
  _Pragma("unroll") for (int ks_ = 0; ks_ < 2; ++ks_) {                      \
    const int rr_ = st_ * 16 + l15;                                          \
    const int cc_ = ((ks_ * 4 + lg) ^ (l15 & 7)) << 3;                       \
    bf16x8 xh_ = *reinterpret_cast<const bf16x8*>(&Xh[rr_][cc_]);            \
    _Pragma("unroll") for (int mtl_ = 0; mtl_ < 2; ++mtl_)                   \
        MFMAB(WX[st_][mtl_], xh_, ph[mtl_][ks_]);                            \
  }

// ---------------------------------------------------------------------------
// f32 -> fp16 conversion pass (16777216 elements).
// ---------------------------------------------------------------------------
__global__ __launch_bounds__(256) void cvt_f16_kernel(
    const float* __restrict__ in, _Float16* __restrict__ out) {
  const size_t stride = (size_t)gridDim.x * 256 * 8;
  for (size_t i = ((size_t)blockIdx.x * 256 + threadIdx.x) * 8; i < 16777216UL;
       i += stride) {
    float4 a = *reinterpret_cast<const float4*>(in + i);
    float4 b = *reinterpret_cast<const float4*>(in + i + 4);
    f16x8 h;
    h[0] = (_Float16)a.x; h[1] = (_Float16)a.y;
    h[2] = (_Float16)a.z; h[3] = (_Float16)a.w;
    h[4] = (_Float16)b.x; h[5] = (_Float16)b.y;
    h[6] = (_Float16)b.z; h[7] = (_Float16)b.w;
    *reinterpret_cast<f16x8*>(out + i) = h;
  }
}

// ---------------------------------------------------------------------------
// Weight transform: W[1024 k][1024 n] f32 -> WT [n][k] fp16.
// ---------------------------------------------------------------------------
__global__ __launch_bounds__(256) void wt_f16_kernel(
    const float* __restrict__ W, _Float16* __restrict__ T) {
  __shared__ float t[32][33];
  const int tx = threadIdx.x & 31, ty = threadIdx.x >> 5;
  const int k0 = blockIdx.x * 32, n0 = blockIdx.y * 32;
#pragma unroll
  for (int i = 0; i < 4; ++i)
    t[ty + 8 * i][tx] = W[(size_t)(k0 + ty + 8 * i) * 1024 + n0 + tx];
  __syncthreads();
#pragma unroll
  for (int i = 0; i < 4; ++i)
    T[(size_t)(n0 + ty + 8 * i) * 1024 + k0 + tx] = (_Float16)t[tx][ty + 8 * i];
}

// ---------------------------------------------------------------------------
// m97-structure fp16 GEMM. Swizzle c ^ ((r>>1)&3) both sides: bank-quad slot
// (4r + c) mod 8 walks 0,4,1,5,2,6,3,7 over 8 rows -> 2 lanes/slot = free.
// C fp16 (projections) or f32 (final output).
// ---------------------------------------------------------------------------
template <int F16OUT>
__global__ __launch_bounds__(256) void gemm_lds(
    const _Float16* __restrict__ A16, const _Float16* __restrict__ BT,
    const float* __restrict__ bias, void* __restrict__ Cout) {
  __shared__ _Float16 As[2][128][32];
  __shared__ _Float16 Bs[2][128][32];
  const int tid = threadIdx.x;
  const int bid = blockIdx.x;
  const int m0 = (bid & 127) << 7;
  const int n0 = (bid >> 7) << 7;
  const int wave = tid >> 6, lane = tid & 63;
  const int wm = (wave >> 1) << 6, wn = (wave & 1) << 6;
  const int l15 = lane & 15, lg = lane >> 4;

  const int rlo = tid >> 2;
  const int cg = ((tid & 3) ^ ((rlo >> 1) & 3)) << 3;  // pre-swizzled source
  const int wqbase = wave << 10;

  const _Float16* pa = A16 + (size_t)(m0 + rlo) * 1024 + cg;
  const _Float16* pb = BT + (size_t)(n0 + rlo) * 1024 + cg;

  f32x4 acc[4][4];
#pragma unroll
  for (int i = 0; i < 4; ++i)
#pragma unroll
    for (int j = 0; j < 4; ++j) acc[i][j] = f32x4{0.f, 0.f, 0.f, 0.f};

#define STAGE_T(nb, kt)                                                   \
  {                                                                       \
    char* la = (char*)&As[nb][0][0] + wqbase;                             \
    char* lb = (char*)&Bs[nb][0][0] + wqbase;                             \
    GLDS(pa + (kt) * 32, la);                                             \
    GLDS(pa + (kt) * 32 + 65536, la + 4096);                              \
    GLDS(pb + (kt) * 32, lb);                                             \
    GLDS(pb + (kt) * 32 + 65536, lb + 4096);                              \
  }

  STAGE_T(0, 0);
  __syncthreads();

  for (int kt = 0; kt < 32; ++kt) {
    const int cur = kt & 1;
    if (kt < 31) STAGE_T(cur ^ 1, kt + 1);

    f16x8 bf[4];
#pragma unroll
    for (int fn = 0; fn < 4; ++fn) {
      const int r = wn + fn * 16 + l15;
      bf[fn] = *reinterpret_cast<const f16x8*>(
          &Bs[cur][r][(lg ^ ((r >> 1) & 3)) << 3]);
    }
#pragma unroll
    for (int fm = 0; fm < 4; ++fm) {
      const int r = wm + fm * 16 + l15;
      f16x8 av = *reinterpret_cast<const f16x8*>(
          &As[cur][r][(lg ^ ((r >> 1) & 3)) << 3]);
#pragma unroll
      for (int fn = 0; fn < 4; ++fn)
        acc[fm][fn] = __builtin_amdgcn_mfma_f32_16x16x32_f16(av, bf[fn],
                                                             acc[fm][fn], 0, 0, 0);
    }
    __syncthreads();
  }

#pragma unroll
  for (int fm = 0; fm < 4; ++fm) {
    const int row = m0 + wm + fm * 16 + (lg << 2);
#pragma unroll
    for (int fn = 0; fn < 4; ++fn) {
      const int col = n0 + wn + fn * 16 + l15;
      const float bc = bias[col];
      f32x4 v = acc[fm][fn];
      if (F16OUT) {
        _Float16* C = (_Float16*)Cout;
#pragma unroll
        for (int j = 0; j < 4; ++j)
          C[(size_t)(row + j) * 1024 + col] = (_Float16)(v[j] + bc);
      } else {
        float* C = (float*)Cout;
#pragma unroll
        for (int j = 0; j < 4; ++j) C[(size_t)(row + j) * 1024 + col] = v[j] + bc;
      }
    }
  }
#undef STAGE_T
}

// ---------------------------------------------------------------------------
// wxmax: global max of wx_k via MFMA. 512 blocks x 512 flat rows.
// ---------------------------------------------------------------------------
__global__ __launch_bounds__(256) void wxmax_mfma_kernel(
    const _Float16* __restrict__ kproj, const float* __restrict__ proj,
    float* __restrict__ blockmax) {
  __shared__ unsigned short Xh[32][64];
  __shared__ float diags[32];  // unused (WANT_DIAG=false)
  __shared__ float redw[4];
  const int tid = threadIdx.x, blk = blockIdx.x;
  const int lane = tid & 63, w = tid >> 6;
  const int l15 = lane & 15, lg = lane >> 4;
  (void)diags;

  bf16x8 ph[2][2];
#pragma unroll
  for (int mtl = 0; mtl < 2; ++mtl)
#pragma unroll
    for (int ks = 0; ks < 2; ++ks)
      load_pfrag(proj, (2 * w + mtl) * 16 + l15, ks * 32 + lg * 8, &ph[mtl][ks]);

  float gmax = -3.4e38f;
  const int srow = tid >> 3, q8 = (tid & 7) << 3;
  const int xc = ((q8 >> 3) ^ (srow & 7)) << 3;

  for (int batch = 0; batch < 16; ++batch) {
    const int row0 = blk * 512 + batch * 32;
    STAGE_X(kproj + (size_t)(row0 + srow) * 64 + q8, false);
    __syncthreads();
    f32x4 wx[2][2];
#pragma unroll
    for (int st = 0; st < 2; ++st)
#pragma unroll
      for (int mtl = 0; mtl < 2; ++mtl) wx[st][mtl] = f32x4{0, 0, 0, 0};
    WX_COMPUTE(wx);
#pragma unroll
    for (int st = 0; st < 2; ++st)
#pragma unroll
      for (int mtl = 0; mtl < 2; ++mtl)
#pragma unroll
        for (int r = 0; r < 4; ++r) gmax = fmaxf(gmax, wx[st][mtl][r]);
    __syncthreads();
  }
#pragma unroll
  for (int off = 32; off; off >>= 1) gmax = fmaxf(gmax, __shfl_xor(gmax, off));
  if (lane == 0) redw[w] = gmax;
  __syncthreads();
  if (tid == 0)
    blockmax[blk] = fmaxf(fmaxf(redw[0], redw[1]), fmaxf(redw[2], redw[3]));
}

__global__ __launch_bounds__(256) void maxreduce_kernel(
    const float* __restrict__ blockmax, float* __restrict__ stab, int n) {
  __shared__ float sm[256];
  float v = -3.4e38f;
  for (int i = threadIdx.x; i < n; i += 256) v = fmaxf(v, blockmax[i]);
  sm[threadIdx.x] = v;
  __syncthreads();
  for (int s = 128; s; s >>= 1) {
    if (threadIdx.x < s)
      sm[threadIdx.x] = fmaxf(sm[threadIdx.x], sm[threadIdx.x + s]);
    __syncthreads();
  }
  if (threadIdx.x == 0) *stab = sm[0];
}

// ---------------------------------------------------------------------------
// kv: kv[m][d] = sum_s phi_k[s][m] V[s][d], plus k1[m].
// ---------------------------------------------------------------------------
__global__ __launch_bounds__(256) void kv_mfma_kernel(
    const _Float16* __restrict__ kproj, const _Float16* __restrict__ vproj,
    const float* __restrict__ proj, const float* __restrict__ stabp,
    float* __restrict__ kvpartT, float* __restrict__ k1part) {
  __shared__ unsigned short Xh[32][64];
  __shared__ float Vs[32][66];
  __shared__ unsigned short phiTh[128][40];
  __shared__ float diags[32];
  const int tid = threadIdx.x, blk = blockIdx.x;
  const int c = blk & 7, bh = blk >> 3, b = bh >> 4, h = bh & 15;
  const int lane = tid & 63, w = tid >> 6;
  const int l15 = lane & 15, lg = lane >> 4;
  const float stab = *stabp;

  bf16x8 ph[2][2];
#pragma unroll
  for (int mtl = 0; mtl < 2; ++mtl)
#pragma unroll
    for (int ks = 0; ks < 2; ++ks)
      load_pfrag(proj, (2 * w + mtl) * 16 + l15, ks * 32 + lg * 8, &ph[mtl][ks]);

  f32x4 akv[2][4];
#pragma unroll
  for (int i = 0; i < 2; ++i)
#pragma unroll
    for (int j = 0; j < 4; ++j) akv[i][j] = f32x4{0, 0, 0, 0};
  float k1acc[2] = {0.f, 0.f};

  const int srow = tid >> 3, q8 = (tid & 7) << 3;
  const int xc = ((q8 >> 3) ^ (srow & 7)) << 3;

  for (int batch = 0; batch < 16; ++batch) {
    const int s0 = c * 512 + batch * 32;
    const size_t rb = (((size_t)(b * S_ + s0 + srow) * H_ + h)) << 6;
    STAGE_X(kproj + rb + q8, true);
    {
      f16x8 vv = *reinterpret_cast<const f16x8*>(vproj + rb + q8);
#pragma unroll
      for (int j = 0; j < 8; ++j) Vs[srow][q8 + j] = (float)vv[j];
    }
    __syncthreads();  // bar1

    f32x4 wx[2][2];
#pragma unroll
    for (int st = 0; st < 2; ++st)
#pragma unroll
      for (int mtl = 0; mtl < 2; ++mtl) wx[st][mtl] = f32x4{0, 0, 0, 0};
    WX_COMPUTE(wx);

    // phi + phiT write + k1
#pragma unroll
    for (int st = 0; st < 2; ++st)
#pragma unroll
      for (int mtl = 0; mtl < 2; ++mtl) {
        const int m = (2 * w + mtl) * 16 + l15;
        s16x4 hv;
        float psum = 0.f;
#pragma unroll
        for (int r = 0; r < 4; ++r) {
          const int s = st * 16 + lg * 4 + r;
          float p = __expf(wx[st][mtl][r] - diags[s] - stab) * CM;
          psum += p;
          hv[r] = (short)f2bf(p);
        }
        k1acc[mtl] += psum;
        *reinterpret_cast<s16x4*>(&phiTh[m][st * 16 + lg * 4]) = hv;
      }
    __syncthreads();  // bar2

    // kv contraction: A = phiT[m][s] (contiguous), B = V[s][d] (scalar gather)
    bf16x8 pah[2];
#pragma unroll
    for (int mtl = 0; mtl < 2; ++mtl)
      pah[mtl] = *reinterpret_cast<const bf16x8*>(
          &phiTh[(2 * w + mtl) * 16 + l15][lg * 8]);
#pragma unroll
    for (int dt = 0; dt < 4; ++dt) {
      bf16x8 bvh;
#pragma unroll
      for (int j = 0; j < 8; ++j)
        bvh[j] = (short)f2bf(Vs[lg * 8 + j][dt * 16 + l15]);
#pragma unroll
      for (int mtl = 0; mtl < 2; ++mtl) MFMAB(akv[mtl][dt], pah[mtl], bvh);
    }
    __syncthreads();  // bar3
  }

#pragma unroll
  for (int mtl = 0; mtl < 2; ++mtl) {
#pragma unroll
    for (int dt = 0; dt < 4; ++dt) {
      const int d = dt * 16 + l15, m0 = (2 * w + mtl) * 16 + lg * 4;
      *reinterpret_cast<f32x4*>(&kvpartT[(size_t)blk * 8192 + d * 128 + m0]) =
          akv[mtl][dt];
    }
    float kk = k1acc[mtl];
    kk += __shfl_xor(kk, 16);
    kk += __shfl_xor(kk, 32);
    if (lane < 16) k1part[blk * 128 + (2 * w + mtl) * 16 + lane] = kk;
  }
}

__global__ __launch_bounds__(256) void kvreduce_kernel(
    const float* __restrict__ kvpartT, const float* __restrict__ k1part,
    unsigned short* __restrict__ kvT, float* __restrict__ k1) {
  const int bh = blockIdx.x;
  for (int i = threadIdx.x; i < 8192; i += 256) {
    float s = 0.f;
#pragma unroll
    for (int c = 0; c < 8; ++c) s += kvpartT[(size_t)(bh * 8 + c) * 8192 + i];
    kvT[(size_t)bh * 8192 + i] = f2bf(s);
  }
  if (threadIdx.x < 128) {
    float s = 0.f;
#pragma unroll
    for (int c = 0; c < 8; ++c) s += k1part[(bh * 8 + c) * 128 + threadIdx.x];
    k1[bh * 128 + threadIdx.x] = s;
  }
}

// ---------------------------------------------------------------------------
// qkv: phi_q (per-row max) -> out^T[d][s] = sum_m kvT[d][m] phi[s][m] / denom.
// Writes out_h as fp16 (consumed only by the final GEMM).
// ---------------------------------------------------------------------------
__global__ __launch_bounds__(256) void qkv_mfma_kernel(
    const _Float16* __restrict__ qproj, const unsigned short* __restrict__ kvT,
    const float* __restrict__ k1g, const float* __restrict__ proj,
    _Float16* __restrict__ outh) {
  __shared__ unsigned short Xh[32][64];
  __shared__ unsigned short Ph[32][128];
  __shared__ float k1s[128];
  __shared__ float diags[32];
  __shared__ float rmaxp[4][32];
  __shared__ float denp[4][32];
  const int tid = threadIdx.x, blk = blockIdx.x;
  const int ch = blk & 15, bh = blk >> 4, b = bh >> 4, h = bh & 15;
  const int lane = tid & 63, w = tid >> 6;
  const int l15 = lane & 15, lg = lane >> 4;

  bf16x8 ph[2][2];
#pragma unroll
  for (int mtl = 0; mtl < 2; ++mtl)
#pragma unroll
    for (int ks = 0; ks < 2; ++ks)
      load_pfrag(proj, (2 * w + mtl) * 16 + l15, ks * 32 + lg * 8, &ph[mtl][ks]);

  // kvT A-fragments (constant per block): A[d = w*16+l15][m contiguous]
  bf16x8 kah[4];
#pragma unroll
  for (int ks = 0; ks < 4; ++ks) {
    const size_t o = (size_t)bh * 8192 + (w * 16 + l15) * 128 + ks * 32 + lg * 8;
    kah[ks] = *reinterpret_cast<const bf16x8*>(kvT + o);
  }
  if (tid < 128) k1s[tid] = k1g[bh * 128 + tid];

  const int srow = tid >> 3, q8 = (tid & 7) << 3;
  const int xc = ((q8 >> 3) ^ (srow & 7)) << 3;

  for (int batch = 0; batch < 8; ++batch) {
    const int s0 = ch * 256 + batch * 32;
    const size_t rb = (((size_t)(b * S_ + s0 + srow) * H_ + h)) << 6;
    STAGE_X(qproj + rb + q8, true);
    __syncthreads();  // bar1

    f32x4 wx[2][2];
#pragma unroll
    for (int st = 0; st < 2; ++st)
#pragma unroll
      for (int mtl = 0; mtl < 2; ++mtl) wx[st][mtl] = f32x4{0, 0, 0, 0};
    WX_COMPUTE(wx);

#pragma unroll
    for (int st = 0; st < 2; ++st)
#pragma unroll
      for (int r = 0; r < 4; ++r) {
        float v = fmaxf(wx[st][0][r], wx[st][1][r]);
        v = fmaxf(v, __shfl_xor(v, 1));
        v = fmaxf(v, __shfl_xor(v, 2));
        v = fmaxf(v, __shfl_xor(v, 4));
        v = fmaxf(v, __shfl_xor(v, 8));
        if (l15 == 0) rmaxp[w][st * 16 + lg * 4 + r] = v;
      }
    __syncthreads();  // bar2

#pragma unroll
    for (int st = 0; st < 2; ++st) {
      float off[4];
#pragma unroll
      for (int r = 0; r < 4; ++r) {
        const int s = st * 16 + lg * 4 + r;
        float rmx = fmaxf(fmaxf(rmaxp[0][s], rmaxp[1][s]),
                          fmaxf(rmaxp[2][s], rmaxp[3][s]));
        off[r] = rmx + diags[s];
      }
      float den[4] = {0.f, 0.f, 0.f, 0.f};
#pragma unroll
      for (int mtl = 0; mtl < 2; ++mtl) {
        const int m = (2 * w + mtl) * 16 + l15;
        const float k1v = k1s[m];
#pragma unroll
        for (int r = 0; r < 4; ++r) {
          const int s = st * 16 + lg * 4 + r;
          float p = __expf(wx[st][mtl][r] - off[r]) * CM;
          den[r] += p * k1v;
          Ph[s][((((m >> 3) ^ (s & 7)) << 3) | (m & 7))] = f2bf(p);
        }
      }
#pragma unroll
      for (int r = 0; r < 4; ++r) {
        float v = den[r];
        v += __shfl_xor(v, 1);
        v += __shfl_xor(v, 2);
        v += __shfl_xor(v, 4);
        v += __shfl_xor(v, 8);
        if (l15 == 0) denp[w][st * 16 + lg * 4 + r] = v;
      }
    }
    __syncthreads();  // bar3

#pragma unroll
    for (int st = 0; st < 2; ++st) {
      f32x4 od = {0.f, 0.f, 0.f, 0.f};
#pragma unroll
      for (int ks = 0; ks < 4; ++ks) {
        const int cc = ((ks * 4 + lg) ^ (l15 & 7)) << 3;
        bf16x8 bph = *reinterpret_cast<const bf16x8*>(&Ph[st * 16 + l15][cc]);
        MFMAB(od, kah[ks], bph);
      }
      const int s = st * 16 + l15;
      const float dens =
          1.f / (denp[0][s] + denp[1][s] + denp[2][s] + denp[3][s] + 1e-6f);
      f16x4 o;
#pragma unroll
      for (int j = 0; j < 4; ++j) o[j] = (_Float16)(od[j] * dens);
      *reinterpret_cast<f16x4*>(
          &outh[(size_t)(b * S_ + s0 + s) * 1024 + h * 64 + w * 16 + lg * 4]) = o;
    }
    __syncthreads();  // bar4
  }
}

// ---------------------------------------------------------------------------
extern "C" void kernel_launch(void* const* d_in, const int* in_sizes, int n_in,
                              void* d_out, int out_size, void* d_ws,
                              size_t ws_size, hipStream_t stream) {
  const float* query = (const float*)d_in[0];
  const float* value = (const float*)d_in[1];
  const float* key   = (const float*)d_in[2];
  const float* Wq = (const float*)d_in[3];
  const float* bq = (const float*)d_in[4];
  const float* Wk = (const float*)d_in[5];
  const float* bk = (const float*)d_in[6];
  const float* Wv = (const float*)d_in[7];
  const float* bv = (const float*)d_in[8];
  const float* Wo = (const float*)d_in[9];
  const float* bo = (const float*)d_in[10];
  const float* proj = (const float*)d_in[11];
  float* out = (float*)d_out;
  float* ws = (float*)d_ws;

  _Float16* KP16 = (_Float16*)(ws + OFF_A);   // kproj then qproj (fp16)
  _Float16* VP16 = (_Float16*)(ws + OFF_B);   // vproj (fp16)
  _Float16* WT = (_Float16*)(ws + OFF_X);
  float* KVPT = ws + OFF_X;
  float* K1P = ws + OFF_X + 4194304;
  unsigned short* KVT = (unsigned short*)(ws + OFF_KV);
  float* K1 = ws + OFF_K1;
  float* BMX = ws + OFF_BM;
  float* ST = ws + OFF_ST;
  _Float16* X16 = (_Float16*)(ws + OFF_A16);

  dim3 gw(32, 32);

  // 1. k_proj (fp16)
  cvt_f16_kernel<<<2048, 256, 0, stream>>>(key, X16);
  wt_f16_kernel<<<gw, 256, 0, stream>>>(Wk, WT);
  gemm_lds<1><<<1024, 256, 0, stream>>>(X16, WT, bk, KP16);
  // 2. stab
  wxmax_mfma_kernel<<<512, 256, 0, stream>>>(KP16, proj, BMX);
  maxreduce_kernel<<<1, 256, 0, stream>>>(BMX, ST, 512);
  // 3. v_proj (fp16)
  cvt_f16_kernel<<<2048, 256, 0, stream>>>(value, X16);
  wt_f16_kernel<<<gw, 256, 0, stream>>>(Wv, WT);
  gemm_lds<1><<<1024, 256, 0, stream>>>(X16, WT, bv, VP16);
  // 4. kv / k1 (KVPT aliases WT region; WT dead now)
  kv_mfma_kernel<<<512, 256, 0, stream>>>(KP16, VP16, proj, ST, KVPT, K1P);
  kvreduce_kernel<<<64, 256, 0, stream>>>(KVPT, K1P, KVT, K1);
  // 5. q_proj (KVPT dead after reduce; kproj dead after kv)
  cvt_f16_kernel<<<2048, 256, 0, stream>>>(query, X16);
  wt_f16_kernel<<<gw, 256, 0, stream>>>(Wq, WT);
  gemm_lds<1><<<1024, 256, 0, stream>>>(X16, WT, bq, KP16);
  // 6. out_h -> X16 as fp16 (query staging dead after q_proj gemm)
  qkv_mfma_kernel<<<1024, 256, 0, stream>>>(KP16, KVT, K1, proj, X16);
  // 7. output projection (f32 out)
  wt_f16_kernel<<<gw, 256, 0, stream>>>(Wo, WT);
  gemm_lds<0><<<1024, 256, 0, stream>>>(X16, WT, bo, out);
}

// Round 12
// 360.528 us; speedup vs baseline: 9.6900x; 1.1389x over previous
//
#include <hip/hip_runtime.h>
#include <hip/hip_bf16.h>

// Performer (FAVOR+) forward. Round 12: R11 + counted-vmcnt pipelined GEMM
// (4-deep LDS buffers, issue-ahead 2, s_waitcnt vmcnt(8) + raw s_barrier —
// never drains vmcnt to 0 in the main loop). Everything else identical to
// R11 (passed, 410us, absmax 9.77e-3).
// B=4, S=4096, D=1024, H=16, K=64, M=128.

#define B_  4
#define S_  4096
#define H_  16

#define SCALE_X 0.3535533905932738f     // 64^-0.25
#define CM      0.08838834764831845f    // 128^-0.5

typedef __attribute__((ext_vector_type(8))) short bf16x8;
typedef __attribute__((ext_vector_type(4))) short s16x4;
typedef __attribute__((ext_vector_type(8))) unsigned short u16x8;
typedef __attribute__((ext_vector_type(8))) _Float16 f16x8;
typedef __attribute__((ext_vector_type(4))) _Float16 f16x4;
typedef __attribute__((ext_vector_type(4))) float f32x4;

// ---- ws layout (float units) ----
#define OFF_A    ((size_t)0)          // kproj16 then qproj16 (fp16, 32MB)
#define OFF_B    ((size_t)16777216)   // vproj16 (fp16)
#define OFF_X    ((size_t)33554432)   // union: WT fp16 / kvpartT+k1part
#define OFF_KV   ((size_t)37814272)   // kvT bf16: 524288 ush
#define OFF_K1   ((size_t)38338560)   // 64*128 f32
#define OFF_BM   ((size_t)38346752)   // 512 block maxes
#define OFF_ST   ((size_t)38347264)   // stab scalar
#define OFF_A16  ((size_t)38347776)   // 16M fp16: GEMM A staging / outh
// total 46736384 f32 = 186.9 MB

__device__ __forceinline__ unsigned short f2bf(float x) {
  union { __hip_bfloat16 b; unsigned short u; } c;
  c.b = __float2bfloat16(x);
  return c.u;
}

#define MFMAB(ACC, A, B)                                               \
  ACC = __builtin_amdgcn_mfma_f32_16x16x32_bf16(A, B, ACC, 0, 0, 0)

#define GLDS(GP, LP)                                                  \
  __builtin_amdgcn_global_load_lds(                                   \
      (const __attribute__((address_space(1))) unsigned int*)(GP),    \
      (__attribute__((address_space(3))) unsigned int*)(LP), 16, 0, 0)

// load P-operand fragment (B for wx): lane supplies P[m][kb..kb+7] as bf16
__device__ __forceinline__ void load_pfrag(const float* __restrict__ proj, int m,
                                           int kb, bf16x8* ph) {
  const float* p = proj + m * 64 + kb;
  float4 a = *reinterpret_cast<const float4*>(p);
  float4 b = *reinterpret_cast<const float4*>(p + 4);
  float v[8] = {a.x, a.y, a.z, a.w, b.x, b.y, b.z, b.w};
  bf16x8 h;
#pragma unroll
  for (int j = 0; j < 8; ++j) h[j] = (short)f2bf(v[j]);
  *ph = h;
}

// Stage one X row-chunk from fp16 source: scale, bf16, chunk-XOR LDS write.
#define STAGE_X(PTR, WANT_DIAG)                                           \
  {                                                                       \
    f16x8 xv_ = *reinterpret_cast<const f16x8*>(PTR);                     \
    u16x8 hh_;                                                            \
    float sq_ = 0.f;                                                      \
    _Pragma("unroll") for (int j = 0; j < 8; ++j) {                       \
      float vf_ = (float)xv_[j] * SCALE_X;                                \
      sq_ += vf_ * vf_;                                                   \
      hh_[j] = f2bf(vf_);                                                 \
    }                                                                     \
    *reinterpret_cast<u16x8*>(&Xh[srow][xc]) = hh_;                       \
    if (WANT_DIAG) {                                                      \
      sq_ += __shfl_xor(sq_, 1);                                          \
      sq_ += __shfl_xor(sq_, 2);                                          \
      sq_ += __shfl_xor(sq_, 4);                                          \
      if ((tid & 7) == 0) diags[srow] = 0.5f * sq_;                       \
    }                                                                     \
  }

// wx MFMA block: 2 st x 2 ks x 2 mtl, single bf16 MFMA each.
#define WX_COMPUTE(WX)                                                       \
  _Pragma("unroll") for (int st_ = 0; st_ < 2; ++st_)                        \
  _Pragma("unroll") for (int ks_ = 0; ks_ < 2; ++ks_) {                      \
    const int rr_ = st_ * 16 + l15;                                          \
    const int cc_ = ((ks_ * 4 + lg) ^ (l15 & 7)) << 3;                       \
    bf16x8 xh_ = *reinterpret_cast<const bf16x8*>(&Xh[rr_][cc_]);            \
    _Pragma("unroll") for (int mtl_ = 0; mtl_ < 2; ++mtl_)                   \
        MFMAB(WX[st_][mtl_], xh_, ph[mtl_][ks_]);                            \
  }

// ---------------------------------------------------------------------------
// f32 -> fp16 conversion pass (16777216 elements).
// ---------------------------------------------------------------------------
__global__ __launch_bounds__(256) void cvt_f16_kernel(
    const float* __restrict__ in, _Float16* __restrict__ out) {
  const size_t stride = (size_t)gridDim.x * 256 * 8;
  for (size_t i = ((size_t)blockIdx.x * 256 + threadIdx.x) * 8; i < 16777216UL;
       i += stride) {
    float4 a = *reinterpret_cast<const float4*>(in + i);
    float4 b = *reinterpret_cast<const float4*>(in + i + 4);
    f16x8 h;
    h[0] = (_Float16)a.x; h[1] = (_Float16)a.y;
    h[2] = (_Float16)a.z; h[3] = (_Float16)a.w;
    h[4] = (_Float16)b.x; h[5] = (_Float16)b.y;
    h[6] = (_Float16)b.z; h[7] = (_Float16)b.w;
    *reinterpret_cast<f16x8*>(out + i) = h;
  }
}

// ---------------------------------------------------------------------------
// Weight transform: W[1024 k][1024 n] f32 -> WT [n][k] fp16.
// ---------------------------------------------------------------------------
__global__ __launch_bounds__(256) void wt_f16_kernel(
    const float* __restrict__ W, _Float16* __restrict__ T) {
  __shared__ float t[32][33];
  const int tx = threadIdx.x & 31, ty = threadIdx.x >> 5;
  const int k0 = blockIdx.x * 32, n0 = blockIdx.y * 32;
#pragma unroll
  for (int i = 0; i < 4; ++i)
    t[ty + 8 * i][tx] = W[(size_t)(k0 + ty + 8 * i) * 1024 + n0 + tx];
  __syncthreads();
#pragma unroll
  for (int i = 0; i < 4; ++i)
    T[(size_t)(n0 + ty + 8 * i) * 1024 + k0 + tx] = (_Float16)t[tx][ty + 8 * i];
}

// ---------------------------------------------------------------------------
// Pipelined fp16 GEMM: 4-deep LDS buffers, issue-ahead 2, counted vmcnt.
// Hazard audit (one barrier/iter, wave skew <= 1 iter):
//   writer at kt targets buf (kt+2)&3; concurrent readers touch kt&3 or
//   (kt-1)&3 — all distinct mod 4. vmcnt(8) leaves the 2 newest iterations'
//   loads (8) in flight, guarantees the oldest 4 (this iteration's buf)
//   landed; barrier makes that true for all 256 threads.
// Swizzle c ^ ((r>>1)&3) both sides (2-way banks = free, R11-verified).
// ---------------------------------------------------------------------------
template <int F16OUT>
__global__ __launch_bounds__(256) void gemm_lds(
    const _Float16* __restrict__ A16, const _Float16* __restrict__ BT,
    const float* __restrict__ bias, void* __restrict__ Cout) {
  __shared__ _Float16 As[4][128][32];
  __shared__ _Float16 Bs[4][128][32];
  const int tid = threadIdx.x;
  const int bid = blockIdx.x;
  const int m0 = (bid & 127) << 7;
  const int n0 = (bid >> 7) << 7;
  const int wave = tid >> 6, lane = tid & 63;
  const int wm = (wave >> 1) << 6, wn = (wave & 1) << 6;
  const int l15 = lane & 15, lg = lane >> 4;

  const int rlo = tid >> 2;
  const int cg = ((tid & 3) ^ ((rlo >> 1) & 3)) << 3;  // pre-swizzled source
  const int wqbase = wave << 10;

  const _Float16* pa = A16 + (size_t)(m0 + rlo) * 1024 + cg;
  const _Float16* pb = BT + (size_t)(n0 + rlo) * 1024 + cg;

  f32x4 acc[4][4];
#pragma unroll
  for (int i = 0; i < 4; ++i)
#pragma unroll
    for (int j = 0; j < 4; ++j) acc[i][j] = f32x4{0.f, 0.f, 0.f, 0.f};

#define STAGE_T(nb, kt)                                                   \
  {                                                                       \
    char* la = (char*)&As[nb][0][0] + wqbase;                             \
    char* lb = (char*)&Bs[nb][0][0] + wqbase;                             \
    GLDS(pa + (kt) * 32, la);                                             \
    GLDS(pa + (kt) * 32 + 65536, la + 4096);                              \
    GLDS(pb + (kt) * 32, lb);                                             \
    GLDS(pb + (kt) * 32 + 65536, lb + 4096);                              \
  }

#define PIPE_BAR(N)                                                       \
  asm volatile("s_waitcnt vmcnt(" #N ")" ::: "memory");                   \
  __builtin_amdgcn_s_barrier();                                           \
  asm volatile("" ::: "memory");                                          \
  __builtin_amdgcn_sched_barrier(0);

#define COMPUTE(cur)                                                      \
  {                                                                       \
    f16x8 bf[4];                                                          \
    _Pragma("unroll") for (int fn = 0; fn < 4; ++fn) {                    \
      const int r = wn + fn * 16 + l15;                                   \
      bf[fn] = *reinterpret_cast<const f16x8*>(                           \
          &Bs[cur][r][(lg ^ ((r >> 1) & 3)) << 3]);                       \
    }                                                                     \
    _Pragma("unroll") for (int fm = 0; fm < 4; ++fm) {                    \
      const int r = wm + fm * 16 + l15;                                   \
      f16x8 av = *reinterpret_cast<const f16x8*>(                         \
          &As[cur][r][(lg ^ ((r >> 1) & 3)) << 3]);                       \
      _Pragma("unroll") for (int fn = 0; fn < 4; ++fn)                    \
        acc[fm][fn] = __builtin_amdgcn_mfma_f32_16x16x32_f16(             \
            av, bf[fn], acc[fm][fn], 0, 0, 0);                            \
    }                                                                     \
  }

  STAGE_T(0, 0);
  STAGE_T(1, 1);

  for (int kt = 0; kt < 30; ++kt) {
    STAGE_T((kt + 2) & 3, kt + 2);
    PIPE_BAR(8);
    COMPUTE(kt & 3);
  }
  PIPE_BAR(4);
  COMPUTE(2);  // kt = 30
  PIPE_BAR(0);
  COMPUTE(3);  // kt = 31

#pragma unroll
  for (int fm = 0; fm < 4; ++fm) {
    const int row = m0 + wm + fm * 16 + (lg << 2);
#pragma unroll
    for (int fn = 0; fn < 4; ++fn) {
      const int col = n0 + wn + fn * 16 + l15;
      const float bc = bias[col];
      f32x4 v = acc[fm][fn];
      if (F16OUT) {
        _Float16* C = (_Float16*)Cout;
#pragma unroll
        for (int j = 0; j < 4; ++j)
          C[(size_t)(row + j) * 1024 + col] = (_Float16)(v[j] + bc);
      } else {
        float* C = (float*)Cout;
#pragma unroll
        for (int j = 0; j < 4; ++j) C[(size_t)(row + j) * 1024 + col] = v[j] + bc;
      }
    }
  }
#undef STAGE_T
#undef PIPE_BAR
#undef COMPUTE
}

// ---------------------------------------------------------------------------
// wxmax: global max of wx_k via MFMA. 512 blocks x 512 flat rows.
// ---------------------------------------------------------------------------
__global__ __launch_bounds__(256) void wxmax_mfma_kernel(
    const _Float16* __restrict__ kproj, const float* __restrict__ proj,
    float* __restrict__ blockmax) {
  __shared__ unsigned short Xh[32][64];
  __shared__ float diags[32];  // unused (WANT_DIAG=false)
  __shared__ float redw[4];
  const int tid = threadIdx.x, blk = blockIdx.x;
  const int lane = tid & 63, w = tid >> 6;
  const int l15 = lane & 15, lg = lane >> 4;
  (void)diags;

  bf16x8 ph[2][2];
#pragma unroll
  for (int mtl = 0; mtl < 2; ++mtl)
#pragma unroll
    for (int ks = 0; ks < 2; ++ks)
      load_pfrag(proj, (2 * w + mtl) * 16 + l15, ks * 32 + lg * 8, &ph[mtl][ks]);

  float gmax = -3.4e38f;
  const int srow = tid >> 3, q8 = (tid & 7) << 3;
  const int xc = ((q8 >> 3) ^ (srow & 7)) << 3;

  for (int batch = 0; batch < 16; ++batch) {
    const int row0 = blk * 512 + batch * 32;
    STAGE_X(kproj + (size_t)(row0 + srow) * 64 + q8, false);
    __syncthreads();
    f32x4 wx[2][2];
#pragma unroll
    for (int st = 0; st < 2; ++st)
#pragma unroll
      for (int mtl = 0; mtl < 2; ++mtl) wx[st][mtl] = f32x4{0, 0, 0, 0};
    WX_COMPUTE(wx);
#pragma unroll
    for (int st = 0; st < 2; ++st)
#pragma unroll
      for (int mtl = 0; mtl < 2; ++mtl)
#pragma unroll
        for (int r = 0; r < 4; ++r) gmax = fmaxf(gmax, wx[st][mtl][r]);
    __syncthreads();
  }
#pragma unroll
  for (int off = 32; off; off >>= 1) gmax = fmaxf(gmax, __shfl_xor(gmax, off));
  if (lane == 0) redw[w] = gmax;
  __syncthreads();
  if (tid == 0)
    blockmax[blk] = fmaxf(fmaxf(redw[0], redw[1]), fmaxf(redw[2], redw[3]));
}

__global__ __launch_bounds__(256) void maxreduce_kernel(
    const float* __restrict__ blockmax, float* __restrict__ stab, int n) {
  __shared__ float sm[256];
  float v = -3.4e38f;
  for (int i = threadIdx.x; i < n; i += 256) v = fmaxf(v, blockmax[i]);
  sm[threadIdx.x] = v;
  __syncthreads();
  for (int s = 128; s; s >>= 1) {
    if (threadIdx.x < s)
      sm[threadIdx.x] = fmaxf(sm[threadIdx.x], sm[threadIdx.x + s]);
    __syncthreads();
  }
  if (threadIdx.x == 0) *stab = sm[0];
}

// ---------------------------------------------------------------------------
// kv: kv[m][d] = sum_s phi_k[s][m] V[s][d], plus k1[m].
// ---------------------------------------------------------------------------
__global__ __launch_bounds__(256) void kv_mfma_kernel(
    const _Float16* __restrict__ kproj, const _Float16* __restrict__ vproj,
    const float* __restrict__ proj, const float* __restrict__ stabp,
    float* __restrict__ kvpartT, float* __restrict__ k1part) {
  __shared__ unsigned short Xh[32][64];
  __shared__ float Vs[32][66];
  __shared__ unsigned short phiTh[128][40];
  __shared__ float diags[32];
  const int tid = threadIdx.x, blk = blockIdx.x;
  const int c = blk & 7, bh = blk >> 3, b = bh >> 4, h = bh & 15;
  const int lane = tid & 63, w = tid >> 6;
  const int l15 = lane & 15, lg = lane >> 4;
  const float stab = *stabp;

  bf16x8 ph[2][2];
#pragma unroll
  for (int mtl = 0; mtl < 2; ++mtl)
#pragma unroll
    for (int ks = 0; ks < 2; ++ks)
      load_pfrag(proj, (2 * w + mtl) * 16 + l15, ks * 32 + lg * 8, &ph[mtl][ks]);

  f32x4 akv[2][4];
#pragma unroll
  for (int i = 0; i < 2; ++i)
#pragma unroll
    for (int j = 0; j < 4; ++j) akv[i][j] = f32x4{0, 0, 0, 0};
  float k1acc[2] = {0.f, 0.f};

  const int srow = tid >> 3, q8 = (tid & 7) << 3;
  const int xc = ((q8 >> 3) ^ (srow & 7)) << 3;

  for (int batch = 0; batch < 16; ++batch) {
    const int s0 = c * 512 + batch * 32;
    const size_t rb = (((size_t)(b * S_ + s0 + srow) * H_ + h)) << 6;
    STAGE_X(kproj + rb + q8, true);
    {
      f16x8 vv = *reinterpret_cast<const f16x8*>(vproj + rb + q8);
#pragma unroll
      for (int j = 0; j < 8; ++j) Vs[srow][q8 + j] = (float)vv[j];
    }
    __syncthreads();  // bar1

    f32x4 wx[2][2];
#pragma unroll
    for (int st = 0; st < 2; ++st)
#pragma unroll
      for (int mtl = 0; mtl < 2; ++mtl) wx[st][mtl] = f32x4{0, 0, 0, 0};
    WX_COMPUTE(wx);

    // phi + phiT write + k1
#pragma unroll
    for (int st = 0; st < 2; ++st)
#pragma unroll
      for (int mtl = 0; mtl < 2; ++mtl) {
        const int m = (2 * w + mtl) * 16 + l15;
        s16x4 hv;
        float psum = 0.f;
#pragma unroll
        for (int r = 0; r < 4; ++r) {
          const int s = st * 16 + lg * 4 + r;
          float p = __expf(wx[st][mtl][r] - diags[s] - stab) * CM;
          psum += p;
          hv[r] = (short)f2bf(p);
        }
        k1acc[mtl] += psum;
        *reinterpret_cast<s16x4*>(&phiTh[m][st * 16 + lg * 4]) = hv;
      }
    __syncthreads();  // bar2

    // kv contraction: A = phiT[m][s] (contiguous), B = V[s][d] (scalar gather)
    bf16x8 pah[2];
#pragma unroll
    for (int mtl = 0; mtl < 2; ++mtl)
      pah[mtl] = *reinterpret_cast<const bf16x8*>(
          &phiTh[(2 * w + mtl) * 16 + l15][lg * 8]);
#pragma unroll
    for (int dt = 0; dt < 4; ++dt) {
      bf16x8 bvh;
#pragma unroll
      for (int j = 0; j < 8; ++j)
        bvh[j] = (short)f2bf(Vs[lg * 8 + j][dt * 16 + l15]);
#pragma unroll
      for (int mtl = 0; mtl < 2; ++mtl) MFMAB(akv[mtl][dt], pah[mtl], bvh);
    }
    __syncthreads();  // bar3
  }

#pragma unroll
  for (int mtl = 0; mtl < 2; ++mtl) {
#pragma unroll
    for (int dt = 0; dt < 4; ++dt) {
      const int d = dt * 16 + l15, m0 = (2 * w + mtl) * 16 + lg * 4;
      *reinterpret_cast<f32x4*>(&kvpartT[(size_t)blk * 8192 + d * 128 + m0]) =
          akv[mtl][dt];
    }
    float kk = k1acc[mtl];
    kk += __shfl_xor(kk, 16);
    kk += __shfl_xor(kk, 32);
    if (lane < 16) k1part[blk * 128 + (2 * w + mtl) * 16 + lane] = kk;
  }
}

__global__ __launch_bounds__(256) void kvreduce_kernel(
    const float* __restrict__ kvpartT, const float* __restrict__ k1part,
    unsigned short* __restrict__ kvT, float* __restrict__ k1) {
  const int bh = blockIdx.x;
  for (int i = threadIdx.x; i < 8192; i += 256) {
    float s = 0.f;
#pragma unroll
    for (int c = 0; c < 8; ++c) s += kvpartT[(size_t)(bh * 8 + c) * 8192 + i];
    kvT[(size_t)bh * 8192 + i] = f2bf(s);
  }
  if (threadIdx.x < 128) {
    float s = 0.f;
#pragma unroll
    for (int c = 0; c < 8; ++c) s += k1part[(bh * 8 + c) * 128 + threadIdx.x];
    k1[bh * 128 + threadIdx.x] = s;
  }
}

// ---------------------------------------------------------------------------
// qkv: phi_q (per-row max) -> out^T[d][s] = sum_m kvT[d][m] phi[s][m] / denom.
// Writes out_h as fp16 (consumed only by the final GEMM).
// ---------------------------------------------------------------------------
__global__ __launch_bounds__(256) void qkv_mfma_kernel(
    const _Float16* __restrict__ qproj, const unsigned short* __restrict__ kvT,
    const float* __restrict__ k1g, const float* __restrict__ proj,
    _Float16* __restrict__ outh) {
  __shared__ unsigned short Xh[32][64];
  __shared__ unsigned short Ph[32][128];
  __shared__ float k1s[128];
  __shared__ float diags[32];
  __shared__ float rmaxp[4][32];
  __shared__ float denp[4][32];
  const int tid = threadIdx.x, blk = blockIdx.x;
  const int ch = blk & 15, bh = blk >> 4, b = bh >> 4, h = bh & 15;
  const int lane = tid & 63, w = tid >> 6;
  const int l15 = lane & 15, lg = lane >> 4;

  bf16x8 ph[2][2];
#pragma unroll
  for (int mtl = 0; mtl < 2; ++mtl)
#pragma unroll
    for (int ks = 0; ks < 2; ++ks)
      load_pfrag(proj, (2 * w + mtl) * 16 + l15, ks * 32 + lg * 8, &ph[mtl][ks]);

  // kvT A-fragments (constant per block): A[d = w*16+l15][m contiguous]
  bf16x8 kah[4];
#pragma unroll
  for (int ks = 0; ks < 4; ++ks) {
    const size_t o = (size_t)bh * 8192 + (w * 16 + l15) * 128 + ks * 32 + lg * 8;
    kah[ks] = *reinterpret_cast<const bf16x8*>(kvT + o);
  }
  if (tid < 128) k1s[tid] = k1g[bh * 128 + tid];

  const int srow = tid >> 3, q8 = (tid & 7) << 3;
  const int xc = ((q8 >> 3) ^ (srow & 7)) << 3;

  for (int batch = 0; batch < 8; ++batch) {
    const int s0 = ch * 256 + batch * 32;
    const size_t rb = (((size_t)(b * S_ + s0 + srow) * H_ + h)) << 6;
    STAGE_X(qproj + rb + q8, true);
    __syncthreads();  // bar1

    f32x4 wx[2][2];
#pragma unroll
    for (int st = 0; st < 2; ++st)
#pragma unroll
      for (int mtl = 0; mtl < 2; ++mtl) wx[st][mtl] = f32x4{0, 0, 0, 0};
    WX_COMPUTE(wx);

#pragma unroll
    for (int st = 0; st < 2; ++st)
#pragma unroll
      for (int r = 0; r < 4; ++r) {
        float v = fmaxf(wx[st][0][r], wx[st][1][r]);
        v = fmaxf(v, __shfl_xor(v, 1));
        v = fmaxf(v, __shfl_xor(v, 2));
        v = fmaxf(v, __shfl_xor(v, 4));
        v = fmaxf(v, __shfl_xor(v, 8));
        if (l15 == 0) rmaxp[w][st * 16 + lg * 4 + r] = v;
      }
    __syncthreads();  // bar2

#pragma unroll
    for (int st = 0; st < 2; ++st) {
      float off[4];
#pragma unroll
      for (int r = 0; r < 4; ++r) {
        const int s = st * 16 + lg * 4 + r;
        float rmx = fmaxf(fmaxf(rmaxp[0][s], rmaxp[1][s]),
                          fmaxf(rmaxp[2][s], rmaxp[3][s]));
        off[r] = rmx + diags[s];
      }
      float den[4] = {0.f, 0.f, 0.f, 0.f};
#pragma unroll
      for (int mtl = 0; mtl < 2; ++mtl) {
        const int m = (2 * w + mtl) * 16 + l15;
        const float k1v = k1s[m];
#pragma unroll
        for (int r = 0; r < 4; ++r) {
          const int s = st * 16 + lg * 4 + r;
          float p = __expf(wx[st][mtl][r] - off[r]) * CM;
          den[r] += p * k1v;
          Ph[s][((((m >> 3) ^ (s & 7)) << 3) | (m & 7))] = f2bf(p);
        }
      }
#pragma unroll
      for (int r = 0; r < 4; ++r) {
        float v = den[r];
        v += __shfl_xor(v, 1);
        v += __shfl_xor(v, 2);
        v += __shfl_xor(v, 4);
        v += __shfl_xor(v, 8);
        if (l15 == 0) denp[w][st * 16 + lg * 4 + r] = v;
      }
    }
    __syncthreads();  // bar3

#pragma unroll
    for (int st = 0; st < 2; ++st) {
      f32x4 od = {0.f, 0.f, 0.f, 0.f};
#pragma unroll
      for (int ks = 0; ks < 4; ++ks) {
        const int cc = ((ks * 4 + lg) ^ (l15 & 7)) << 3;
        bf16x8 bph = *reinterpret_cast<const bf16x8*>(&Ph[st * 16 + l15][cc]);
        MFMAB(od, kah[ks], bph);
      }
      const int s = st * 16 + l15;
      const float dens =
          1.f / (denp[0][s] + denp[1][s] + denp[2][s] + denp[3][s] + 1e-6f);
      f16x4 o;
#pragma unroll
      for (int j = 0; j < 4; ++j) o[j] = (_Float16)(od[j] * dens);
      *reinterpret_cast<f16x4*>(
          &outh[(size_t)(b * S_ + s0 + s) * 1024 + h * 64 + w * 16 + lg * 4]) = o;
    }
    __syncthreads();  // bar4
  }
}

// ---------------------------------------------------------------------------
extern "C" void kernel_launch(void* const* d_in, const int* in_sizes, int n_in,
                              void* d_out, int out_size, void* d_ws,
                              size_t ws_size, hipStream_t stream) {
  const float* query = (const float*)d_in[0];
  const float* value = (const float*)d_in[1];
  const float* key   = (const float*)d_in[2];
  const float* Wq = (const float*)d_in[3];
  const float* bq = (const float*)d_in[4];
  const float* Wk = (const float*)d_in[5];
  const float* bk = (const float*)d_in[6];
  const float* Wv = (const float*)d_in[7];
  const float* bv = (const float*)d_in[8];
  const float* Wo = (const float*)d_in[9];
  const float* bo = (const float*)d_in[10];
  const float* proj = (const float*)d_in[11];
  float* out = (float*)d_out;
  float* ws = (float*)d_ws;

  _Float16* KP16 = (_Float16*)(ws + OFF_A);   // kproj then qproj (fp16)
  _Float16* VP16 = (_Float16*)(ws + OFF_B);   // vproj (fp16)
  _Float16* WT = (_Float16*)(ws + OFF_X);
  float* KVPT = ws + OFF_X;
  float* K1P = ws + OFF_X + 4194304;
  unsigned short* KVT = (unsigned short*)(ws + OFF_KV);
  float* K1 = ws + OFF_K1;
  float* BMX = ws + OFF_BM;
  float* ST = ws + OFF_ST;
  _Float16* X16 = (_Float16*)(ws + OFF_A16);

  dim3 gw(32, 32);

  // 1. k_proj (fp16)
  cvt_f16_kernel<<<2048, 256, 0, stream>>>(key, X16);
  wt_f16_kernel<<<gw, 256, 0, stream>>>(Wk, WT);
  gemm_lds<1><<<1024, 256, 0, stream>>>(X16, WT, bk, KP16);
  // 2. stab
  wxmax_mfma_kernel<<<512, 256, 0, stream>>>(KP16, proj, BMX);
  maxreduce_kernel<<<1, 256, 0, stream>>>(BMX, ST, 512);
  // 3. v_proj (fp16)
  cvt_f16_kernel<<<2048, 256, 0, stream>>>(value, X16);
  wt_f16_kernel<<<gw, 256, 0, stream>>>(Wv, WT);
  gemm_lds<1><<<1024, 256, 0, stream>>>(X16, WT, bv, VP16);
  // 4. kv / k1 (KVPT aliases WT region; WT dead now)
  kv_mfma_kernel<<<512, 256, 0, stream>>>(KP16, VP16, proj, ST, KVPT, K1P);
  kvreduce_kernel<<<64, 256, 0, stream>>>(KVPT, K1P, KVT, K1);
  // 5. q_proj (KVPT dead after reduce; kproj dead after kv)
  cvt_f16_kernel<<<2048, 256, 0, stream>>>(query, X16);
  wt_f16_kernel<<<gw, 256, 0, stream>>>(Wq, WT);
  gemm_lds<1><<<1024, 256, 0, stream>>>(X16, WT, bq, KP16);
  // 6. out_h -> X16 as fp16 (query staging dead after q_proj gemm)
  qkv_mfma_kernel<<<1024, 256, 0, stream>>>(KP16, KVT, K1, proj, X16);
  // 7. output projection (f32 out)
  wt_f16_kernel<<<gw, 256, 0, stream>>>(Wo, WT);
  gemm_lds<0><<<1024, 256, 0, stream>>>(X16, WT, bo, out);
}

// Round 14
// 358.530 us; speedup vs baseline: 9.7440x; 1.0056x over previous
//
#include <hip/hip_runtime.h>
#include <hip/hip_bf16.h>

// Performer (FAVOR+) forward. Round 14: R12 numerics EXACTLY (reference phi
// scales must be preserved — the reference's +1e-6 epsilon dominates its
// denominator, so stab/CM/diag rescalings do NOT cancel). Only change vs
// R12: finer grids for kv (1024 blocks) and qkv (2048 blocks), with kv
// partials relocated to the dead A16 staging region.
// B=4, S=4096, D=1024, H=16, K=64, M=128.

#define B_  4
#define S_  4096
#define H_  16

#define SCALE_X 0.3535533905932738f     // 64^-0.25
#define CM      0.08838834764831845f    // 128^-0.5

typedef __attribute__((ext_vector_type(8))) short bf16x8;
typedef __attribute__((ext_vector_type(4))) short s16x4;
typedef __attribute__((ext_vector_type(8))) unsigned short u16x8;
typedef __attribute__((ext_vector_type(8))) _Float16 f16x8;
typedef __attribute__((ext_vector_type(4))) _Float16 f16x4;
typedef __attribute__((ext_vector_type(4))) float f32x4;

// ---- ws layout (float units) ----
#define OFF_A    ((size_t)0)          // kproj16 then qproj16 (fp16, 32MB)
#define OFF_B    ((size_t)16777216)   // vproj16 (fp16)
#define OFF_X    ((size_t)33554432)   // union: WT fp16 / k1part(131072)
#define OFF_KV   ((size_t)37814272)   // kvT bf16: 524288 ush
#define OFF_K1   ((size_t)38338560)   // 64*128 f32
#define OFF_BM   ((size_t)38346752)   // 512 block maxes
#define OFF_ST   ((size_t)38347264)   // stab scalar
#define OFF_A16  ((size_t)38347776)   // 8388608 f32: GEMM A staging / kvpartT
// total 46736384 f32 = 186.9 MB

__device__ __forceinline__ unsigned short f2bf(float x) {
  union { __hip_bfloat16 b; unsigned short u; } c;
  c.b = __float2bfloat16(x);
  return c.u;
}

#define MFMAB(ACC, A, B)                                               \
  ACC = __builtin_amdgcn_mfma_f32_16x16x32_bf16(A, B, ACC, 0, 0, 0)

#define GLDS(GP, LP)                                                  \
  __builtin_amdgcn_global_load_lds(                                   \
      (const __attribute__((address_space(1))) unsigned int*)(GP),    \
      (__attribute__((address_space(3))) unsigned int*)(LP), 16, 0, 0)

// load P-operand fragment (B for wx): lane supplies P[m][kb..kb+7] as bf16
__device__ __forceinline__ void load_pfrag(const float* __restrict__ proj, int m,
                                           int kb, bf16x8* ph) {
  const float* p = proj + m * 64 + kb;
  float4 a = *reinterpret_cast<const float4*>(p);
  float4 b = *reinterpret_cast<const float4*>(p + 4);
  float v[8] = {a.x, a.y, a.z, a.w, b.x, b.y, b.z, b.w};
  bf16x8 h;
#pragma unroll
  for (int j = 0; j < 8; ++j) h[j] = (short)f2bf(v[j]);
  *ph = h;
}

// Stage one X row-chunk from fp16 source: scale, bf16, chunk-XOR LDS write.
#define STAGE_X(PTR, WANT_DIAG)                                           \
  {                                                                       \
    f16x8 xv_ = *reinterpret_cast<const f16x8*>(PTR);                     \
    u16x8 hh_;                                                            \
    float sq_ = 0.f;                                                      \
    _Pragma("unroll") for (int j = 0; j < 8; ++j) {                       \
      float vf_ = (float)xv_[j] * SCALE_X;                                \
      sq_ += vf_ * vf_;                                                   \
      hh_[j] = f2bf(vf_);                                                 \
    }                                                                     \
    *reinterpret_cast<u16x8*>(&Xh[srow][xc]) = hh_;                       \
    if (WANT_DIAG) {                                                      \
      sq_ += __shfl_xor(sq_, 1);                                          \
      sq_ += __shfl_xor(sq_, 2);                                          \
      sq_ += __shfl_xor(sq_, 4);                                          \
      if ((tid & 7) == 0) diags[srow] = 0.5f * sq_;                       \
    }                                                                     \
  }

// wx MFMA block: 2 st x 2 ks x 2 mtl, single bf16 MFMA each.
#define WX_COMPUTE(WX)                                                       \
  _Pragma("unroll") for (int st_ = 0; st_ < 2; ++st_)                        \
  _Pragma("unroll") for (int ks_ = 0; ks_ < 2; ++ks_) {                      \
    const int rr_ = st_ * 16 + l15;                                          \
    const int cc_ = ((ks_ * 4 + lg) ^ (l15 & 7)) << 3;                       \
    bf16x8 xh_ = *reinterpret_cast<const bf16x8*>(&Xh[rr_][cc_]);            \
    _Pragma("unroll") for (int mtl_ = 0; mtl_ < 2; ++mtl_)                   \
        MFMAB(WX[st_][mtl_], xh_, ph[mtl_][ks_]);                            \
  }

// ---------------------------------------------------------------------------
// f32 -> fp16 conversion pass (16777216 elements).
// ---------------------------------------------------------------------------
__global__ __launch_bounds__(256) void cvt_f16_kernel(
    const float* __restrict__ in, _Float16* __restrict__ out) {
  const size_t stride = (size_t)gridDim.x * 256 * 8;
  for (size_t i = ((size_t)blockIdx.x * 256 + threadIdx.x) * 8; i < 16777216UL;
       i += stride) {
    float4 a = *reinterpret_cast<const float4*>(in + i);
    float4 b = *reinterpret_cast<const float4*>(in + i + 4);
    f16x8 h;
    h[0] = (_Float16)a.x; h[1] = (_Float16)a.y;
    h[2] = (_Float16)a.z; h[3] = (_Float16)a.w;
    h[4] = (_Float16)b.x; h[5] = (_Float16)b.y;
    h[6] = (_Float16)b.z; h[7] = (_Float16)b.w;
    *reinterpret_cast<f16x8*>(out + i) = h;
  }
}

// ---------------------------------------------------------------------------
// Weight transform: W[1024 k][1024 n] f32 -> WT [n][k] fp16.
// ---------------------------------------------------------------------------
__global__ __launch_bounds__(256) void wt_f16_kernel(
    const float* __restrict__ W, _Float16* __restrict__ T) {
  __shared__ float t[32][33];
  const int tx = threadIdx.x & 31, ty = threadIdx.x >> 5;
  const int k0 = blockIdx.x * 32, n0 = blockIdx.y * 32;
#pragma unroll
  for (int i = 0; i < 4; ++i)
    t[ty + 8 * i][tx] = W[(size_t)(k0 + ty + 8 * i) * 1024 + n0 + tx];
  __syncthreads();
#pragma unroll
  for (int i = 0; i < 4; ++i)
    T[(size_t)(n0 + ty + 8 * i) * 1024 + k0 + tx] = (_Float16)t[tx][ty + 8 * i];
}

// ---------------------------------------------------------------------------
// Pipelined fp16 GEMM (R12, verified): 4-deep LDS, issue-ahead 2, vmcnt(8).
// ---------------------------------------------------------------------------
template <int F16OUT>
__global__ __launch_bounds__(256) void gemm_lds(
    const _Float16* __restrict__ A16, const _Float16* __restrict__ BT,
    const float* __restrict__ bias, void* __restrict__ Cout) {
  __shared__ _Float16 As[4][128][32];
  __shared__ _Float16 Bs[4][128][32];
  const int tid = threadIdx.x;
  const int bid = blockIdx.x;
  const int m0 = (bid & 127) << 7;
  const int n0 = (bid >> 7) << 7;
  const int wave = tid >> 6, lane = tid & 63;
  const int wm = (wave >> 1) << 6, wn = (wave & 1) << 6;
  const int l15 = lane & 15, lg = lane >> 4;

  const int rlo = tid >> 2;
  const int cg = ((tid & 3) ^ ((rlo >> 1) & 3)) << 3;
  const int wqbase = wave << 10;

  const _Float16* pa = A16 + (size_t)(m0 + rlo) * 1024 + cg;
  const _Float16* pb = BT + (size_t)(n0 + rlo) * 1024 + cg;

  f32x4 acc[4][4];
#pragma unroll
  for (int i = 0; i < 4; ++i)
#pragma unroll
    for (int j = 0; j < 4; ++j) acc[i][j] = f32x4{0.f, 0.f, 0.f, 0.f};

#define STAGE_T(nb, kt)                                                   \
  {                                                                       \
    char* la = (char*)&As[nb][0][0] + wqbase;                             \
    char* lb = (char*)&Bs[nb][0][0] + wqbase;                             \
    GLDS(pa + (kt) * 32, la);                                             \
    GLDS(pa + (kt) * 32 + 65536, la + 4096);                              \
    GLDS(pb + (kt) * 32, lb);                                             \
    GLDS(pb + (kt) * 32 + 65536, lb + 4096);                              \
  }

#define PIPE_BAR(N)                                                       \
  asm volatile("s_waitcnt vmcnt(" #N ")" ::: "memory");                   \
  __builtin_amdgcn_s_barrier();                                           \
  asm volatile("" ::: "memory");                                          \
  __builtin_amdgcn_sched_barrier(0);

#define COMPUTE(cur)                                                      \
  {                                                                       \
    f16x8 bf[4];                                                          \
    _Pragma("unroll") for (int fn = 0; fn < 4; ++fn) {                    \
      const int r = wn + fn * 16 + l15;                                   \
      bf[fn] = *reinterpret_cast<const f16x8*>(                           \
          &Bs[cur][r][(lg ^ ((r >> 1) & 3)) << 3]);                       \
    }                                                                     \
    _Pragma("unroll") for (int fm = 0; fm < 4; ++fm) {                    \
      const int r = wm + fm * 16 + l15;                                   \
      f16x8 av = *reinterpret_cast<const f16x8*>(                         \
          &As[cur][r][(lg ^ ((r >> 1) & 3)) << 3]);                       \
      _Pragma("unroll") for (int fn = 0; fn < 4; ++fn)                    \
        acc[fm][fn] = __builtin_amdgcn_mfma_f32_16x16x32_f16(             \
            av, bf[fn], acc[fm][fn], 0, 0, 0);                            \
    }                                                                     \
  }

  STAGE_T(0, 0);
  STAGE_T(1, 1);

  for (int kt = 0; kt < 30; ++kt) {
    STAGE_T((kt + 2) & 3, kt + 2);
    PIPE_BAR(8);
    COMPUTE(kt & 3);
  }
  PIPE_BAR(4);
  COMPUTE(2);  // kt = 30
  PIPE_BAR(0);
  COMPUTE(3);  // kt = 31

#pragma unroll
  for (int fm = 0; fm < 4; ++fm) {
    const int row = m0 + wm + fm * 16 + (lg << 2);
#pragma unroll
    for (int fn = 0; fn < 4; ++fn) {
      const int col = n0 + wn + fn * 16 + l15;
      const float bc = bias[col];
      f32x4 v = acc[fm][fn];
      if (F16OUT) {
        _Float16* C = (_Float16*)Cout;
#pragma unroll
        for (int j = 0; j < 4; ++j)
          C[(size_t)(row + j) * 1024 + col] = (_Float16)(v[j] + bc);
      } else {
        float* C = (float*)Cout;
#pragma unroll
        for (int j = 0; j < 4; ++j) C[(size_t)(row + j) * 1024 + col] = v[j] + bc;
      }
    }
  }
#undef STAGE_T
#undef PIPE_BAR
#undef COMPUTE
}

// ---------------------------------------------------------------------------
// wxmax: global max of wx_k via MFMA (reference stabilizer). 512 blocks.
// ---------------------------------------------------------------------------
__global__ __launch_bounds__(256) void wxmax_mfma_kernel(
    const _Float16* __restrict__ kproj, const float* __restrict__ proj,
    float* __restrict__ blockmax) {
  __shared__ unsigned short Xh[32][64];
  __shared__ float diags[32];  // unused (WANT_DIAG=false)
  __shared__ float redw[4];
  const int tid = threadIdx.x, blk = blockIdx.x;
  const int lane = tid & 63, w = tid >> 6;
  const int l15 = lane & 15, lg = lane >> 4;
  (void)diags;

  bf16x8 ph[2][2];
#pragma unroll
  for (int mtl = 0; mtl < 2; ++mtl)
#pragma unroll
    for (int ks = 0; ks < 2; ++ks)
      load_pfrag(proj, (2 * w + mtl) * 16 + l15, ks * 32 + lg * 8, &ph[mtl][ks]);

  float gmax = -3.4e38f;
  const int srow = tid >> 3, q8 = (tid & 7) << 3;
  const int xc = ((q8 >> 3) ^ (srow & 7)) << 3;

  for (int batch = 0; batch < 16; ++batch) {
    const int row0 = blk * 512 + batch * 32;
    STAGE_X(kproj + (size_t)(row0 + srow) * 64 + q8, false);
    __syncthreads();
    f32x4 wx[2][2];
#pragma unroll
    for (int st = 0; st < 2; ++st)
#pragma unroll
      for (int mtl = 0; mtl < 2; ++mtl) wx[st][mtl] = f32x4{0, 0, 0, 0};
    WX_COMPUTE(wx);
#pragma unroll
    for (int st = 0; st < 2; ++st)
#pragma unroll
      for (int mtl = 0; mtl < 2; ++mtl)
#pragma unroll
        for (int r = 0; r < 4; ++r) gmax = fmaxf(gmax, wx[st][mtl][r]);
    __syncthreads();
  }
#pragma unroll
  for (int off = 32; off; off >>= 1) gmax = fmaxf(gmax, __shfl_xor(gmax, off));
  if (lane == 0) redw[w] = gmax;
  __syncthreads();
  if (tid == 0)
    blockmax[blk] = fmaxf(fmaxf(redw[0], redw[1]), fmaxf(redw[2], redw[3]));
}

__global__ __launch_bounds__(256) void maxreduce_kernel(
    const float* __restrict__ blockmax, float* __restrict__ stab, int n) {
  __shared__ float sm[256];
  float v = -3.4e38f;
  for (int i = threadIdx.x; i < n; i += 256) v = fmaxf(v, blockmax[i]);
  sm[threadIdx.x] = v;
  __syncthreads();
  for (int s = 128; s; s >>= 1) {
    if (threadIdx.x < s)
      sm[threadIdx.x] = fmaxf(sm[threadIdx.x], sm[threadIdx.x + s]);
    __syncthreads();
  }
  if (threadIdx.x == 0) *stab = sm[0];
}

// ---------------------------------------------------------------------------
// kv: kv[m][d] = sum_s phi_k[s][m] V[s][d], plus k1[m].
// 1024 blocks = 64 bh x 16 chunks of 256 s. Numerics identical to R12.
// ---------------------------------------------------------------------------
__global__ __launch_bounds__(256) void kv_mfma_kernel(
    const _Float16* __restrict__ kproj, const _Float16* __restrict__ vproj,
    const float* __restrict__ proj, const float* __restrict__ stabp,
    float* __restrict__ kvpartT, float* __restrict__ k1part) {
  __shared__ unsigned short Xh[32][64];
  __shared__ float Vs[32][66];
  __shared__ unsigned short phiTh[128][40];
  __shared__ float diags[32];
  const int tid = threadIdx.x, blk = blockIdx.x;
  const int c = blk & 15, bh = blk >> 4, b = bh >> 4, h = bh & 15;
  const int lane = tid & 63, w = tid >> 6;
  const int l15 = lane & 15, lg = lane >> 4;
  const float stab = *stabp;

  bf16x8 ph[2][2];
#pragma unroll
  for (int mtl = 0; mtl < 2; ++mtl)
#pragma unroll
    for (int ks = 0; ks < 2; ++ks)
      load_pfrag(proj, (2 * w + mtl) * 16 + l15, ks * 32 + lg * 8, &ph[mtl][ks]);

  f32x4 akv[2][4];
#pragma unroll
  for (int i = 0; i < 2; ++i)
#pragma unroll
    for (int j = 0; j < 4; ++j) akv[i][j] = f32x4{0, 0, 0, 0};
  float k1acc[2] = {0.f, 0.f};

  const int srow = tid >> 3, q8 = (tid & 7) << 3;
  const int xc = ((q8 >> 3) ^ (srow & 7)) << 3;

  for (int batch = 0; batch < 8; ++batch) {
    const int s0 = c * 256 + batch * 32;
    const size_t rb = (((size_t)(b * S_ + s0 + srow) * H_ + h)) << 6;
    STAGE_X(kproj + rb + q8, true);
    {
      f16x8 vv = *reinterpret_cast<const f16x8*>(vproj + rb + q8);
#pragma unroll
      for (int j = 0; j < 8; ++j) Vs[srow][q8 + j] = (float)vv[j];
    }
    __syncthreads();  // bar1

    f32x4 wx[2][2];
#pragma unroll
    for (int st = 0; st < 2; ++st)
#pragma unroll
      for (int mtl = 0; mtl < 2; ++mtl) wx[st][mtl] = f32x4{0, 0, 0, 0};
    WX_COMPUTE(wx);

    // phi + phiT write + k1 (reference scale: exp(wx - diag - stab) * CM)
#pragma unroll
    for (int st = 0; st < 2; ++st)
#pragma unroll
      for (int mtl = 0; mtl < 2; ++mtl) {
        const int m = (2 * w + mtl) * 16 + l15;
        s16x4 hv;
        float psum = 0.f;
#pragma unroll
        for (int r = 0; r < 4; ++r) {
          const int s = st * 16 + lg * 4 + r;
          float p = __expf(wx[st][mtl][r] - diags[s] - stab) * CM;
          psum += p;
          hv[r] = (short)f2bf(p);
        }
        k1acc[mtl] += psum;
        *reinterpret_cast<s16x4*>(&phiTh[m][st * 16 + lg * 4]) = hv;
      }
    __syncthreads();  // bar2

    // kv contraction: A = phiT[m][s], B = V[s][d]
    bf16x8 pah[2];
#pragma unroll
    for (int mtl = 0; mtl < 2; ++mtl)
      pah[mtl] = *reinterpret_cast<const bf16x8*>(
          &phiTh[(2 * w + mtl) * 16 + l15][lg * 8]);
#pragma unroll
    for (int dt = 0; dt < 4; ++dt) {
      bf16x8 bvh;
#pragma unroll
      for (int j = 0; j < 8; ++j)
        bvh[j] = (short)f2bf(Vs[lg * 8 + j][dt * 16 + l15]);
#pragma unroll
      for (int mtl = 0; mtl < 2; ++mtl) MFMAB(akv[mtl][dt], pah[mtl], bvh);
    }
    __syncthreads();  // bar3
  }

#pragma unroll
  for (int mtl = 0; mtl < 2; ++mtl) {
#pragma unroll
    for (int dt = 0; dt < 4; ++dt) {
      const int d = dt * 16 + l15, m0 = (2 * w + mtl) * 16 + lg * 4;
      *reinterpret_cast<f32x4*>(&kvpartT[(size_t)blk * 8192 + d * 128 + m0]) =
          akv[mtl][dt];
    }
    float kk = k1acc[mtl];
    kk += __shfl_xor(kk, 16);
    kk += __shfl_xor(kk, 32);
    if (lane < 16) k1part[blk * 128 + (2 * w + mtl) * 16 + lane] = kk;
  }
}

__global__ __launch_bounds__(256) void kvreduce_kernel(
    const float* __restrict__ kvpartT, const float* __restrict__ k1part,
    unsigned short* __restrict__ kvT, float* __restrict__ k1) {
  const int bh = blockIdx.x;
  for (int i = threadIdx.x; i < 8192; i += 256) {
    float s = 0.f;
#pragma unroll
    for (int c = 0; c < 16; ++c) s += kvpartT[(size_t)(bh * 16 + c) * 8192 + i];
    kvT[(size_t)bh * 8192 + i] = f2bf(s);
  }
  if (threadIdx.x < 128) {
    float s = 0.f;
#pragma unroll
    for (int c = 0; c < 16; ++c) s += k1part[(bh * 16 + c) * 128 + threadIdx.x];
    k1[bh * 128 + threadIdx.x] = s;
  }
}

// ---------------------------------------------------------------------------
// qkv: phi_q = exp(wx - diag - rmax) * CM (reference scale; epsilon-matched).
// 2048 blocks = 64 bh x 32 chunks of 128 t.
// ---------------------------------------------------------------------------
__global__ __launch_bounds__(256) void qkv_mfma_kernel(
    const _Float16* __restrict__ qproj, const unsigned short* __restrict__ kvT,
    const float* __restrict__ k1g, const float* __restrict__ proj,
    _Float16* __restrict__ outh) {
  __shared__ unsigned short Xh[32][64];
  __shared__ unsigned short Ph[32][128];
  __shared__ float k1s[128];
  __shared__ float diags[32];
  __shared__ float rmaxp[4][32];
  __shared__ float denp[4][32];
  const int tid = threadIdx.x, blk = blockIdx.x;
  const int ch = blk & 31, bh = blk >> 5, b = bh >> 4, h = bh & 15;
  const int lane = tid & 63, w = tid >> 6;
  const int l15 = lane & 15, lg = lane >> 4;

  bf16x8 ph[2][2];
#pragma unroll
  for (int mtl = 0; mtl < 2; ++mtl)
#pragma unroll
    for (int ks = 0; ks < 2; ++ks)
      load_pfrag(proj, (2 * w + mtl) * 16 + l15, ks * 32 + lg * 8, &ph[mtl][ks]);

  bf16x8 kah[4];
#pragma unroll
  for (int ks = 0; ks < 4; ++ks) {
    const size_t o = (size_t)bh * 8192 + (w * 16 + l15) * 128 + ks * 32 + lg * 8;
    kah[ks] = *reinterpret_cast<const bf16x8*>(kvT + o);
  }
  if (tid < 128) k1s[tid] = k1g[bh * 128 + tid];

  const int srow = tid >> 3, q8 = (tid & 7) << 3;
  const int xc = ((q8 >> 3) ^ (srow & 7)) << 3;

  for (int batch = 0; batch < 4; ++batch) {
    const int s0 = ch * 128 + batch * 32;
    const size_t rb = (((size_t)(b * S_ + s0 + srow) * H_ + h)) << 6;
    STAGE_X(qproj + rb + q8, true);
    __syncthreads();  // bar1

    f32x4 wx[2][2];
#pragma unroll
    for (int st = 0; st < 2; ++st)
#pragma unroll
      for (int mtl = 0; mtl < 2; ++mtl) wx[st][mtl] = f32x4{0, 0, 0, 0};
    WX_COMPUTE(wx);

#pragma unroll
    for (int st = 0; st < 2; ++st)
#pragma unroll
      for (int r = 0; r < 4; ++r) {
        float v = fmaxf(wx[st][0][r], wx[st][1][r]);
        v = fmaxf(v, __shfl_xor(v, 1));
        v = fmaxf(v, __shfl_xor(v, 2));
        v = fmaxf(v, __shfl_xor(v, 4));
        v = fmaxf(v, __shfl_xor(v, 8));
        if (l15 == 0) rmaxp[w][st * 16 + lg * 4 + r] = v;
      }
    __syncthreads();  // bar2

#pragma unroll
    for (int st = 0; st < 2; ++st) {
      float off[4];
#pragma unroll
      for (int r = 0; r < 4; ++r) {
        const int s = st * 16 + lg * 4 + r;
        float rmx = fmaxf(fmaxf(rmaxp[0][s], rmaxp[1][s]),
                          fmaxf(rmaxp[2][s], rmaxp[3][s]));
        off[r] = rmx + diags[s];
      }
      float den[4] = {0.f, 0.f, 0.f, 0.f};
#pragma unroll
      for (int mtl = 0; mtl < 2; ++mtl) {
        const int m = (2 * w + mtl) * 16 + l15;
        const float k1v = k1s[m];
#pragma unroll
        for (int r = 0; r < 4; ++r) {
          const int s = st * 16 + lg * 4 + r;
          float p = __expf(wx[st][mtl][r] - off[r]) * CM;
          den[r] += p * k1v;
          Ph[s][((((m >> 3) ^ (s & 7)) << 3) | (m & 7))] = f2bf(p);
        }
      }
#pragma unroll
      for (int r = 0; r < 4; ++r) {
        float v = den[r];
        v += __shfl_xor(v, 1);
        v += __shfl_xor(v, 2);
        v += __shfl_xor(v, 4);
        v += __shfl_xor(v, 8);
        if (l15 == 0) denp[w][st * 16 + lg * 4 + r] = v;
      }
    }
    __syncthreads();  // bar3

#pragma unroll
    for (int st = 0; st < 2; ++st) {
      f32x4 od = {0.f, 0.f, 0.f, 0.f};
#pragma unroll
      for (int ks = 0; ks < 4; ++ks) {
        const int cc = ((ks * 4 + lg) ^ (l15 & 7)) << 3;
        bf16x8 bph = *reinterpret_cast<const bf16x8*>(&Ph[st * 16 + l15][cc]);
        MFMAB(od, kah[ks], bph);
      }
      const int s = st * 16 + l15;
      const float dens =
          1.f / (denp[0][s] + denp[1][s] + denp[2][s] + denp[3][s] + 1e-6f);
      f16x4 o;
#pragma unroll
      for (int j = 0; j < 4; ++j) o[j] = (_Float16)(od[j] * dens);
      *reinterpret_cast<f16x4*>(
          &outh[(size_t)(b * S_ + s0 + s) * 1024 + h * 64 + w * 16 + lg * 4]) = o;
    }
    __syncthreads();  // bar4
  }
}

// ---------------------------------------------------------------------------
extern "C" void kernel_launch(void* const* d_in, const int* in_sizes, int n_in,
                              void* d_out, int out_size, void* d_ws,
                              size_t ws_size, hipStream_t stream) {
  const float* query = (const float*)d_in[0];
  const float* value = (const float*)d_in[1];
  const float* key   = (const float*)d_in[2];
  const float* Wq = (const float*)d_in[3];
  const float* bq = (const float*)d_in[4];
  const float* Wk = (const float*)d_in[5];
  const float* bk = (const float*)d_in[6];
  const float* Wv = (const float*)d_in[7];
  const float* bv = (const float*)d_in[8];
  const float* Wo = (const float*)d_in[9];
  const float* bo = (const float*)d_in[10];
  const float* proj = (const float*)d_in[11];
  float* out = (float*)d_out;
  float* ws = (float*)d_ws;

  _Float16* KP16 = (_Float16*)(ws + OFF_A);   // kproj then qproj (fp16)
  _Float16* VP16 = (_Float16*)(ws + OFF_B);   // vproj (fp16)
  _Float16* WT = (_Float16*)(ws + OFF_X);
  float* K1P = ws + OFF_X;                    // k1part (WT dead at kv time)
  unsigned short* KVT = (unsigned short*)(ws + OFF_KV);
  float* K1 = ws + OFF_K1;
  float* BMX = ws + OFF_BM;
  float* ST = ws + OFF_ST;
  _Float16* X16 = (_Float16*)(ws + OFF_A16);  // GEMM A staging
  float* KVPT = ws + OFF_A16;                 // kv partials (staging dead)

  dim3 gw(32, 32);

  // 1. k_proj (fp16)
  cvt_f16_kernel<<<2048, 256, 0, stream>>>(key, X16);
  wt_f16_kernel<<<gw, 256, 0, stream>>>(Wk, WT);
  gemm_lds<1><<<1024, 256, 0, stream>>>(X16, WT, bk, KP16);
  // 2. stab (reference global max wx_k)
  wxmax_mfma_kernel<<<512, 256, 0, stream>>>(KP16, proj, BMX);
  maxreduce_kernel<<<1, 256, 0, stream>>>(BMX, ST, 512);
  // 3. v_proj (fp16)
  cvt_f16_kernel<<<2048, 256, 0, stream>>>(value, X16);
  wt_f16_kernel<<<gw, 256, 0, stream>>>(Wv, WT);
  gemm_lds<1><<<1024, 256, 0, stream>>>(X16, WT, bv, VP16);
  // 4. kv / k1 (KVPT aliases X16 staging — dead; K1P aliases WT — dead)
  kv_mfma_kernel<<<1024, 256, 0, stream>>>(KP16, VP16, proj, ST, KVPT, K1P);
  kvreduce_kernel<<<64, 256, 0, stream>>>(KVPT, K1P, KVT, K1);
  // 5. q_proj (KVPT dead after reduce; kproj dead after kv)
  cvt_f16_kernel<<<2048, 256, 0, stream>>>(query, X16);
  wt_f16_kernel<<<gw, 256, 0, stream>>>(Wq, WT);
  gemm_lds<1><<<1024, 256, 0, stream>>>(X16, WT, bq, KP16);
  // 6. out_h -> X16 as fp16 (query staging dead after q_proj gemm)
  qkv_mfma_kernel<<<2048, 256, 0, stream>>>(KP16, KVT, K1, proj, X16);
  // 7. output projection (f32 out)
  wt_f16_kernel<<<gw, 256, 0, stream>>>(Wo, WT);
  gemm_lds<0><<<1024, 256, 0, stream>>>(X16, WT, bo, out);
}

// Round 15
// 330.034 us; speedup vs baseline: 10.5853x; 1.0863x over previous
//
#include <hip/hip_runtime.h>
#include <hip/hip_bf16.h>

// Performer (FAVOR+) forward. Round 15: R14 + GEMM scaled to 256x256 tile
// (512 threads / 8 waves, same verified 4-deep counted-vmcnt pipeline:
// 4 GLDS per thread per K-step -> identical vmcnt numbers). 1 block/CU,
// 32 MFMA per barrier per wave (2x R12). Numerics bit-identical to R14.
// B=4, S=4096, D=1024, H=16, K=64, M=128.

#define B_  4
#define S_  4096
#define H_  16

#define SCALE_X 0.3535533905932738f     // 64^-0.25
#define CM      0.08838834764831845f    // 128^-0.5

typedef __attribute__((ext_vector_type(8))) short bf16x8;
typedef __attribute__((ext_vector_type(4))) short s16x4;
typedef __attribute__((ext_vector_type(8))) unsigned short u16x8;
typedef __attribute__((ext_vector_type(8))) _Float16 f16x8;
typedef __attribute__((ext_vector_type(4))) _Float16 f16x4;
typedef __attribute__((ext_vector_type(4))) float f32x4;

// ---- ws layout (float units) ----
#define OFF_A    ((size_t)0)          // kproj16 then qproj16 (fp16, 32MB)
#define OFF_B    ((size_t)16777216)   // vproj16 (fp16)
#define OFF_X    ((size_t)33554432)   // union: WT fp16 / k1part(131072)
#define OFF_KV   ((size_t)37814272)   // kvT bf16: 524288 ush
#define OFF_K1   ((size_t)38338560)   // 64*128 f32
#define OFF_BM   ((size_t)38346752)   // 512 block maxes
#define OFF_ST   ((size_t)38347264)   // stab scalar
#define OFF_A16  ((size_t)38347776)   // 8388608 f32: GEMM A staging / kvpartT
// total 46736384 f32 = 186.9 MB

__device__ __forceinline__ unsigned short f2bf(float x) {
  union { __hip_bfloat16 b; unsigned short u; } c;
  c.b = __float2bfloat16(x);
  return c.u;
}

#define MFMAB(ACC, A, B)                                               \
  ACC = __builtin_amdgcn_mfma_f32_16x16x32_bf16(A, B, ACC, 0, 0, 0)

#define GLDS(GP, LP)                                                  \
  __builtin_amdgcn_global_load_lds(                                   \
      (const __attribute__((address_space(1))) unsigned int*)(GP),    \
      (__attribute__((address_space(3))) unsigned int*)(LP), 16, 0, 0)

// load P-operand fragment (B for wx): lane supplies P[m][kb..kb+7] as bf16
__device__ __forceinline__ void load_pfrag(const float* __restrict__ proj, int m,
                                           int kb, bf16x8* ph) {
  const float* p = proj + m * 64 + kb;
  float4 a = *reinterpret_cast<const float4*>(p);
  float4 b = *reinterpret_cast<const float4*>(p + 4);
  float v[8] = {a.x, a.y, a.z, a.w, b.x, b.y, b.z, b.w};
  bf16x8 h;
#pragma unroll
  for (int j = 0; j < 8; ++j) h[j] = (short)f2bf(v[j]);
  *ph = h;
}

// Stage one X row-chunk from fp16 source: scale, bf16, chunk-XOR LDS write.
#define STAGE_X(PTR, WANT_DIAG)                                           \
  {                                                                       \
    f16x8 xv_ = *reinterpret_cast<const f16x8*>(PTR);                     \
    u16x8 hh_;                                                            \
    float sq_ = 0.f;                                                      \
    _Pragma("unroll") for (int j = 0; j < 8; ++j) {                       \
      float vf_ = (float)xv_[j] * SCALE_X;                                \
      sq_ += vf_ * vf_;                                                   \
      hh_[j] = f2bf(vf_);                                                 \
    }                                                                     \
    *reinterpret_cast<u16x8*>(&Xh[srow][xc]) = hh_;                       \
    if (WANT_DIAG) {                                                      \
      sq_ += __shfl_xor(sq_, 1);                                          \
      sq_ += __shfl_xor(sq_, 2);                                          \
      sq_ += __shfl_xor(sq_, 4);                                          \
      if ((tid & 7) == 0) diags[srow] = 0.5f * sq_;                       \
    }                                                                     \
  }

// wx MFMA block: 2 st x 2 ks x 2 mtl, single bf16 MFMA each.
#define WX_COMPUTE(WX)                                                       \
  _Pragma("unroll") for (int st_ = 0; st_ < 2; ++st_)                        \
  _Pragma("unroll") for (int ks_ = 0; ks_ < 2; ++ks_) {                      \
    const int rr_ = st_ * 16 + l15;                                          \
    const int cc_ = ((ks_ * 4 + lg) ^ (l15 & 7)) << 3;                       \
    bf16x8 xh_ = *reinterpret_cast<const bf16x8*>(&Xh[rr_][cc_]);            \
    _Pragma("unroll") for (int mtl_ = 0; mtl_ < 2; ++mtl_)                   \
        MFMAB(WX[st_][mtl_], xh_, ph[mtl_][ks_]);                            \
  }

// ---------------------------------------------------------------------------
// f32 -> fp16 conversion pass (16777216 elements).
// ---------------------------------------------------------------------------
__global__ __launch_bounds__(256) void cvt_f16_kernel(
    const float* __restrict__ in, _Float16* __restrict__ out) {
  const size_t stride = (size_t)gridDim.x * 256 * 8;
  for (size_t i = ((size_t)blockIdx.x * 256 + threadIdx.x) * 8; i < 16777216UL;
       i += stride) {
    float4 a = *reinterpret_cast<const float4*>(in + i);
    float4 b = *reinterpret_cast<const float4*>(in + i + 4);
    f16x8 h;
    h[0] = (_Float16)a.x; h[1] = (_Float16)a.y;
    h[2] = (_Float16)a.z; h[3] = (_Float16)a.w;
    h[4] = (_Float16)b.x; h[5] = (_Float16)b.y;
    h[6] = (_Float16)b.z; h[7] = (_Float16)b.w;
    *reinterpret_cast<f16x8*>(out + i) = h;
  }
}

// ---------------------------------------------------------------------------
// Weight transform: W[1024 k][1024 n] f32 -> WT [n][k] fp16.
// ---------------------------------------------------------------------------
__global__ __launch_bounds__(256) void wt_f16_kernel(
    const float* __restrict__ W, _Float16* __restrict__ T) {
  __shared__ float t[32][33];
  const int tx = threadIdx.x & 31, ty = threadIdx.x >> 5;
  const int k0 = blockIdx.x * 32, n0 = blockIdx.y * 32;
#pragma unroll
  for (int i = 0; i < 4; ++i)
    t[ty + 8 * i][tx] = W[(size_t)(k0 + ty + 8 * i) * 1024 + n0 + tx];
  __syncthreads();
#pragma unroll
  for (int i = 0; i < 4; ++i)
    T[(size_t)(n0 + ty + 8 * i) * 1024 + k0 + tx] = (_Float16)t[tx][ty + 8 * i];
}

// ---------------------------------------------------------------------------
// Pipelined fp16 GEMM, 256x256 tile, 512 threads (8 waves = 2m x 4n of
// 128x64). BK=32, 4-deep LDS buffers, issue-ahead 2, counted vmcnt(8)
// (4 GLDS per thread per K-step — identical pipeline math to R12).
// Swizzle c ^ ((r>>1)&3) both sides; swz(r+128)==swz(r) so both staging
// issues share one source offset. LDS 128KB -> 1 block/CU.
// ---------------------------------------------------------------------------
template <int F16OUT>
__global__ __launch_bounds__(512) void gemm_lds(
    const _Float16* __restrict__ A16, const _Float16* __restrict__ BT,
    const float* __restrict__ bias, void* __restrict__ Cout) {
  __shared__ _Float16 As[4][256][32];
  __shared__ _Float16 Bs[4][256][32];
  const int tid = threadIdx.x;
  const int bid = blockIdx.x;
  const int m0 = (bid & 63) << 8;    // 64 m-blocks
  const int n0 = (bid >> 6) << 8;    // 4 n-blocks
  const int wave = tid >> 6, lane = tid & 63;
  const int wm = (wave >> 2) << 7;   // 0 or 128
  const int wn = (wave & 3) << 6;    // 0,64,128,192
  const int l15 = lane & 15, lg = lane >> 4;

  const int rlo = tid >> 2;                            // 0..127 (issue 0 row)
  const int cg = ((tid & 3) ^ ((rlo >> 1) & 3)) << 3;  // pre-swizzled source
  const int wqbase = wave << 10;                       // 1KB per wave

  const _Float16* pa = A16 + (size_t)(m0 + rlo) * 1024 + cg;
  const _Float16* pb = BT + (size_t)(n0 + rlo) * 1024 + cg;

  f32x4 acc[8][4];
#pragma unroll
  for (int i = 0; i < 8; ++i)
#pragma unroll
    for (int j = 0; j < 4; ++j) acc[i][j] = f32x4{0.f, 0.f, 0.f, 0.f};

#define STAGE_T(nb, kt)                                                   \
  {                                                                       \
    char* la = (char*)&As[nb][0][0] + wqbase;                             \
    char* lb = (char*)&Bs[nb][0][0] + wqbase;                             \
    GLDS(pa + (kt) * 32, la);                                             \
    GLDS(pa + (kt) * 32 + 131072, la + 8192);                             \
    GLDS(pb + (kt) * 32, lb);                                             \
    GLDS(pb + (kt) * 32 + 131072, lb + 8192);                             \
  }

#define PIPE_BAR(N)                                                       \
  asm volatile("s_waitcnt vmcnt(" #N ")" ::: "memory");                   \
  __builtin_amdgcn_s_barrier();                                           \
  asm volatile("" ::: "memory");                                          \
  __builtin_amdgcn_sched_barrier(0);

#define COMPUTE(cur)                                                      \
  {                                                                       \
    f16x8 bf[4];                                                          \
    _Pragma("unroll") for (int fn = 0; fn < 4; ++fn) {                    \
      const int r = wn + fn * 16 + l15;                                   \
      bf[fn] = *reinterpret_cast<const f16x8*>(                           \
          &Bs[cur][r][(lg ^ ((r >> 1) & 3)) << 3]);                       \
    }                                                                     \
    _Pragma("unroll") for (int fm = 0; fm < 8; ++fm) {                    \
      const int r = wm + fm * 16 + l15;                                   \
      f16x8 av = *reinterpret_cast<const f16x8*>(                         \
          &As[cur][r][(lg ^ ((r >> 1) & 3)) << 3]);                       \
      _Pragma("unroll") for (int fn = 0; fn < 4; ++fn)                    \
        acc[fm][fn] = __builtin_amdgcn_mfma_f32_16x16x32_f16(             \
            av, bf[fn], acc[fm][fn], 0, 0, 0);                            \
    }                                                                     \
  }

  STAGE_T(0, 0);
  STAGE_T(1, 1);

  for (int kt = 0; kt < 30; ++kt) {
    STAGE_T((kt + 2) & 3, kt + 2);
    PIPE_BAR(8);
    COMPUTE(kt & 3);
  }
  PIPE_BAR(4);
  COMPUTE(2);  // kt = 30
  PIPE_BAR(0);
  COMPUTE(3);  // kt = 31

#pragma unroll
  for (int fm = 0; fm < 8; ++fm) {
    const int row = m0 + wm + fm * 16 + (lg << 2);
#pragma unroll
    for (int fn = 0; fn < 4; ++fn) {
      const int col = n0 + wn + fn * 16 + l15;
      const float bc = bias[col];
      f32x4 v = acc[fm][fn];
      if (F16OUT) {
        _Float16* C = (_Float16*)Cout;
#pragma unroll
        for (int j = 0; j < 4; ++j)
          C[(size_t)(row + j) * 1024 + col] = (_Float16)(v[j] + bc);
      } else {
        float* C = (float*)Cout;
#pragma unroll
        for (int j = 0; j < 4; ++j) C[(size_t)(row + j) * 1024 + col] = v[j] + bc;
      }
    }
  }
#undef STAGE_T
#undef PIPE_BAR
#undef COMPUTE
}

// ---------------------------------------------------------------------------
// wxmax: global max of wx_k via MFMA (reference stabilizer). 512 blocks.
// ---------------------------------------------------------------------------
__global__ __launch_bounds__(256) void wxmax_mfma_kernel(
    const _Float16* __restrict__ kproj, const float* __restrict__ proj,
    float* __restrict__ blockmax) {
  __shared__ unsigned short Xh[32][64];
  __shared__ float diags[32];  // unused (WANT_DIAG=false)
  __shared__ float redw[4];
  const int tid = threadIdx.x, blk = blockIdx.x;
  const int lane = tid & 63, w = tid >> 6;
  const int l15 = lane & 15, lg = lane >> 4;
  (void)diags;

  bf16x8 ph[2][2];
#pragma unroll
  for (int mtl = 0; mtl < 2; ++mtl)
#pragma unroll
    for (int ks = 0; ks < 2; ++ks)
      load_pfrag(proj, (2 * w + mtl) * 16 + l15, ks * 32 + lg * 8, &ph[mtl][ks]);

  float gmax = -3.4e38f;
  const int srow = tid >> 3, q8 = (tid & 7) << 3;
  const int xc = ((q8 >> 3) ^ (srow & 7)) << 3;

  for (int batch = 0; batch < 16; ++batch) {
    const int row0 = blk * 512 + batch * 32;
    STAGE_X(kproj + (size_t)(row0 + srow) * 64 + q8, false);
    __syncthreads();
    f32x4 wx[2][2];
#pragma unroll
    for (int st = 0; st < 2; ++st)
#pragma unroll
      for (int mtl = 0; mtl < 2; ++mtl) wx[st][mtl] = f32x4{0, 0, 0, 0};
    WX_COMPUTE(wx);
#pragma unroll
    for (int st = 0; st < 2; ++st)
#pragma unroll
      for (int mtl = 0; mtl < 2; ++mtl)
#pragma unroll
        for (int r = 0; r < 4; ++r) gmax = fmaxf(gmax, wx[st][mtl][r]);
    __syncthreads();
  }
#pragma unroll
  for (int off = 32; off; off >>= 1) gmax = fmaxf(gmax, __shfl_xor(gmax, off));
  if (lane == 0) redw[w] = gmax;
  __syncthreads();
  if (tid == 0)
    blockmax[blk] = fmaxf(fmaxf(redw[0], redw[1]), fmaxf(redw[2], redw[3]));
}

__global__ __launch_bounds__(256) void maxreduce_kernel(
    const float* __restrict__ blockmax, float* __restrict__ stab, int n) {
  __shared__ float sm[256];
  float v = -3.4e38f;
  for (int i = threadIdx.x; i < n; i += 256) v = fmaxf(v, blockmax[i]);
  sm[threadIdx.x] = v;
  __syncthreads();
  for (int s = 128; s; s >>= 1) {
    if (threadIdx.x < s)
      sm[threadIdx.x] = fmaxf(sm[threadIdx.x], sm[threadIdx.x + s]);
    __syncthreads();
  }
  if (threadIdx.x == 0) *stab = sm[0];
}

// ---------------------------------------------------------------------------
// kv: kv[m][d] = sum_s phi_k[s][m] V[s][d], plus k1[m].
// 1024 blocks = 64 bh x 16 chunks of 256 s. Numerics identical to R12.
// ---------------------------------------------------------------------------
__global__ __launch_bounds__(256) void kv_mfma_kernel(
    const _Float16* __restrict__ kproj, const _Float16* __restrict__ vproj,
    const float* __restrict__ proj, const float* __restrict__ stabp,
    float* __restrict__ kvpartT, float* __restrict__ k1part) {
  __shared__ unsigned short Xh[32][64];
  __shared__ float Vs[32][66];
  __shared__ unsigned short phiTh[128][40];
  __shared__ float diags[32];
  const int tid = threadIdx.x, blk = blockIdx.x;
  const int c = blk & 15, bh = blk >> 4, b = bh >> 4, h = bh & 15;
  const int lane = tid & 63, w = tid >> 6;
  const int l15 = lane & 15, lg = lane >> 4;
  const float stab = *stabp;

  bf16x8 ph[2][2];
#pragma unroll
  for (int mtl = 0; mtl < 2; ++mtl)
#pragma unroll
    for (int ks = 0; ks < 2; ++ks)
      load_pfrag(proj, (2 * w + mtl) * 16 + l15, ks * 32 + lg * 8, &ph[mtl][ks]);

  f32x4 akv[2][4];
#pragma unroll
  for (int i = 0; i < 2; ++i)
#pragma unroll
    for (int j = 0; j < 4; ++j) akv[i][j] = f32x4{0, 0, 0, 0};
  float k1acc[2] = {0.f, 0.f};

  const int srow = tid >> 3, q8 = (tid & 7) << 3;
  const int xc = ((q8 >> 3) ^ (srow & 7)) << 3;

  for (int batch = 0; batch < 8; ++batch) {
    const int s0 = c * 256 + batch * 32;
    const size_t rb = (((size_t)(b * S_ + s0 + srow) * H_ + h)) << 6;
    STAGE_X(kproj + rb + q8, true);
    {
      f16x8 vv = *reinterpret_cast<const f16x8*>(vproj + rb + q8);
#pragma unroll
      for (int j = 0; j < 8; ++j) Vs[srow][q8 + j] = (float)vv[j];
    }
    __syncthreads();  // bar1

    f32x4 wx[2][2];
#pragma unroll
    for (int st = 0; st < 2; ++st)
#pragma unroll
      for (int mtl = 0; mtl < 2; ++mtl) wx[st][mtl] = f32x4{0, 0, 0, 0};
    WX_COMPUTE(wx);

    // phi + phiT write + k1 (reference scale: exp(wx - diag - stab) * CM)
#pragma unroll
    for (int st = 0; st < 2; ++st)
#pragma unroll
      for (int mtl = 0; mtl < 2; ++mtl) {
        const int m = (2 * w + mtl) * 16 + l15;
        s16x4 hv;
        float psum = 0.f;
#pragma unroll
        for (int r = 0; r < 4; ++r) {
          const int s = st * 16 + lg * 4 + r;
          float p = __expf(wx[st][mtl][r] - diags[s] - stab) * CM;
          psum += p;
          hv[r] = (short)f2bf(p);
        }
        k1acc[mtl] += psum;
        *reinterpret_cast<s16x4*>(&phiTh[m][st * 16 + lg * 4]) = hv;
      }
    __syncthreads();  // bar2

    // kv contraction: A = phiT[m][s], B = V[s][d]
    bf16x8 pah[2];
#pragma unroll
    for (int mtl = 0; mtl < 2; ++mtl)
      pah[mtl] = *reinterpret_cast<const bf16x8*>(
          &phiTh[(2 * w + mtl) * 16 + l15][lg * 8]);
#pragma unroll
    for (int dt = 0; dt < 4; ++dt) {
      bf16x8 bvh;
#pragma unroll
      for (int j = 0; j < 8; ++j)
        bvh[j] = (short)f2bf(Vs[lg * 8 + j][dt * 16 + l15]);
#pragma unroll
      for (int mtl = 0; mtl < 2; ++mtl) MFMAB(akv[mtl][dt], pah[mtl], bvh);
    }
    __syncthreads();  // bar3
  }

#pragma unroll
  for (int mtl = 0; mtl < 2; ++mtl) {
#pragma unroll
    for (int dt = 0; dt < 4; ++dt) {
      const int d = dt * 16 + l15, m0 = (2 * w + mtl) * 16 + lg * 4;
      *reinterpret_cast<f32x4*>(&kvpartT[(size_t)blk * 8192 + d * 128 + m0]) =
          akv[mtl][dt];
    }
    float kk = k1acc[mtl];
    kk += __shfl_xor(kk, 16);
    kk += __shfl_xor(kk, 32);
    if (lane < 16) k1part[blk * 128 + (2 * w + mtl) * 16 + lane] = kk;
  }
}

__global__ __launch_bounds__(256) void kvreduce_kernel(
    const float* __restrict__ kvpartT, const float* __restrict__ k1part,
    unsigned short* __restrict__ kvT, float* __restrict__ k1) {
  const int bh = blockIdx.x;
  for (int i = threadIdx.x; i < 8192; i += 256) {
    float s = 0.f;
#pragma unroll
    for (int c = 0; c < 16; ++c) s += kvpartT[(size_t)(bh * 16 + c) * 8192 + i];
    kvT[(size_t)bh * 8192 + i] = f2bf(s);
  }
  if (threadIdx.x < 128) {
    float s = 0.f;
#pragma unroll
    for (int c = 0; c < 16; ++c) s += k1part[(bh * 16 + c) * 128 + threadIdx.x];
    k1[bh * 128 + threadIdx.x] = s;
  }
}

// ---------------------------------------------------------------------------
// qkv: phi_q = exp(wx - diag - rmax) * CM (reference scale; epsilon-matched).
// 2048 blocks = 64 bh x 32 chunks of 128 t.
// ---------------------------------------------------------------------------
__global__ __launch_bounds__(256) void qkv_mfma_kernel(
    const _Float16* __restrict__ qproj, const unsigned short* __restrict__ kvT,
    const float* __restrict__ k1g, const float* __restrict__ proj,
    _Float16* __restrict__ outh) {
  __shared__ unsigned short Xh[32][64];
  __shared__ unsigned short Ph[32][128];
  __shared__ float k1s[128];
  __shared__ float diags[32];
  __shared__ float rmaxp[4][32];
  __shared__ float denp[4][32];
  const int tid = threadIdx.x, blk = blockIdx.x;
  const int ch = blk & 31, bh = blk >> 5, b = bh >> 4, h = bh & 15;
  const int lane = tid & 63, w = tid >> 6;
  const int l15 = lane & 15, lg = lane >> 4;

  bf16x8 ph[2][2];
#pragma unroll
  for (int mtl = 0; mtl < 2; ++mtl)
#pragma unroll
    for (int ks = 0; ks < 2; ++ks)
      load_pfrag(proj, (2 * w + mtl) * 16 + l15, ks * 32 + lg * 8, &ph[mtl][ks]);

  bf16x8 kah[4];
#pragma unroll
  for (int ks = 0; ks < 4; ++ks) {
    const size_t o = (size_t)bh * 8192 + (w * 16 + l15) * 128 + ks * 32 + lg * 8;
    kah[ks] = *reinterpret_cast<const bf16x8*>(kvT + o);
  }
  if (tid < 128) k1s[tid] = k1g[bh * 128 + tid];

  const int srow = tid >> 3, q8 = (tid & 7) << 3;
  const int xc = ((q8 >> 3) ^ (srow & 7)) << 3;

  for (int batch = 0; batch < 4; ++batch) {
    const int s0 = ch * 128 + batch * 32;
    const size_t rb = (((size_t)(b * S_ + s0 + srow) * H_ + h)) << 6;
    STAGE_X(qproj + rb + q8, true);
    __syncthreads();  // bar1

    f32x4 wx[2][2];
#pragma unroll
    for (int st = 0; st < 2; ++st)
#pragma unroll
      for (int mtl = 0; mtl < 2; ++mtl) wx[st][mtl] = f32x4{0, 0, 0, 0};
    WX_COMPUTE(wx);

#pragma unroll
    for (int st = 0; st < 2; ++st)
#pragma unroll
      for (int r = 0; r < 4; ++r) {
        float v = fmaxf(wx[st][0][r], wx[st][1][r]);
        v = fmaxf(v, __shfl_xor(v, 1));
        v = fmaxf(v, __shfl_xor(v, 2));
        v = fmaxf(v, __shfl_xor(v, 4));
        v = fmaxf(v, __shfl_xor(v, 8));
        if (l15 == 0) rmaxp[w][st * 16 + lg * 4 + r] = v;
      }
    __syncthreads();  // bar2

#pragma unroll
    for (int st = 0; st < 2; ++st) {
      float off[4];
#pragma unroll
      for (int r = 0; r < 4; ++r) {
        const int s = st * 16 + lg * 4 + r;
        float rmx = fmaxf(fmaxf(rmaxp[0][s], rmaxp[1][s]),
                          fmaxf(rmaxp[2][s], rmaxp[3][s]));
        off[r] = rmx + diags[s];
      }
      float den[4] = {0.f, 0.f, 0.f, 0.f};
#pragma unroll
      for (int mtl = 0; mtl < 2; ++mtl) {
        const int m = (2 * w + mtl) * 16 + l15;
        const float k1v = k1s[m];
#pragma unroll
        for (int r = 0; r < 4; ++r) {
          const int s = st * 16 + lg * 4 + r;
          float p = __expf(wx[st][mtl][r] - off[r]) * CM;
          den[r] += p * k1v;
          Ph[s][((((m >> 3) ^ (s & 7)) << 3) | (m & 7))] = f2bf(p);
        }
      }
#pragma unroll
      for (int r = 0; r < 4; ++r) {
        float v = den[r];
        v += __shfl_xor(v, 1);
        v += __shfl_xor(v, 2);
        v += __shfl_xor(v, 4);
        v += __shfl_xor(v, 8);
        if (l15 == 0) denp[w][st * 16 + lg * 4 + r] = v;
      }
    }
    __syncthreads();  // bar3

#pragma unroll
    for (int st = 0; st < 2; ++st) {
      f32x4 od = {0.f, 0.f, 0.f, 0.f};
#pragma unroll
      for (int ks = 0; ks < 4; ++ks) {
        const int cc = ((ks * 4 + lg) ^ (l15 & 7)) << 3;
        bf16x8 bph = *reinterpret_cast<const bf16x8*>(&Ph[st * 16 + l15][cc]);
        MFMAB(od, kah[ks], bph);
      }
      const int s = st * 16 + l15;
      const float dens =
          1.f / (denp[0][s] + denp[1][s] + denp[2][s] + denp[3][s] + 1e-6f);
      f16x4 o;
#pragma unroll
      for (int j = 0; j < 4; ++j) o[j] = (_Float16)(od[j] * dens);
      *reinterpret_cast<f16x4*>(
          &outh[(size_t)(b * S_ + s0 + s) * 1024 + h * 64 + w * 16 + lg * 4]) = o;
    }
    __syncthreads();  // bar4
  }
}

// ---------------------------------------------------------------------------
extern "C" void kernel_launch(void* const* d_in, const int* in_sizes, int n_in,
                              void* d_out, int out_size, void* d_ws,
                              size_t ws_size, hipStream_t stream) {
  const float* query = (const float*)d_in[0];
  const float* value = (const float*)d_in[1];
  const float* key   = (const float*)d_in[2];
  const float* Wq = (const float*)d_in[3];
  const float* bq = (const float*)d_in[4];
  const float* Wk = (const float*)d_in[5];
  const float* bk = (const float*)d_in[6];
  const float* Wv = (const float*)d_in[7];
  const float* bv = (const float*)d_in[8];
  const float* Wo = (const float*)d_in[9];
  const float* bo = (const float*)d_in[10];
  const float* proj = (const float*)d_in[11];
  float* out = (float*)d_out;
  float* ws = (float*)d_ws;

  _Float16* KP16 = (_Float16*)(ws + OFF_A);   // kproj then qproj (fp16)
  _Float16* VP16 = (_Float16*)(ws + OFF_B);   // vproj (fp16)
  _Float16* WT = (_Float16*)(ws + OFF_X);
  float* K1P = ws + OFF_X;                    // k1part (WT dead at kv time)
  unsigned short* KVT = (unsigned short*)(ws + OFF_KV);
  float* K1 = ws + OFF_K1;
  float* BMX = ws + OFF_BM;
  float* ST = ws + OFF_ST;
  _Float16* X16 = (_Float16*)(ws + OFF_A16);  // GEMM A staging
  float* KVPT = ws + OFF_A16;                 // kv partials (staging dead)

  dim3 gw(32, 32);

  // 1. k_proj (fp16)
  cvt_f16_kernel<<<2048, 256, 0, stream>>>(key, X16);
  wt_f16_kernel<<<gw, 256, 0, stream>>>(Wk, WT);
  gemm_lds<1><<<256, 512, 0, stream>>>(X16, WT, bk, KP16);
  // 2. stab (reference global max wx_k)
  wxmax_mfma_kernel<<<512, 256, 0, stream>>>(KP16, proj, BMX);
  maxreduce_kernel<<<1, 256, 0, stream>>>(BMX, ST, 512);
  // 3. v_proj (fp16)
  cvt_f16_kernel<<<2048, 256, 0, stream>>>(value, X16);
  wt_f16_kernel<<<gw, 256, 0, stream>>>(Wv, WT);
  gemm_lds<1><<<256, 512, 0, stream>>>(X16, WT, bv, VP16);
  // 4. kv / k1 (KVPT aliases X16 staging — dead; K1P aliases WT — dead)
  kv_mfma_kernel<<<1024, 256, 0, stream>>>(KP16, VP16, proj, ST, KVPT, K1P);
  kvreduce_kernel<<<64, 256, 0, stream>>>(KVPT, K1P, KVT, K1);
  // 5. q_proj (KVPT dead after reduce; kproj dead after kv)
  cvt_f16_kernel<<<2048, 256, 0, stream>>>(query, X16);
  wt_f16_kernel<<<gw, 256, 0, stream>>>(Wq, WT);
  gemm_lds<1><<<256, 512, 0, stream>>>(X16, WT, bq, KP16);
  // 6. out_h -> X16 as fp16 (query staging dead after q_proj gemm)
  qkv_mfma_kernel<<<2048, 256, 0, stream>>>(KP16, KVT, K1, proj, X16);
  // 7. output projection (f32 out)
  wt_f16_kernel<<<gw, 256, 0, stream>>>(Wo, WT);
  gemm_lds<0><<<256, 512, 0, stream>>>(X16, WT, bo, out);
}

// Round 16
// 328.361 us; speedup vs baseline: 10.6393x; 1.0051x over previous
//
#include <hip/hip_runtime.h>
#include <hip/hip_bf16.h>

// Performer (FAVOR+) forward. Round 16: R15 + T14 async-stage prefetch in
// the middle kernels (qkv: all-4-batch register prefetch; kv/wxmax: depth-1
// rotating prefetch). No layout/barrier/numeric changes — bit-identical to
// R15 (passed, 330us, absmax 9.77e-3).
// B=4, S=4096, D=1024, H=16, K=64, M=128.

#define B_  4
#define S_  4096
#define H_  16

#define SCALE_X 0.3535533905932738f     // 64^-0.25
#define CM      0.08838834764831845f    // 128^-0.5

typedef __attribute__((ext_vector_type(8))) short bf16x8;
typedef __attribute__((ext_vector_type(4))) short s16x4;
typedef __attribute__((ext_vector_type(8))) unsigned short u16x8;
typedef __attribute__((ext_vector_type(8))) _Float16 f16x8;
typedef __attribute__((ext_vector_type(4))) _Float16 f16x4;
typedef __attribute__((ext_vector_type(4))) float f32x4;

// ---- ws layout (float units) ----
#define OFF_A    ((size_t)0)          // kproj16 then qproj16 (fp16, 32MB)
#define OFF_B    ((size_t)16777216)   // vproj16 (fp16)
#define OFF_X    ((size_t)33554432)   // union: WT fp16 / k1part(131072)
#define OFF_KV   ((size_t)37814272)   // kvT bf16: 524288 ush
#define OFF_K1   ((size_t)38338560)   // 64*128 f32
#define OFF_BM   ((size_t)38346752)   // 512 block maxes
#define OFF_ST   ((size_t)38347264)   // stab scalar
#define OFF_A16  ((size_t)38347776)   // 8388608 f32: GEMM A staging / kvpartT
// total 46736384 f32 = 186.9 MB

__device__ __forceinline__ unsigned short f2bf(float x) {
  union { __hip_bfloat16 b; unsigned short u; } c;
  c.b = __float2bfloat16(x);
  return c.u;
}

#define MFMAB(ACC, A, B)                                               \
  ACC = __builtin_amdgcn_mfma_f32_16x16x32_bf16(A, B, ACC, 0, 0, 0)

#define GLDS(GP, LP)                                                  \
  __builtin_amdgcn_global_load_lds(                                   \
      (const __attribute__((address_space(1))) unsigned int*)(GP),    \
      (__attribute__((address_space(3))) unsigned int*)(LP), 16, 0, 0)

// load P-operand fragment (B for wx): lane supplies P[m][kb..kb+7] as bf16
__device__ __forceinline__ void load_pfrag(const float* __restrict__ proj, int m,
                                           int kb, bf16x8* ph) {
  const float* p = proj + m * 64 + kb;
  float4 a = *reinterpret_cast<const float4*>(p);
  float4 b = *reinterpret_cast<const float4*>(p + 4);
  float v[8] = {a.x, a.y, a.z, a.w, b.x, b.y, b.z, b.w};
  bf16x8 h;
#pragma unroll
  for (int j = 0; j < 8; ++j) h[j] = (short)f2bf(v[j]);
  *ph = h;
}

// Stage one X row-chunk FROM REGISTERS: scale, bf16, chunk-XOR LDS write.
#define STAGE_XR(XV, WANT_DIAG)                                           \
  {                                                                       \
    f16x8 xv_ = (XV);                                                     \
    u16x8 hh_;                                                            \
    float sq_ = 0.f;                                                      \
    _Pragma("unroll") for (int j = 0; j < 8; ++j) {                       \
      float vf_ = (float)xv_[j] * SCALE_X;                                \
      sq_ += vf_ * vf_;                                                   \
      hh_[j] = f2bf(vf_);                                                 \
    }                                                                     \
    *reinterpret_cast<u16x8*>(&Xh[srow][xc]) = hh_;                       \
    if (WANT_DIAG) {                                                      \
      sq_ += __shfl_xor(sq_, 1);                                          \
      sq_ += __shfl_xor(sq_, 2);                                          \
      sq_ += __shfl_xor(sq_, 4);                                          \
      if ((tid & 7) == 0) diags[srow] = 0.5f * sq_;                       \
    }                                                                     \
  }

// wx MFMA block: 2 st x 2 ks x 2 mtl, single bf16 MFMA each.
#define WX_COMPUTE(WX)                                                       \
  _Pragma("unroll") for (int st_ = 0; st_ < 2; ++st_)                        \
  _Pragma("unroll") for (int ks_ = 0; ks_ < 2; ++ks_) {                      \
    const int rr_ = st_ * 16 + l15;                                          \
    const int cc_ = ((ks_ * 4 + lg) ^ (l15 & 7)) << 3;                       \
    bf16x8 xh_ = *reinterpret_cast<const bf16x8*>(&Xh[rr_][cc_]);            \
    _Pragma("unroll") for (int mtl_ = 0; mtl_ < 2; ++mtl_)                   \
        MFMAB(WX[st_][mtl_], xh_, ph[mtl_][ks_]);                            \
  }

// ---------------------------------------------------------------------------
// f32 -> fp16 conversion pass (16777216 elements).
// ---------------------------------------------------------------------------
__global__ __launch_bounds__(256) void cvt_f16_kernel(
    const float* __restrict__ in, _Float16* __restrict__ out) {
  const size_t stride = (size_t)gridDim.x * 256 * 8;
  for (size_t i = ((size_t)blockIdx.x * 256 + threadIdx.x) * 8; i < 16777216UL;
       i += stride) {
    float4 a = *reinterpret_cast<const float4*>(in + i);
    float4 b = *reinterpret_cast<const float4*>(in + i + 4);
    f16x8 h;
    h[0] = (_Float16)a.x; h[1] = (_Float16)a.y;
    h[2] = (_Float16)a.z; h[3] = (_Float16)a.w;
    h[4] = (_Float16)b.x; h[5] = (_Float16)b.y;
    h[6] = (_Float16)b.z; h[7] = (_Float16)b.w;
    *reinterpret_cast<f16x8*>(out + i) = h;
  }
}

// ---------------------------------------------------------------------------
// Weight transform: W[1024 k][1024 n] f32 -> WT [n][k] fp16.
// ---------------------------------------------------------------------------
__global__ __launch_bounds__(256) void wt_f16_kernel(
    const float* __restrict__ W, _Float16* __restrict__ T) {
  __shared__ float t[32][33];
  const int tx = threadIdx.x & 31, ty = threadIdx.x >> 5;
  const int k0 = blockIdx.x * 32, n0 = blockIdx.y * 32;
#pragma unroll
  for (int i = 0; i < 4; ++i)
    t[ty + 8 * i][tx] = W[(size_t)(k0 + ty + 8 * i) * 1024 + n0 + tx];
  __syncthreads();
#pragma unroll
  for (int i = 0; i < 4; ++i)
    T[(size_t)(n0 + ty + 8 * i) * 1024 + k0 + tx] = (_Float16)t[tx][ty + 8 * i];
}

// ---------------------------------------------------------------------------
// Pipelined fp16 GEMM, 256x256 tile (R15, verified): 512 threads, BK=32,
// 4-deep LDS, issue-ahead 2, counted vmcnt(8).
// ---------------------------------------------------------------------------
template <int F16OUT>
__global__ __launch_bounds__(512) void gemm_lds(
    const _Float16* __restrict__ A16, const _Float16* __restrict__ BT,
    const float* __restrict__ bias, void* __restrict__ Cout) {
  __shared__ _Float16 As[4][256][32];
  __shared__ _Float16 Bs[4][256][32];
  const int tid = threadIdx.x;
  const int bid = blockIdx.x;
  const int m0 = (bid & 63) << 8;
  const int n0 = (bid >> 6) << 8;
  const int wave = tid >> 6, lane = tid & 63;
  const int wm = (wave >> 2) << 7;
  const int wn = (wave & 3) << 6;
  const int l15 = lane & 15, lg = lane >> 4;

  const int rlo = tid >> 2;
  const int cg = ((tid & 3) ^ ((rlo >> 1) & 3)) << 3;
  const int wqbase = wave << 10;

  const _Float16* pa = A16 + (size_t)(m0 + rlo) * 1024 + cg;
  const _Float16* pb = BT + (size_t)(n0 + rlo) * 1024 + cg;

  f32x4 acc[8][4];
#pragma unroll
  for (int i = 0; i < 8; ++i)
#pragma unroll
    for (int j = 0; j < 4; ++j) acc[i][j] = f32x4{0.f, 0.f, 0.f, 0.f};

#define STAGE_T(nb, kt)                                                   \
  {                                                                       \
    char* la = (char*)&As[nb][0][0] + wqbase;                             \
    char* lb = (char*)&Bs[nb][0][0] + wqbase;                             \
    GLDS(pa + (kt) * 32, la);                                             \
    GLDS(pa + (kt) * 32 + 131072, la + 8192);                             \
    GLDS(pb + (kt) * 32, lb);                                             \
    GLDS(pb + (kt) * 32 + 131072, lb + 8192);                             \
  }

#define PIPE_BAR(N)                                                       \
  asm volatile("s_waitcnt vmcnt(" #N ")" ::: "memory");                   \
  __builtin_amdgcn_s_barrier();                                           \
  asm volatile("" ::: "memory");                                          \
  __builtin_amdgcn_sched_barrier(0);

#define COMPUTE(cur)                                                      \
  {                                                                       \
    f16x8 bf[4];                                                          \
    _Pragma("unroll") for (int fn = 0; fn < 4; ++fn) {                    \
      const int r = wn + fn * 16 + l15;                                   \
      bf[fn] = *reinterpret_cast<const f16x8*>(                           \
          &Bs[cur][r][(lg ^ ((r >> 1) & 3)) << 3]);                       \
    }                                                                     \
    _Pragma("unroll") for (int fm = 0; fm < 8; ++fm) {                    \
      const int r = wm + fm * 16 + l15;                                   \
      f16x8 av = *reinterpret_cast<const f16x8*>(                         \
          &As[cur][r][(lg ^ ((r >> 1) & 3)) << 3]);                       \
      _Pragma("unroll") for (int fn = 0; fn < 4; ++fn)                    \
        acc[fm][fn] = __builtin_amdgcn_mfma_f32_16x16x32_f16(             \
            av, bf[fn], acc[fm][fn], 0, 0, 0);                            \
    }                                                                     \
  }

  STAGE_T(0, 0);
  STAGE_T(1, 1);

  for (int kt = 0; kt < 30; ++kt) {
    STAGE_T((kt + 2) & 3, kt + 2);
    PIPE_BAR(8);
    COMPUTE(kt & 3);
  }
  PIPE_BAR(4);
  COMPUTE(2);  // kt = 30
  PIPE_BAR(0);
  COMPUTE(3);  // kt = 31

#pragma unroll
  for (int fm = 0; fm < 8; ++fm) {
    const int row = m0 + wm + fm * 16 + (lg << 2);
#pragma unroll
    for (int fn = 0; fn < 4; ++fn) {
      const int col = n0 + wn + fn * 16 + l15;
      const float bc = bias[col];
      f32x4 v = acc[fm][fn];
      if (F16OUT) {
        _Float16* C = (_Float16*)Cout;
#pragma unroll
        for (int j = 0; j < 4; ++j)
          C[(size_t)(row + j) * 1024 + col] = (_Float16)(v[j] + bc);
      } else {
        float* C = (float*)Cout;
#pragma unroll
        for (int j = 0; j < 4; ++j) C[(size_t)(row + j) * 1024 + col] = v[j] + bc;
      }
    }
  }
#undef STAGE_T
#undef PIPE_BAR
#undef COMPUTE
}

// ---------------------------------------------------------------------------
// wxmax: global max of wx_k via MFMA. 512 blocks; depth-1 prefetch.
// ---------------------------------------------------------------------------
__global__ __launch_bounds__(256) void wxmax_mfma_kernel(
    const _Float16* __restrict__ kproj, const float* __restrict__ proj,
    float* __restrict__ blockmax) {
  __shared__ unsigned short Xh[32][64];
  __shared__ float diags[32];  // unused (WANT_DIAG=false)
  __shared__ float redw[4];
  const int tid = threadIdx.x, blk = blockIdx.x;
  const int lane = tid & 63, w = tid >> 6;
  const int l15 = lane & 15, lg = lane >> 4;
  (void)diags;

  bf16x8 ph[2][2];
#pragma unroll
  for (int mtl = 0; mtl < 2; ++mtl)
#pragma unroll
    for (int ks = 0; ks < 2; ++ks)
      load_pfrag(proj, (2 * w + mtl) * 16 + l15, ks * 32 + lg * 8, &ph[mtl][ks]);

  float gmax = -3.4e38f;
  const int srow = tid >> 3, q8 = (tid & 7) << 3;
  const int xc = ((q8 >> 3) ^ (srow & 7)) << 3;

  f16x8 xk = *reinterpret_cast<const f16x8*>(
      kproj + (size_t)(blk * 512 + srow) * 64 + q8);

  for (int batch = 0; batch < 16; ++batch) {
    STAGE_XR(xk, false);
    f16x8 xk2;
    if (batch < 15)
      xk2 = *reinterpret_cast<const f16x8*>(
          kproj + (size_t)(blk * 512 + (batch + 1) * 32 + srow) * 64 + q8);
    __syncthreads();
    f32x4 wx[2][2];
#pragma unroll
    for (int st = 0; st < 2; ++st)
#pragma unroll
      for (int mtl = 0; mtl < 2; ++mtl) wx[st][mtl] = f32x4{0, 0, 0, 0};
    WX_COMPUTE(wx);
#pragma unroll
    for (int st = 0; st < 2; ++st)
#pragma unroll
      for (int mtl = 0; mtl < 2; ++mtl)
#pragma unroll
        for (int r = 0; r < 4; ++r) gmax = fmaxf(gmax, wx[st][mtl][r]);
    __syncthreads();
    if (batch < 15) xk = xk2;
  }
#pragma unroll
  for (int off = 32; off; off >>= 1) gmax = fmaxf(gmax, __shfl_xor(gmax, off));
  if (lane == 0) redw[w] = gmax;
  __syncthreads();
  if (tid == 0)
    blockmax[blk] = fmaxf(fmaxf(redw[0], redw[1]), fmaxf(redw[2], redw[3]));
}

__global__ __launch_bounds__(256) void maxreduce_kernel(
    const float* __restrict__ blockmax, float* __restrict__ stab, int n) {
  __shared__ float sm[256];
  float v = -3.4e38f;
  for (int i = threadIdx.x; i < n; i += 256) v = fmaxf(v, blockmax[i]);
  sm[threadIdx.x] = v;
  __syncthreads();
  for (int s = 128; s; s >>= 1) {
    if (threadIdx.x < s)
      sm[threadIdx.x] = fmaxf(sm[threadIdx.x], sm[threadIdx.x + s]);
    __syncthreads();
  }
  if (threadIdx.x == 0) *stab = sm[0];
}

// ---------------------------------------------------------------------------
// kv: kv[m][d] = sum_s phi_k[s][m] V[s][d], plus k1[m].
// 1024 blocks = 64 bh x 16 chunks of 256 s; depth-1 prefetch of (k,v).
// ---------------------------------------------------------------------------
__global__ __launch_bounds__(256) void kv_mfma_kernel(
    const _Float16* __restrict__ kproj, const _Float16* __restrict__ vproj,
    const float* __restrict__ proj, const float* __restrict__ stabp,
    float* __restrict__ kvpartT, float* __restrict__ k1part) {
  __shared__ unsigned short Xh[32][64];
  __shared__ float Vs[32][66];
  __shared__ unsigned short phiTh[128][40];
  __shared__ float diags[32];
  const int tid = threadIdx.x, blk = blockIdx.x;
  const int c = blk & 15, bh = blk >> 4, b = bh >> 4, h = bh & 15;
  const int lane = tid & 63, w = tid >> 6;
  const int l15 = lane & 15, lg = lane >> 4;
  const float stab = *stabp;

  bf16x8 ph[2][2];
#pragma unroll
  for (int mtl = 0; mtl < 2; ++mtl)
#pragma unroll
    for (int ks = 0; ks < 2; ++ks)
      load_pfrag(proj, (2 * w + mtl) * 16 + l15, ks * 32 + lg * 8, &ph[mtl][ks]);

  f32x4 akv[2][4];
#pragma unroll
  for (int i = 0; i < 2; ++i)
#pragma unroll
    for (int j = 0; j < 4; ++j) akv[i][j] = f32x4{0, 0, 0, 0};
  float k1acc[2] = {0.f, 0.f};

  const int srow = tid >> 3, q8 = (tid & 7) << 3;
  const int xc = ((q8 >> 3) ^ (srow & 7)) << 3;

  size_t rb = (((size_t)(b * S_ + c * 256 + srow) * H_ + h)) << 6;
  f16x8 xk = *reinterpret_cast<const f16x8*>(kproj + rb + q8);
  f16x8 xv = *reinterpret_cast<const f16x8*>(vproj + rb + q8);

  for (int batch = 0; batch < 8; ++batch) {
    STAGE_XR(xk, true);
    {
#pragma unroll
      for (int j = 0; j < 8; ++j) Vs[srow][q8 + j] = (float)xv[j];
    }
    f16x8 xk2, xv2;
    if (batch < 7) {
      const size_t rb2 =
          (((size_t)(b * S_ + c * 256 + (batch + 1) * 32 + srow) * H_ + h)) << 6;
      xk2 = *reinterpret_cast<const f16x8*>(kproj + rb2 + q8);
      xv2 = *reinterpret_cast<const f16x8*>(vproj + rb2 + q8);
    }
    __syncthreads();  // bar1

    f32x4 wx[2][2];
#pragma unroll
    for (int st = 0; st < 2; ++st)
#pragma unroll
      for (int mtl = 0; mtl < 2; ++mtl) wx[st][mtl] = f32x4{0, 0, 0, 0};
    WX_COMPUTE(wx);

    // phi + phiT write + k1 (reference scale: exp(wx - diag - stab) * CM)
#pragma unroll
    for (int st = 0; st < 2; ++st)
#pragma unroll
      for (int mtl = 0; mtl < 2; ++mtl) {
        const int m = (2 * w + mtl) * 16 + l15;
        s16x4 hv;
        float psum = 0.f;
#pragma unroll
        for (int r = 0; r < 4; ++r) {
          const int s = st * 16 + lg * 4 + r;
          float p = __expf(wx[st][mtl][r] - diags[s] - stab) * CM;
          psum += p;
          hv[r] = (short)f2bf(p);
        }
        k1acc[mtl] += psum;
        *reinterpret_cast<s16x4*>(&phiTh[m][st * 16 + lg * 4]) = hv;
      }
    __syncthreads();  // bar2

    // kv contraction: A = phiT[m][s], B = V[s][d]
    bf16x8 pah[2];
#pragma unroll
    for (int mtl = 0; mtl < 2; ++mtl)
      pah[mtl] = *reinterpret_cast<const bf16x8*>(
          &phiTh[(2 * w + mtl) * 16 + l15][lg * 8]);
#pragma unroll
    for (int dt = 0; dt < 4; ++dt) {
      bf16x8 bvh;
#pragma unroll
      for (int j = 0; j < 8; ++j)
        bvh[j] = (short)f2bf(Vs[lg * 8 + j][dt * 16 + l15]);
#pragma unroll
      for (int mtl = 0; mtl < 2; ++mtl) MFMAB(akv[mtl][dt], pah[mtl], bvh);
    }
    __syncthreads();  // bar3
    if (batch < 7) {
      xk = xk2;
      xv = xv2;
    }
  }

#pragma unroll
  for (int mtl = 0; mtl < 2; ++mtl) {
#pragma unroll
    for (int dt = 0; dt < 4; ++dt) {
      const int d = dt * 16 + l15, m0 = (2 * w + mtl) * 16 + lg * 4;
      *reinterpret_cast<f32x4*>(&kvpartT[(size_t)blk * 8192 + d * 128 + m0]) =
          akv[mtl][dt];
    }
    float kk = k1acc[mtl];
    kk += __shfl_xor(kk, 16);
    kk += __shfl_xor(kk, 32);
    if (lane < 16) k1part[blk * 128 + (2 * w + mtl) * 16 + lane] = kk;
  }
}

__global__ __launch_bounds__(256) void kvreduce_kernel(
    const float* __restrict__ kvpartT, const float* __restrict__ k1part,
    unsigned short* __restrict__ kvT, float* __restrict__ k1) {
  const int bh = blockIdx.x;
  for (int i = threadIdx.x; i < 8192; i += 256) {
    float s = 0.f;
#pragma unroll
    for (int c = 0; c < 16; ++c) s += kvpartT[(size_t)(bh * 16 + c) * 8192 + i];
    kvT[(size_t)bh * 8192 + i] = f2bf(s);
  }
  if (threadIdx.x < 128) {
    float s = 0.f;
#pragma unroll
    for (int c = 0; c < 16; ++c) s += k1part[(bh * 16 + c) * 128 + threadIdx.x];
    k1[bh * 128 + threadIdx.x] = s;
  }
}

// ---------------------------------------------------------------------------
// qkv: phi_q = exp(wx - diag - rmax) * CM. 2048 blocks = 64 bh x 32 chunks
// of 128 t. All 4 batches' X prefetched into registers at entry (T14).
// ---------------------------------------------------------------------------
__global__ __launch_bounds__(256) void qkv_mfma_kernel(
    const _Float16* __restrict__ qproj, const unsigned short* __restrict__ kvT,
    const float* __restrict__ k1g, const float* __restrict__ proj,
    _Float16* __restrict__ outh) {
  __shared__ unsigned short Xh[32][64];
  __shared__ unsigned short Ph[32][128];
  __shared__ float k1s[128];
  __shared__ float diags[32];
  __shared__ float rmaxp[4][32];
  __shared__ float denp[4][32];
  const int tid = threadIdx.x, blk = blockIdx.x;
  const int ch = blk & 31, bh = blk >> 5, b = bh >> 4, h = bh & 15;
  const int lane = tid & 63, w = tid >> 6;
  const int l15 = lane & 15, lg = lane >> 4;

  bf16x8 ph[2][2];
#pragma unroll
  for (int mtl = 0; mtl < 2; ++mtl)
#pragma unroll
    for (int ks = 0; ks < 2; ++ks)
      load_pfrag(proj, (2 * w + mtl) * 16 + l15, ks * 32 + lg * 8, &ph[mtl][ks]);

  bf16x8 kah[4];
#pragma unroll
  for (int ks = 0; ks < 4; ++ks) {
    const size_t o = (size_t)bh * 8192 + (w * 16 + l15) * 128 + ks * 32 + lg * 8;
    kah[ks] = *reinterpret_cast<const bf16x8*>(kvT + o);
  }
  if (tid < 128) k1s[tid] = k1g[bh * 128 + tid];

  const int srow = tid >> 3, q8 = (tid & 7) << 3;
  const int xc = ((q8 >> 3) ^ (srow & 7)) << 3;

  // T14: prefetch all 4 batches' X at entry.
  f16x8 xpre[4];
#pragma unroll
  for (int batch = 0; batch < 4; ++batch) {
    const int s0 = ch * 128 + batch * 32;
    xpre[batch] = *reinterpret_cast<const f16x8*>(
        qproj + ((((size_t)(b * S_ + s0 + srow) * H_ + h)) << 6) + q8);
  }

#pragma unroll
  for (int batch = 0; batch < 4; ++batch) {
    const int s0 = ch * 128 + batch * 32;
    STAGE_XR(xpre[batch], true);
    __syncthreads();  // bar1

    f32x4 wx[2][2];
#pragma unroll
    for (int st = 0; st < 2; ++st)
#pragma unroll
      for (int mtl = 0; mtl < 2; ++mtl) wx[st][mtl] = f32x4{0, 0, 0, 0};
    WX_COMPUTE(wx);

#pragma unroll
    for (int st = 0; st < 2; ++st)
#pragma unroll
      for (int r = 0; r < 4; ++r) {
        float v = fmaxf(wx[st][0][r], wx[st][1][r]);
        v = fmaxf(v, __shfl_xor(v, 1));
        v = fmaxf(v, __shfl_xor(v, 2));
        v = fmaxf(v, __shfl_xor(v, 4));
        v = fmaxf(v, __shfl_xor(v, 8));
        if (l15 == 0) rmaxp[w][st * 16 + lg * 4 + r] = v;
      }
    __syncthreads();  // bar2

#pragma unroll
    for (int st = 0; st < 2; ++st) {
      float off[4];
#pragma unroll
      for (int r = 0; r < 4; ++r) {
        const int s = st * 16 + lg * 4 + r;
        float rmx = fmaxf(fmaxf(rmaxp[0][s], rmaxp[1][s]),
                          fmaxf(rmaxp[2][s], rmaxp[3][s]));
        off[r] = rmx + diags[s];
      }
      float den[4] = {0.f, 0.f, 0.f, 0.f};
#pragma unroll
      for (int mtl = 0; mtl < 2; ++mtl) {
        const int m = (2 * w + mtl) * 16 + l15;
        const float k1v = k1s[m];
#pragma unroll
        for (int r = 0; r < 4; ++r) {
          const int s = st * 16 + lg * 4 + r;
          float p = __expf(wx[st][mtl][r] - off[r]) * CM;
          den[r] += p * k1v;
          Ph[s][((((m >> 3) ^ (s & 7)) << 3) | (m & 7))] = f2bf(p);
        }
      }
#pragma unroll
      for (int r = 0; r < 4; ++r) {
        float v = den[r];
        v += __shfl_xor(v, 1);
        v += __shfl_xor(v, 2);
        v += __shfl_xor(v, 4);
        v += __shfl_xor(v, 8);
        if (l15 == 0) denp[w][st * 16 + lg * 4 + r] = v;
      }
    }
    __syncthreads();  // bar3

#pragma unroll
    for (int st = 0; st < 2; ++st) {
      f32x4 od = {0.f, 0.f, 0.f, 0.f};
#pragma unroll
      for (int ks = 0; ks < 4; ++ks) {
        const int cc = ((ks * 4 + lg) ^ (l15 & 7)) << 3;
        bf16x8 bph = *reinterpret_cast<const bf16x8*>(&Ph[st * 16 + l15][cc]);
        MFMAB(od, kah[ks], bph);
      }
      const int s = st * 16 + l15;
      const float dens =
          1.f / (denp[0][s] + denp[1][s] + denp[2][s] + denp[3][s] + 1e-6f);
      f16x4 o;
#pragma unroll
      for (int j = 0; j < 4; ++j) o[j] = (_Float16)(od[j] * dens);
      *reinterpret_cast<f16x4*>(
          &outh[(size_t)(b * S_ + s0 + s) * 1024 + h * 64 + w * 16 + lg * 4]) = o;
    }
    __syncthreads();  // bar4
  }
}

// ---------------------------------------------------------------------------
extern "C" void kernel_launch(void* const* d_in, const int* in_sizes, int n_in,
                              void* d_out, int out_size, void* d_ws,
                              size_t ws_size, hipStream_t stream) {
  const float* query = (const float*)d_in[0];
  const float* value = (const float*)d_in[1];
  const float* key   = (const float*)d_in[2];
  const float* Wq = (const float*)d_in[3];
  const float* bq = (const float*)d_in[4];
  const float* Wk = (const float*)d_in[5];
  const float* bk = (const float*)d_in[6];
  const float* Wv = (const float*)d_in[7];
  const float* bv = (const float*)d_in[8];
  const float* Wo = (const float*)d_in[9];
  const float* bo = (const float*)d_in[10];
  const float* proj = (const float*)d_in[11];
  float* out = (float*)d_out;
  float* ws = (float*)d_ws;

  _Float16* KP16 = (_Float16*)(ws + OFF_A);   // kproj then qproj (fp16)
  _Float16* VP16 = (_Float16*)(ws + OFF_B);   // vproj (fp16)
  _Float16* WT = (_Float16*)(ws + OFF_X);
  float* K1P = ws + OFF_X;                    // k1part (WT dead at kv time)
  unsigned short* KVT = (unsigned short*)(ws + OFF_KV);
  float* K1 = ws + OFF_K1;
  float* BMX = ws + OFF_BM;
  float* ST = ws + OFF_ST;
  _Float16* X16 = (_Float16*)(ws + OFF_A16);  // GEMM A staging
  float* KVPT = ws + OFF_A16;                 // kv partials (staging dead)

  dim3 gw(32, 32);

  // 1. k_proj (fp16)
  cvt_f16_kernel<<<2048, 256, 0, stream>>>(key, X16);
  wt_f16_kernel<<<gw, 256, 0, stream>>>(Wk, WT);
  gemm_lds<1><<<256, 512, 0, stream>>>(X16, WT, bk, KP16);
  // 2. stab (reference global max wx_k)
  wxmax_mfma_kernel<<<512, 256, 0, stream>>>(KP16, proj, BMX);
  maxreduce_kernel<<<1, 256, 0, stream>>>(BMX, ST, 512);
  // 3. v_proj (fp16)
  cvt_f16_kernel<<<2048, 256, 0, stream>>>(value, X16);
  wt_f16_kernel<<<gw, 256, 0, stream>>>(Wv, WT);
  gemm_lds<1><<<256, 512, 0, stream>>>(X16, WT, bv, VP16);
  // 4. kv / k1 (KVPT aliases X16 staging — dead; K1P aliases WT — dead)
  kv_mfma_kernel<<<1024, 256, 0, stream>>>(KP16, VP16, proj, ST, KVPT, K1P);
  kvreduce_kernel<<<64, 256, 0, stream>>>(KVPT, K1P, KVT, K1);
  // 5. q_proj (KVPT dead after reduce; kproj dead after kv)
  cvt_f16_kernel<<<2048, 256, 0, stream>>>(query, X16);
  wt_f16_kernel<<<gw, 256, 0, stream>>>(Wq, WT);
  gemm_lds<1><<<256, 512, 0, stream>>>(X16, WT, bq, KP16);
  // 6. out_h -> X16 as fp16 (query staging dead after q_proj gemm)
  qkv_mfma_kernel<<<2048, 256, 0, stream>>>(KP16, KVT, K1, proj, X16);
  // 7. output projection (f32 out)
  wt_f16_kernel<<<gw, 256, 0, stream>>>(Wo, WT);
  gemm_lds<0><<<256, 512, 0, stream>>>(X16, WT, bo, out);
}

// Round 17
// 301.469 us; speedup vs baseline: 11.5883x; 1.0892x over previous
//
#include <hip/hip_runtime.h>
#include <hip/hip_bf16.h>

// Performer (FAVOR+) forward. Round 17: barrier-free wave-local qkv (each
// wave owns 16 t-rows entirely: wave-local softmax reductions, per-wave phi
// transpose buffer, P/kvT staged once in swizzled LDS; zero barriers in the
// main loop). qkv prefetch from R16 reverted (regressed). Everything else
// identical to R16 (passed, 328us, absmax 9.77e-3).
// B=4, S=4096, D=1024, H=16, K=64, M=128.

#define B_  4
#define S_  4096
#define H_  16

#define SCALE_X 0.3535533905932738f     // 64^-0.25
#define CM      0.08838834764831845f    // 128^-0.5

typedef __attribute__((ext_vector_type(8))) short bf16x8;
typedef __attribute__((ext_vector_type(4))) short s16x4;
typedef __attribute__((ext_vector_type(8))) unsigned short u16x8;
typedef __attribute__((ext_vector_type(8))) _Float16 f16x8;
typedef __attribute__((ext_vector_type(4))) _Float16 f16x4;
typedef __attribute__((ext_vector_type(4))) float f32x4;

// ---- ws layout (float units) ----
#define OFF_A    ((size_t)0)          // kproj16 then qproj16 (fp16, 32MB)
#define OFF_B    ((size_t)16777216)   // vproj16 (fp16)
#define OFF_X    ((size_t)33554432)   // union: WT fp16 / k1part(131072)
#define OFF_KV   ((size_t)37814272)   // kvT bf16: 524288 ush
#define OFF_K1   ((size_t)38338560)   // 64*128 f32
#define OFF_BM   ((size_t)38346752)   // 512 block maxes
#define OFF_ST   ((size_t)38347264)   // stab scalar
#define OFF_A16  ((size_t)38347776)   // 8388608 f32: GEMM A staging / kvpartT
// total 46736384 f32 = 186.9 MB

__device__ __forceinline__ unsigned short f2bf(float x) {
  union { __hip_bfloat16 b; unsigned short u; } c;
  c.b = __float2bfloat16(x);
  return c.u;
}

#define MFMAB(ACC, A, B)                                               \
  ACC = __builtin_amdgcn_mfma_f32_16x16x32_bf16(A, B, ACC, 0, 0, 0)

#define GLDS(GP, LP)                                                  \
  __builtin_amdgcn_global_load_lds(                                   \
      (const __attribute__((address_space(1))) unsigned int*)(GP),    \
      (__attribute__((address_space(3))) unsigned int*)(LP), 16, 0, 0)

// load P-operand fragment (B for wx): lane supplies P[m][kb..kb+7] as bf16
__device__ __forceinline__ void load_pfrag(const float* __restrict__ proj, int m,
                                           int kb, bf16x8* ph) {
  const float* p = proj + m * 64 + kb;
  float4 a = *reinterpret_cast<const float4*>(p);
  float4 b = *reinterpret_cast<const float4*>(p + 4);
  float v[8] = {a.x, a.y, a.z, a.w, b.x, b.y, b.z, b.w};
  bf16x8 h;
#pragma unroll
  for (int j = 0; j < 8; ++j) h[j] = (short)f2bf(v[j]);
  *ph = h;
}

// Stage one X row-chunk FROM REGISTERS: scale, bf16, chunk-XOR LDS write.
#define STAGE_XR(XV, WANT_DIAG)                                           \
  {                                                                       \
    f16x8 xv_ = (XV);                                                     \
    u16x8 hh_;                                                            \
    float sq_ = 0.f;                                                      \
    _Pragma("unroll") for (int j = 0; j < 8; ++j) {                       \
      float vf_ = (float)xv_[j] * SCALE_X;                                \
      sq_ += vf_ * vf_;                                                   \
      hh_[j] = f2bf(vf_);                                                 \
    }                                                                     \
    *reinterpret_cast<u16x8*>(&Xh[srow][xc]) = hh_;                       \
    if (WANT_DIAG) {                                                      \
      sq_ += __shfl_xor(sq_, 1);                                          \
      sq_ += __shfl_xor(sq_, 2);                                          \
      sq_ += __shfl_xor(sq_, 4);                                          \
      if ((tid & 7) == 0) diags[srow] = 0.5f * sq_;                       \
    }                                                                     \
  }

// wx MFMA block: 2 st x 2 ks x 2 mtl, single bf16 MFMA each.
#define WX_COMPUTE(WX)                                                       \
  _Pragma("unroll") for (int st_ = 0; st_ < 2; ++st_)                        \
  _Pragma("unroll") for (int ks_ = 0; ks_ < 2; ++ks_) {                      \
    const int rr_ = st_ * 16 + l15;                                          \
    const int cc_ = ((ks_ * 4 + lg) ^ (l15 & 7)) << 3;                       \
    bf16x8 xh_ = *reinterpret_cast<const bf16x8*>(&Xh[rr_][cc_]);            \
    _Pragma("unroll") for (int mtl_ = 0; mtl_ < 2; ++mtl_)                   \
        MFMAB(WX[st_][mtl_], xh_, ph[mtl_][ks_]);                            \
  }

// ---------------------------------------------------------------------------
// f32 -> fp16 conversion pass (16777216 elements).
// ---------------------------------------------------------------------------
__global__ __launch_bounds__(256) void cvt_f16_kernel(
    const float* __restrict__ in, _Float16* __restrict__ out) {
  const size_t stride = (size_t)gridDim.x * 256 * 8;
  for (size_t i = ((size_t)blockIdx.x * 256 + threadIdx.x) * 8; i < 16777216UL;
       i += stride) {
    float4 a = *reinterpret_cast<const float4*>(in + i);
    float4 b = *reinterpret_cast<const float4*>(in + i + 4);
    f16x8 h;
    h[0] = (_Float16)a.x; h[1] = (_Float16)a.y;
    h[2] = (_Float16)a.z; h[3] = (_Float16)a.w;
    h[4] = (_Float16)b.x; h[5] = (_Float16)b.y;
    h[6] = (_Float16)b.z; h[7] = (_Float16)b.w;
    *reinterpret_cast<f16x8*>(out + i) = h;
  }
}

// ---------------------------------------------------------------------------
// Weight transform: W[1024 k][1024 n] f32 -> WT [n][k] fp16.
// ---------------------------------------------------------------------------
__global__ __launch_bounds__(256) void wt_f16_kernel(
    const float* __restrict__ W, _Float16* __restrict__ T) {
  __shared__ float t[32][33];
  const int tx = threadIdx.x & 31, ty = threadIdx.x >> 5;
  const int k0 = blockIdx.x * 32, n0 = blockIdx.y * 32;
#pragma unroll
  for (int i = 0; i < 4; ++i)
    t[ty + 8 * i][tx] = W[(size_t)(k0 + ty + 8 * i) * 1024 + n0 + tx];
  __syncthreads();
#pragma unroll
  for (int i = 0; i < 4; ++i)
    T[(size_t)(n0 + ty + 8 * i) * 1024 + k0 + tx] = (_Float16)t[tx][ty + 8 * i];
}

// ---------------------------------------------------------------------------
// Pipelined fp16 GEMM, 256x256 tile (R15, verified): 512 threads, BK=32,
// 4-deep LDS, issue-ahead 2, counted vmcnt(8).
// ---------------------------------------------------------------------------
template <int F16OUT>
__global__ __launch_bounds__(512) void gemm_lds(
    const _Float16* __restrict__ A16, const _Float16* __restrict__ BT,
    const float* __restrict__ bias, void* __restrict__ Cout) {
  __shared__ _Float16 As[4][256][32];
  __shared__ _Float16 Bs[4][256][32];
  const int tid = threadIdx.x;
  const int bid = blockIdx.x;
  const int m0 = (bid & 63) << 8;
  const int n0 = (bid >> 6) << 8;
  const int wave = tid >> 6, lane = tid & 63;
  const int wm = (wave >> 2) << 7;
  const int wn = (wave & 3) << 6;
  const int l15 = lane & 15, lg = lane >> 4;

  const int rlo = tid >> 2;
  const int cg = ((tid & 3) ^ ((rlo >> 1) & 3)) << 3;
  const int wqbase = wave << 10;

  const _Float16* pa = A16 + (size_t)(m0 + rlo) * 1024 + cg;
  const _Float16* pb = BT + (size_t)(n0 + rlo) * 1024 + cg;

  f32x4 acc[8][4];
#pragma unroll
  for (int i = 0; i < 8; ++i)
#pragma unroll
    for (int j = 0; j < 4; ++j) acc[i][j] = f32x4{0.f, 0.f, 0.f, 0.f};

#define STAGE_T(nb, kt)                                                   \
  {                                                                       \
    char* la = (char*)&As[nb][0][0] + wqbase;                             \
    char* lb = (char*)&Bs[nb][0][0] + wqbase;                             \
    GLDS(pa + (kt) * 32, la);                                             \
    GLDS(pa + (kt) * 32 + 131072, la + 8192);                             \
    GLDS(pb + (kt) * 32, lb);                                             \
    GLDS(pb + (kt) * 32 + 131072, lb + 8192);                             \
  }

#define PIPE_BAR(N)                                                       \
  asm volatile("s_waitcnt vmcnt(" #N ")" ::: "memory");                   \
  __builtin_amdgcn_s_barrier();                                           \
  asm volatile("" ::: "memory");                                          \
  __builtin_amdgcn_sched_barrier(0);

#define COMPUTE(cur)                                                      \
  {                                                                       \
    f16x8 bf[4];                                                          \
    _Pragma("unroll") for (int fn = 0; fn < 4; ++fn) {                    \
      const int r = wn + fn * 16 + l15;                                   \
      bf[fn] = *reinterpret_cast<const f16x8*>(                           \
          &Bs[cur][r][(lg ^ ((r >> 1) & 3)) << 3]);                       \
    }                                                                     \
    _Pragma("unroll") for (int fm = 0; fm < 8; ++fm) {                    \
      const int r = wm + fm * 16 + l15;                                   \
      f16x8 av = *reinterpret_cast<const f16x8*>(                         \
          &As[cur][r][(lg ^ ((r >> 1) & 3)) << 3]);                       \
      _Pragma("unroll") for (int fn = 0; fn < 4; ++fn)                    \
        acc[fm][fn] = __builtin_amdgcn_mfma_f32_16x16x32_f16(             \
            av, bf[fn], acc[fm][fn], 0, 0, 0);                            \
    }                                                                     \
  }

  STAGE_T(0, 0);
  STAGE_T(1, 1);

  for (int kt = 0; kt < 30; ++kt) {
    STAGE_T((kt + 2) & 3, kt + 2);
    PIPE_BAR(8);
    COMPUTE(kt & 3);
  }
  PIPE_BAR(4);
  COMPUTE(2);  // kt = 30
  PIPE_BAR(0);
  COMPUTE(3);  // kt = 31

#pragma unroll
  for (int fm = 0; fm < 8; ++fm) {
    const int row = m0 + wm + fm * 16 + (lg << 2);
#pragma unroll
    for (int fn = 0; fn < 4; ++fn) {
      const int col = n0 + wn + fn * 16 + l15;
      const float bc = bias[col];
      f32x4 v = acc[fm][fn];
      if (F16OUT) {
        _Float16* C = (_Float16*)Cout;
#pragma unroll
        for (int j = 0; j < 4; ++j)
          C[(size_t)(row + j) * 1024 + col] = (_Float16)(v[j] + bc);
      } else {
        float* C = (float*)Cout;
#pragma unroll
        for (int j = 0; j < 4; ++j) C[(size_t)(row + j) * 1024 + col] = v[j] + bc;
      }
    }
  }
#undef STAGE_T
#undef PIPE_BAR
#undef COMPUTE
}

// ---------------------------------------------------------------------------
// wxmax: global max of wx_k via MFMA. 512 blocks; depth-1 prefetch (R16).
// ---------------------------------------------------------------------------
__global__ __launch_bounds__(256) void wxmax_mfma_kernel(
    const _Float16* __restrict__ kproj, const float* __restrict__ proj,
    float* __restrict__ blockmax) {
  __shared__ unsigned short Xh[32][64];
  __shared__ float diags[32];  // unused (WANT_DIAG=false)
  __shared__ float redw[4];
  const int tid = threadIdx.x, blk = blockIdx.x;
  const int lane = tid & 63, w = tid >> 6;
  const int l15 = lane & 15, lg = lane >> 4;
  (void)diags;

  bf16x8 ph[2][2];
#pragma unroll
  for (int mtl = 0; mtl < 2; ++mtl)
#pragma unroll
    for (int ks = 0; ks < 2; ++ks)
      load_pfrag(proj, (2 * w + mtl) * 16 + l15, ks * 32 + lg * 8, &ph[mtl][ks]);

  float gmax = -3.4e38f;
  const int srow = tid >> 3, q8 = (tid & 7) << 3;
  const int xc = ((q8 >> 3) ^ (srow & 7)) << 3;

  f16x8 xk = *reinterpret_cast<const f16x8*>(
      kproj + (size_t)(blk * 512 + srow) * 64 + q8);

  for (int batch = 0; batch < 16; ++batch) {
    STAGE_XR(xk, false);
    f16x8 xk2;
    if (batch < 15)
      xk2 = *reinterpret_cast<const f16x8*>(
          kproj + (size_t)(blk * 512 + (batch + 1) * 32 + srow) * 64 + q8);
    __syncthreads();
    f32x4 wx[2][2];
#pragma unroll
    for (int st = 0; st < 2; ++st)
#pragma unroll
      for (int mtl = 0; mtl < 2; ++mtl) wx[st][mtl] = f32x4{0, 0, 0, 0};
    WX_COMPUTE(wx);
#pragma unroll
    for (int st = 0; st < 2; ++st)
#pragma unroll
      for (int mtl = 0; mtl < 2; ++mtl)
#pragma unroll
        for (int r = 0; r < 4; ++r) gmax = fmaxf(gmax, wx[st][mtl][r]);
    __syncthreads();
    if (batch < 15) xk = xk2;
  }
#pragma unroll
  for (int off = 32; off; off >>= 1) gmax = fmaxf(gmax, __shfl_xor(gmax, off));
  if (lane == 0) redw[w] = gmax;
  __syncthreads();
  if (tid == 0)
    blockmax[blk] = fmaxf(fmaxf(redw[0], redw[1]), fmaxf(redw[2], redw[3]));
}

__global__ __launch_bounds__(256) void maxreduce_kernel(
    const float* __restrict__ blockmax, float* __restrict__ stab, int n) {
  __shared__ float sm[256];
  float v = -3.4e38f;
  for (int i = threadIdx.x; i < n; i += 256) v = fmaxf(v, blockmax[i]);
  sm[threadIdx.x] = v;
  __syncthreads();
  for (int s = 128; s; s >>= 1) {
    if (threadIdx.x < s)
      sm[threadIdx.x] = fmaxf(sm[threadIdx.x], sm[threadIdx.x + s]);
    __syncthreads();
  }
  if (threadIdx.x == 0) *stab = sm[0];
}

// ---------------------------------------------------------------------------
// kv: kv[m][d] = sum_s phi_k[s][m] V[s][d], plus k1[m]. (R16, verified)
// ---------------------------------------------------------------------------
__global__ __launch_bounds__(256) void kv_mfma_kernel(
    const _Float16* __restrict__ kproj, const _Float16* __restrict__ vproj,
    const float* __restrict__ proj, const float* __restrict__ stabp,
    float* __restrict__ kvpartT, float* __restrict__ k1part) {
  __shared__ unsigned short Xh[32][64];
  __shared__ float Vs[32][66];
  __shared__ unsigned short phiTh[128][40];
  __shared__ float diags[32];
  const int tid = threadIdx.x, blk = blockIdx.x;
  const int c = blk & 15, bh = blk >> 4, b = bh >> 4, h = bh & 15;
  const int lane = tid & 63, w = tid >> 6;
  const int l15 = lane & 15, lg = lane >> 4;
  const float stab = *stabp;

  bf16x8 ph[2][2];
#pragma unroll
  for (int mtl = 0; mtl < 2; ++mtl)
#pragma unroll
    for (int ks = 0; ks < 2; ++ks)
      load_pfrag(proj, (2 * w + mtl) * 16 + l15, ks * 32 + lg * 8, &ph[mtl][ks]);

  f32x4 akv[2][4];
#pragma unroll
  for (int i = 0; i < 2; ++i)
#pragma unroll
    for (int j = 0; j < 4; ++j) akv[i][j] = f32x4{0, 0, 0, 0};
  float k1acc[2] = {0.f, 0.f};

  const int srow = tid >> 3, q8 = (tid & 7) << 3;
  const int xc = ((q8 >> 3) ^ (srow & 7)) << 3;

  size_t rb = (((size_t)(b * S_ + c * 256 + srow) * H_ + h)) << 6;
  f16x8 xk = *reinterpret_cast<const f16x8*>(kproj + rb + q8);
  f16x8 xv = *reinterpret_cast<const f16x8*>(vproj + rb + q8);

  for (int batch = 0; batch < 8; ++batch) {
    STAGE_XR(xk, true);
    {
#pragma unroll
      for (int j = 0; j < 8; ++j) Vs[srow][q8 + j] = (float)xv[j];
    }
    f16x8 xk2, xv2;
    if (batch < 7) {
      const size_t rb2 =
          (((size_t)(b * S_ + c * 256 + (batch + 1) * 32 + srow) * H_ + h)) << 6;
      xk2 = *reinterpret_cast<const f16x8*>(kproj + rb2 + q8);
      xv2 = *reinterpret_cast<const f16x8*>(vproj + rb2 + q8);
    }
    __syncthreads();  // bar1

    f32x4 wx[2][2];
#pragma unroll
    for (int st = 0; st < 2; ++st)
#pragma unroll
      for (int mtl = 0; mtl < 2; ++mtl) wx[st][mtl] = f32x4{0, 0, 0, 0};
    WX_COMPUTE(wx);

#pragma unroll
    for (int st = 0; st < 2; ++st)
#pragma unroll
      for (int mtl = 0; mtl < 2; ++mtl) {
        const int m = (2 * w + mtl) * 16 + l15;
        s16x4 hv;
        float psum = 0.f;
#pragma unroll
        for (int r = 0; r < 4; ++r) {
          const int s = st * 16 + lg * 4 + r;
          float p = __expf(wx[st][mtl][r] - diags[s] - stab) * CM;
          psum += p;
          hv[r] = (short)f2bf(p);
        }
        k1acc[mtl] += psum;
        *reinterpret_cast<s16x4*>(&phiTh[m][st * 16 + lg * 4]) = hv;
      }
    __syncthreads();  // bar2

    bf16x8 pah[2];
#pragma unroll
    for (int mtl = 0; mtl < 2; ++mtl)
      pah[mtl] = *reinterpret_cast<const bf16x8*>(
          &phiTh[(2 * w + mtl) * 16 + l15][lg * 8]);
#pragma unroll
    for (int dt = 0; dt < 4; ++dt) {
      bf16x8 bvh;
#pragma unroll
      for (int j = 0; j < 8; ++j)
        bvh[j] = (short)f2bf(Vs[lg * 8 + j][dt * 16 + l15]);
#pragma unroll
      for (int mtl = 0; mtl < 2; ++mtl) MFMAB(akv[mtl][dt], pah[mtl], bvh);
    }
    __syncthreads();  // bar3
    if (batch < 7) {
      xk = xk2;
      xv = xv2;
    }
  }

#pragma unroll
  for (int mtl = 0; mtl < 2; ++mtl) {
#pragma unroll
    for (int dt = 0; dt < 4; ++dt) {
      const int d = dt * 16 + l15, m0 = (2 * w + mtl) * 16 + lg * 4;
      *reinterpret_cast<f32x4*>(&kvpartT[(size_t)blk * 8192 + d * 128 + m0]) =
          akv[mtl][dt];
    }
    float kk = k1acc[mtl];
    kk += __shfl_xor(kk, 16);
    kk += __shfl_xor(kk, 32);
    if (lane < 16) k1part[blk * 128 + (2 * w + mtl) * 16 + lane] = kk;
  }
}

__global__ __launch_bounds__(256) void kvreduce_kernel(
    const float* __restrict__ kvpartT, const float* __restrict__ k1part,
    unsigned short* __restrict__ kvT, float* __restrict__ k1) {
  const int bh = blockIdx.x;
  for (int i = threadIdx.x; i < 8192; i += 256) {
    float s = 0.f;
#pragma unroll
    for (int c = 0; c < 16; ++c) s += kvpartT[(size_t)(bh * 16 + c) * 8192 + i];
    kvT[(size_t)bh * 8192 + i] = f2bf(s);
  }
  if (threadIdx.x < 128) {
    float s = 0.f;
#pragma unroll
    for (int c = 0; c < 16; ++c) s += k1part[(bh * 16 + c) * 128 + threadIdx.x];
    k1[bh * 128 + threadIdx.x] = s;
  }
}

// ---------------------------------------------------------------------------
// qkv (wave-local, barrier-free): each wave owns 16 t-rows completely.
// 2048 blocks = 64 bh x 32 chunks of 128 t; wave w does 2 iters of 16 t.
// P[128][64] and kvT[64][128] staged once (chunk-XOR swizzle), phi goes
// through a per-wave swizzled transpose buffer (same-wave write->read).
// Numerics: same per-value ops as R16; only diag/den f32 reduce order moves.
// ---------------------------------------------------------------------------
__global__ __launch_bounds__(256) void qkv_wave_kernel(
    const _Float16* __restrict__ qproj, const unsigned short* __restrict__ kvT,
    const float* __restrict__ k1g, const float* __restrict__ proj,
    _Float16* __restrict__ outh) {
  __shared__ unsigned short Pl[128][64];    // bf16(P), chunk-XOR by (m&7)
  __shared__ unsigned short Kl[64][128];    // bf16(kvT), chunk-XOR by (d&7)
  __shared__ unsigned short Phw[4][16][128];// per-wave phi, chunk-XOR by (t&7)
  __shared__ float k1s[128];
  __shared__ float dgw[4][16];              // per-wave diag[t]
  __shared__ float dnw[4][16];              // per-wave den[t]
  const int tid = threadIdx.x, blk = blockIdx.x;
  const int ch = blk & 31, bh = blk >> 5, b = bh >> 4, h = bh & 15;
  const int lane = tid & 63, w = tid >> 6;
  const int l15 = lane & 15, lg = lane >> 4;

  // ---- cooperative staging (once) ----
  {
    const int r = tid >> 1;                 // P row m (0..127)
    const int cb = (tid & 1) << 2;          // chunk base 0 or 4
#pragma unroll
    for (int j = 0; j < 4; ++j) {
      const int ck = cb + j;                // 0..7
      float4 a = *reinterpret_cast<const float4*>(proj + r * 64 + ck * 8);
      float4 bq = *reinterpret_cast<const float4*>(proj + r * 64 + ck * 8 + 4);
      float v[8] = {a.x, a.y, a.z, a.w, bq.x, bq.y, bq.z, bq.w};
      u16x8 hh;
#pragma unroll
      for (int q = 0; q < 8; ++q) hh[q] = f2bf(v[q]);
      *reinterpret_cast<u16x8*>(&Pl[r][(ck ^ (r & 7)) << 3]) = hh;
    }
    const int d = tid >> 2;                 // kvT row d (0..63)
    const int kb = (tid & 3) << 2;          // chunk base 0,4,8,12
#pragma unroll
    for (int j = 0; j < 4; ++j) {
      const int ck = kb + j;                // 0..15
      u16x8 kk = *reinterpret_cast<const u16x8*>(
          kvT + (size_t)bh * 8192 + d * 128 + ck * 8);
      *reinterpret_cast<u16x8*>(&Kl[d][(ck ^ (d & 7)) << 3]) = kk;
    }
    if (tid < 128) k1s[tid] = k1g[bh * 128 + tid];
  }
  __syncthreads();  // the ONLY barrier

  float k1v[8];
#pragma unroll
  for (int mt = 0; mt < 8; ++mt) k1v[mt] = k1s[mt * 16 + l15];

#pragma unroll
  for (int it = 0; it < 2; ++it) {
    const int t0 = ch * 128 + w * 32 + it * 16;
    // X A-frags straight from global (rows t0+l15, k-groups lg)
    const size_t xrow = (((size_t)(b * S_ + t0 + l15) * H_ + h)) << 6;
    f16x8 x0 = *reinterpret_cast<const f16x8*>(qproj + xrow + lg * 8);
    f16x8 x1 = *reinterpret_cast<const f16x8*>(qproj + xrow + 32 + lg * 8);
    bf16x8 xb0, xb1;
    float sq = 0.f;
#pragma unroll
    for (int j = 0; j < 8; ++j) {
      float v0 = (float)x0[j] * SCALE_X;
      float v1 = (float)x1[j] * SCALE_X;
      sq += v0 * v0 + v1 * v1;
      xb0[j] = (short)f2bf(v0);
      xb1[j] = (short)f2bf(v1);
    }
    sq += __shfl_xor(sq, 16);
    sq += __shfl_xor(sq, 32);
    if (lg == 0) dgw[w][l15] = 0.5f * sq;   // diag for row l15 (wave-local)

    // wx: 8 m-tiles x 2 ks
    f32x4 wxa[8];
#pragma unroll
    for (int mt = 0; mt < 8; ++mt) {
      wxa[mt] = f32x4{0.f, 0.f, 0.f, 0.f};
      bf16x8 p0 = *reinterpret_cast<const bf16x8*>(
          &Pl[mt * 16 + l15][((lg) ^ (l15 & 7)) << 3]);
      bf16x8 p1 = *reinterpret_cast<const bf16x8*>(
          &Pl[mt * 16 + l15][((4 + lg) ^ (l15 & 7)) << 3]);
      MFMAB(wxa[mt], xb0, p0);
      MFMAB(wxa[mt], xb1, p1);
    }

    // rowmax over m (wave-local, rows lg*4+r)
    float rmx[4];
#pragma unroll
    for (int r = 0; r < 4; ++r) {
      float v = wxa[0][r];
#pragma unroll
      for (int mt = 1; mt < 8; ++mt) v = fmaxf(v, wxa[mt][r]);
      v = fmaxf(v, __shfl_xor(v, 1));
      v = fmaxf(v, __shfl_xor(v, 2));
      v = fmaxf(v, __shfl_xor(v, 4));
      v = fmaxf(v, __shfl_xor(v, 8));
      rmx[r] = v;
    }
    // phi + den + transpose write (per-wave buffer, same-wave ordering)
    float den[4] = {0.f, 0.f, 0.f, 0.f};
#pragma unroll
    for (int r = 0; r < 4; ++r) {
      const int trow = lg * 4 + r;
      const float off = rmx[r] + dgw[w][trow];
#pragma unroll
      for (int mt = 0; mt < 8; ++mt) {
        const int m = mt * 16 + l15;
        float p = __expf(wxa[mt][r] - off) * CM;
        den[r] += p * k1v[mt];
        Phw[w][trow][((((m >> 3)) ^ (trow & 7)) << 3) | (m & 7)] = f2bf(p);
      }
    }
#pragma unroll
    for (int r = 0; r < 4; ++r) {
      float v = den[r];
      v += __shfl_xor(v, 1);
      v += __shfl_xor(v, 2);
      v += __shfl_xor(v, 4);
      v += __shfl_xor(v, 8);
      if (l15 == 0) dnw[w][lg * 4 + r] = v;
    }

    // PV: out[d][t] = sum_m kvT[d][m] phi[t][m]
    const float dens = 1.f / (dnw[w][l15] + 1e-6f);
#pragma unroll
    for (int dt = 0; dt < 4; ++dt) {
      f32x4 od = {0.f, 0.f, 0.f, 0.f};
#pragma unroll
      for (int ks = 0; ks < 4; ++ks) {
        bf16x8 ka = *reinterpret_cast<const bf16x8*>(
            &Kl[dt * 16 + l15][((ks * 4 + lg) ^ (l15 & 7)) << 3]);
        bf16x8 bp = *reinterpret_cast<const bf16x8*>(
            &Phw[w][l15][((ks * 4 + lg) ^ (l15 & 7)) << 3]);
        MFMAB(od, ka, bp);
      }
      f16x4 o;
#pragma unroll
      for (int j = 0; j < 4; ++j) o[j] = (_Float16)(od[j] * dens);
      *reinterpret_cast<f16x4*>(
          &outh[(size_t)(b * S_ + t0 + l15) * 1024 + h * 64 + dt * 16 +
                lg * 4]) = o;
    }
  }
}

// ---------------------------------------------------------------------------
extern "C" void kernel_launch(void* const* d_in, const int* in_sizes, int n_in,
                              void* d_out, int out_size, void* d_ws,
                              size_t ws_size, hipStream_t stream) {
  const float* query = (const float*)d_in[0];
  const float* value = (const float*)d_in[1];
  const float* key   = (const float*)d_in[2];
  const float* Wq = (const float*)d_in[3];
  const float* bq = (const float*)d_in[4];
  const float* Wk = (const float*)d_in[5];
  const float* bk = (const float*)d_in[6];
  const float* Wv = (const float*)d_in[7];
  const float* bv = (const float*)d_in[8];
  const float* Wo = (const float*)d_in[9];
  const float* bo = (const float*)d_in[10];
  const float* proj = (const float*)d_in[11];
  float* out = (float*)d_out;
  float* ws = (float*)d_ws;

  _Float16* KP16 = (_Float16*)(ws + OFF_A);   // kproj then qproj (fp16)
  _Float16* VP16 = (_Float16*)(ws + OFF_B);   // vproj (fp16)
  _Float16* WT = (_Float16*)(ws + OFF_X);
  float* K1P = ws + OFF_X;                    // k1part (WT dead at kv time)
  unsigned short* KVT = (unsigned short*)(ws + OFF_KV);
  float* K1 = ws + OFF_K1;
  float* BMX = ws + OFF_BM;
  float* ST = ws + OFF_ST;
  _Float16* X16 = (_Float16*)(ws + OFF_A16);  // GEMM A staging
  float* KVPT = ws + OFF_A16;                 // kv partials (staging dead)

  dim3 gw(32, 32);

  // 1. k_proj (fp16)
  cvt_f16_kernel<<<2048, 256, 0, stream>>>(key, X16);
  wt_f16_kernel<<<gw, 256, 0, stream>>>(Wk, WT);
  gemm_lds<1><<<256, 512, 0, stream>>>(X16, WT, bk, KP16);
  // 2. stab (reference global max wx_k)
  wxmax_mfma_kernel<<<512, 256, 0, stream>>>(KP16, proj, BMX);
  maxreduce_kernel<<<1, 256, 0, stream>>>(BMX, ST, 512);
  // 3. v_proj (fp16)
  cvt_f16_kernel<<<2048, 256, 0, stream>>>(value, X16);
  wt_f16_kernel<<<gw, 256, 0, stream>>>(Wv, WT);
  gemm_lds<1><<<256, 512, 0, stream>>>(X16, WT, bv, VP16);
  // 4. kv / k1 (KVPT aliases X16 staging — dead; K1P aliases WT — dead)
  kv_mfma_kernel<<<1024, 256, 0, stream>>>(KP16, VP16, proj, ST, KVPT, K1P);
  kvreduce_kernel<<<64, 256, 0, stream>>>(KVPT, K1P, KVT, K1);
  // 5. q_proj (KVPT dead after reduce; kproj dead after kv)
  cvt_f16_kernel<<<2048, 256, 0, stream>>>(query, X16);
  wt_f16_kernel<<<gw, 256, 0, stream>>>(Wq, WT);
  gemm_lds<1><<<256, 512, 0, stream>>>(X16, WT, bq, KP16);
  // 6. out_h -> X16 as fp16 (query staging dead after q_proj gemm)
  qkv_wave_kernel<<<2048, 256, 0, stream>>>(KP16, KVT, K1, proj, X16);
  // 7. output projection (f32 out)
  wt_f16_kernel<<<gw, 256, 0, stream>>>(Wo, WT);
  gemm_lds<0><<<256, 512, 0, stream>>>(X16, WT, bo, out);
}